// Round 3
// baseline (2612.376 us; speedup 1.0000x reference)
//
#include <hip/hip_runtime.h>
#include <hip/hip_bf16.h>

#define BLK   256
#define NSAMP 558
#define NRAYS 2048
#define RESI  160
#define R2I   25600
#define R3I   4096000
#define NTOT  (NRAYS * NSAMP)          // 1,142,784
#define SAMP_BLOCKS (NTOT / BLK)       // 4464 exact
#define RAYSTRIDE 32
#define NVOX  4096000                  // 160^3
#define TG_BLOCKS (NVOX / BLK)         // 16000 exact
#define TPR2  279                      // threads per ray at K=2 (558/2)
#define MLP2_THREADS (NRAYS * TPR2)    // 571,392
#define MLP2_BLOCKS (MLP2_THREADS / BLK) // 2232 exact

#define ACT_SHIFT_F (-4.5951198501345896f)
#define STEP_F 0.00625f   // STEPSIZE * VOXEL

// ---------------- ws layout ----------------
#define RAYDATA_OFF 256
#define SAMP_OFF    (RAYDATA_OFF + NRAYS * RAYSTRIDE * 4)
#define TG_OFF      (SAMP_OFF + (size_t)NTOT * 16)
#define WS_BIG      (TG_OFF + (size_t)NVOX * 32)
#define LAT_OFF     WS_BIG
#define WS_SPLIT    (LAT_OFF + (size_t)NTOT * 48)

template <typename T> __device__ __forceinline__ float ldv(const T* p, int i);
template <> __device__ __forceinline__ float ldv<float>(const float* p, int i) { return p[i]; }
template <> __device__ __forceinline__ float ldv<__hip_bfloat16>(const __hip_bfloat16* p, int i) {
    return __bfloat162float(p[i]);
}
template <typename T> __device__ __forceinline__ T cvt_out(float v);
template <> __device__ __forceinline__ float cvt_out<float>(float v) { return v; }
template <> __device__ __forceinline__ __hip_bfloat16 cvt_out<__hip_bfloat16>(float v) {
    return __float2bfloat16(v);
}
__device__ __forceinline__ float b2f(unsigned short u) {
    union { float f; unsigned int i; } c; c.i = ((unsigned int)u) << 16; return c.f;
}
__device__ __forceinline__ float blo(unsigned int u) {
    union { float f; unsigned int i; } c; c.i = u << 16; return c.f;
}
__device__ __forceinline__ float bhi(unsigned int u) {
    union { float f; unsigned int i; } c; c.i = u & 0xffff0000u; return c.f;
}
__device__ __forceinline__ unsigned short f2b(float v) {
    __hip_bfloat16 h = __float2bfloat16(v);
    unsigned short u;
    __builtin_memcpy(&u, &h, sizeof(u));
    return u;
}

template <typename T>
struct KParams {
    const T *rays_o, *rays_d, *viewdirs, *grid;
    const T *aw1,*ab1,*aw2,*ab2,*aw3,*ab3;
    const T *pw1,*pb1,*pw2,*pb2,*pw3,*pb3;
    const T *dw1,*db1,*dw2,*db2,*dw3,*db3,*dw4,*db4;
    T *out;
    const int* flag;
    float* rayData;
    float4* samp;
    unsigned short* tgrid;
    float4* lat;     // [3*NTOT]: A=lat[idx], B=lat[NTOT+idx], C=lat[2*NTOT+idx]
    int want;
};

// ---- dtype detector ----
__global__ void detect_dtype(const void* vd, int* flag) {
    if (threadIdx.x == 0 && blockIdx.x == 0) {
        const float* f = (const float*)vd;
        const __hip_bfloat16* h = (const __hip_bfloat16*)vd;
        float sf = 0.f, sb = 0.f;
        for (int r = 0; r < 8; ++r) {
            float a = f[r*3], b = f[r*3+1], c = f[r*3+2];
            float d = (a*a + b*b + c*c) - 1.f;
            sf += d*d;
            float a2 = __bfloat162float(h[r*3]);
            float b2 = __bfloat162float(h[r*3+1]);
            float c2 = __bfloat162float(h[r*3+2]);
            float d2 = (a2*a2 + b2*b2 + c2*c2) - 1.f;
            sb += d2*d2;
        }
        bool sf_ok = (sf == sf) && (sf < 1e30f);
        bool sb_ok = (sb == sb) && (sb < 1e30f);
        int fl = 0;
        if (sb_ok && (!sf_ok || sb < sf)) fl = 1;
        *flag = fl;
    }
}

// =============== Transpose: (12, X, Y, Z) -> voxel-major [X][Y][Z][16ch] bf16 ===============
template <typename T>
__global__ __launch_bounds__(BLK)
void transpose_k(KParams<T> P) {
    if (*P.flag != P.want) return;
    const int i = blockIdx.x * BLK + threadIdx.x;
    unsigned short r[16];
    #pragma unroll
    for (int c = 0; c < 12; ++c) r[c] = f2b(ldv<T>(P.grid, c * R3I + i));
    #pragma unroll
    for (int c = 12; c < 16; ++c) r[c] = 0;
    uint4* dst = (uint4*)(P.tgrid + (size_t)i * 16);
    uint4 w0, w1;
    w0.x = (unsigned int)r[0] | ((unsigned int)r[1] << 16);
    w0.y = (unsigned int)r[2] | ((unsigned int)r[3] << 16);
    w0.z = (unsigned int)r[4] | ((unsigned int)r[5] << 16);
    w0.w = (unsigned int)r[6] | ((unsigned int)r[7] << 16);
    w1.x = (unsigned int)r[8] | ((unsigned int)r[9] << 16);
    w1.y = (unsigned int)r[10] | ((unsigned int)r[11] << 16);
    w1.z = 0; w1.w = 0;
    dst[0] = w0; dst[1] = w1;
}

// =============== Kernel 1: per-ray prep ===============
template <typename T>
__global__ __launch_bounds__(BLK)
void prep_k(KParams<T> P) {
    if (*P.flag != P.want) return;
    __shared__ float semb[BLK * 39];
    const int tid = threadIdx.x;
    const int ray = blockIdx.x * BLK + tid;
    if (ray >= NRAYS) return;
    const float ox = ldv<T>(P.rays_o, ray*3+0);
    const float oy = ldv<T>(P.rays_o, ray*3+1);
    const float oz = ldv<T>(P.rays_o, ray*3+2);
    const float dx = ldv<T>(P.rays_d, ray*3+0);
    const float dy = ldv<T>(P.rays_d, ray*3+1);
    const float dz = ldv<T>(P.rays_d, ray*3+2);
    const float vx = (dx == 0.f) ? 1e-6f : dx;
    const float vy = (dy == 0.f) ? 1e-6f : dy;
    const float vz = (dz == 0.f) ? 1e-6f : dz;
    const float rax = (1.f - ox) / vx, rbx = (-1.f - ox) / vx;
    const float ray_ = (1.f - oy) / vy, rby = (-1.f - oy) / vy;
    const float raz = (1.f - oz) / vz, rbz = (-1.f - oz) / vz;
    float tmin = fmaxf(fmaxf(fminf(rax, rbx), fminf(ray_, rby)), fminf(raz, rbz));
    float tmax = fminf(fminf(fmaxf(rax, rbx), fmaxf(ray_, rby)), fmaxf(raz, rbz));
    tmin = fminf(fmaxf(tmin, 0.05f), 3.5f);
    tmax = fminf(fmaxf(tmax, 0.05f), 3.5f);
    const bool mask_ray = (tmax <= tmin);
    const float norm_d = sqrtf(dx*dx + dy*dy + dz*dz);
    const float inv_nd = 1.f / norm_d;
    {
        float v0 = ldv<T>(P.viewdirs, ray*3+0);
        float v1 = ldv<T>(P.viewdirs, ray*3+1);
        float v2 = ldv<T>(P.viewdirs, ray*3+2);
        float* e = semb + tid*39;
        e[0] = v0; e[1] = v1; e[2] = v2;
        #pragma unroll
        for (int l = 0; l < 6; ++l) {
            float f = (float)(1 << l);
            e[3 + l*6 + 0] = __sinf(v0*f);
            e[3 + l*6 + 1] = __sinf(v1*f);
            e[3 + l*6 + 2] = __sinf(v2*f);
            e[3 + l*6 + 3] = __cosf(v0*f);
            e[3 + l*6 + 4] = __cosf(v1*f);
            e[3 + l*6 + 5] = __cosf(v2*f);
        }
    }
    float acc[16];
    #pragma unroll
    for (int j = 0; j < 16; ++j) acc[j] = ldv<T>(P.db1, j);
    const float* e = semb + tid*39;
    for (int i = 0; i < 39; ++i) {
        float xi = e[i];
        #pragma unroll
        for (int j = 0; j < 16; ++j) acc[j] = fmaf(xi, ldv<T>(P.dw1, (15+i)*16 + j), acc[j]);
    }
    float* rd = P.rayData + ray * RAYSTRIDE;
    rd[0] = ox; rd[1] = oy; rd[2] = oz;
    rd[3] = dx; rd[4] = dy; rd[5] = dz;
    rd[6] = mask_ray ? __int_as_float(0x7fc00000) : tmin;
    rd[7] = inv_nd;
    #pragma unroll
    for (int j = 0; j < 16; ++j) rd[8 + j] = acc[j];
    rd[24] = tmin * norm_d;
}

// =============== shared LDS weight layout for sample kernels ===============
#define AW1_O 0
#define AB1_O 480
#define AW2_O 512
#define AB2_O 1536
#define AW3_O 1568
#define AB3_O 1696
#define PW1_O 1700
#define PB1_O 1892
#define PW2_O 1908
#define PB2_O 2164
#define PW3_O 2180
#define PB3_O 2436
#define DW1_O 2452   /* rows 0..14 only: 240 */
#define DW2_O 2692
#define DB2_O 2948
#define DW3_O 2964
#define DB3_O 3220
#define DW4_O 3236   /* PADDED: 16 rows x 4 floats (col 3 = 0) */
#define DB4_O 3300   /* PADDED: 4 floats (last = 0) */
#define SW2_FLOATS 3304

template <typename T>
__device__ __forceinline__ void stage_w(float* dst, const T* src, int n, int tid) {
    for (int i = tid; i < n; i += BLK) dst[i] = ldv<T>(src, i);
}

template <typename T>
__device__ __forceinline__ void stage_all(float* sw, const KParams<T>& P, int tid) {
    stage_w(sw + AW1_O, P.aw1, 480, tid);
    stage_w(sw + AB1_O, P.ab1, 32, tid);
    stage_w(sw + AW2_O, P.aw2, 1024, tid);
    stage_w(sw + AB2_O, P.ab2, 32, tid);
    stage_w(sw + AW3_O, P.aw3, 128, tid);
    stage_w(sw + AB3_O, P.ab3, 4, tid);
    stage_w(sw + PW1_O, P.pw1, 192, tid);
    stage_w(sw + PB1_O, P.pb1, 16, tid);
    stage_w(sw + PW2_O, P.pw2, 256, tid);
    stage_w(sw + PB2_O, P.pb2, 16, tid);
    stage_w(sw + PW3_O, P.pw3, 256, tid);
    stage_w(sw + PB3_O, P.pb3, 16, tid);
    stage_w(sw + DW1_O, P.dw1, 240, tid);
    stage_w(sw + DW2_O, P.dw2, 256, tid);
    stage_w(sw + DB2_O, P.db2, 16, tid);
    stage_w(sw + DW3_O, P.dw3, 256, tid);
    stage_w(sw + DB3_O, P.db3, 16, tid);
    for (int i = tid; i < 64; i += BLK) {
        int r = i >> 2, c = i & 3;
        sw[DW4_O + i] = (c < 3) ? ldv<T>(P.dw4, r*3 + c) : 0.f;
    }
    if (tid < 4) sw[DB4_O + tid] = (tid < 3) ? ldv<T>(P.db4, tid) : 0.f;
}

// ---- register-resident float4 helpers ----
__device__ __forceinline__ float4 lds4(const float* p) { return *(const float4*)p; }
__device__ __forceinline__ void fma4(float4& a, float s, float4 w) {
    a.x = fmaf(s, w.x, a.x); a.y = fmaf(s, w.y, a.y);
    a.z = fmaf(s, w.z, a.z); a.w = fmaf(s, w.w, a.w);
}
__device__ __forceinline__ void relu4(float4& a) {
    a.x = fmaxf(a.x, 0.f); a.y = fmaxf(a.y, 0.f);
    a.z = fmaxf(a.z, 0.f); a.w = fmaxf(a.w, 0.f);
}

// =====================================================================================
// PAIRED MLP: two samples per thread. Each LDS weight load is used by BOTH samples
// (halves ds_read count per sample) and the two FMA chains are independent (ILP=2).
// =====================================================================================
__device__ __forceinline__ void mlp_macro2(const float* sw, const float* rd,
        float4 A0, float4 B0, float4 C0, float4 A1, float4 B1, float4 C1,
        float px0, float py0, float pz0, float px1, float py1, float pz1,
        float4& res0, float4& res1) {
    // ---- attention layer 1: in[15] = {pz,py,px, lat0..11} -> 32 ----
    float4 qa0 = lds4(sw+AB1_O+0),  qa1 = lds4(sw+AB1_O+4),
           qa2 = lds4(sw+AB1_O+8),  qa3 = lds4(sw+AB1_O+12),
           qa4 = lds4(sw+AB1_O+16), qa5 = lds4(sw+AB1_O+20),
           qa6 = lds4(sw+AB1_O+24), qa7 = lds4(sw+AB1_O+28);
    float4 qb0 = qa0, qb1 = qa1, qb2 = qa2, qb3 = qa3,
           qb4 = qa4, qb5 = qa5, qb6 = qa6, qb7 = qa7;
#define PL1ROW(i, sa_, sb_) { const float* W_ = sw + AW1_O + (i)*32; const float sa=(sa_), sb=(sb_); \
    { const float4 w_=lds4(W_+0);  fma4(qa0,sa,w_); fma4(qb0,sb,w_); } \
    { const float4 w_=lds4(W_+4);  fma4(qa1,sa,w_); fma4(qb1,sb,w_); } \
    { const float4 w_=lds4(W_+8);  fma4(qa2,sa,w_); fma4(qb2,sb,w_); } \
    { const float4 w_=lds4(W_+12); fma4(qa3,sa,w_); fma4(qb3,sb,w_); } \
    { const float4 w_=lds4(W_+16); fma4(qa4,sa,w_); fma4(qb4,sb,w_); } \
    { const float4 w_=lds4(W_+20); fma4(qa5,sa,w_); fma4(qb5,sb,w_); } \
    { const float4 w_=lds4(W_+24); fma4(qa6,sa,w_); fma4(qb6,sb,w_); } \
    { const float4 w_=lds4(W_+28); fma4(qa7,sa,w_); fma4(qb7,sb,w_); } }
    PL1ROW(0,pz0,pz1) PL1ROW(1,py0,py1) PL1ROW(2,px0,px1)
    PL1ROW(3,A0.x,A1.x) PL1ROW(4,A0.y,A1.y) PL1ROW(5,A0.z,A1.z) PL1ROW(6,A0.w,A1.w)
    PL1ROW(7,B0.x,B1.x) PL1ROW(8,B0.y,B1.y) PL1ROW(9,B0.z,B1.z) PL1ROW(10,B0.w,B1.w)
    PL1ROW(11,C0.x,C1.x) PL1ROW(12,C0.y,C1.y) PL1ROW(13,C0.z,C1.z) PL1ROW(14,C0.w,C1.w)
#undef PL1ROW
    relu4(qa0); relu4(qa1); relu4(qa2); relu4(qa3);
    relu4(qa4); relu4(qa5); relu4(qa6); relu4(qa7);
    relu4(qb0); relu4(qb1); relu4(qb2); relu4(qb3);
    relu4(qb4); relu4(qb5); relu4(qb6); relu4(qb7);

    // ---- attention layers 2+3, blocked by output group c ----
    float4 lga = lds4(sw+AB3_O);
    float4 lgb = lga;
#define PA2ROW(c,i,sa_,sb_) { const float* W_ = sw + AW2_O + (i)*32 + (c)*8; \
    const float4 w0_=lds4(W_), w1_=lds4(W_+4); const float sa=(sa_), sb=(sb_); \
    fma4(ta0,sa,w0_); fma4(ta1,sa,w1_); fma4(tb0,sb,w0_); fma4(tb1,sb,w1_); }
#define PA2Q(c,i0,qva,qvb) PA2ROW(c,(i0)+0,qva.x,qvb.x) PA2ROW(c,(i0)+1,qva.y,qvb.y) \
                           PA2ROW(c,(i0)+2,qva.z,qvb.z) PA2ROW(c,(i0)+3,qva.w,qvb.w)
#define PA3F(c,j,ta_,tb_) { const float4 w_=lds4(sw + AW3_O + ((c)*8+(j))*4); \
    fma4(lga, fmaxf((ta_),0.f), w_); fma4(lgb, fmaxf((tb_),0.f), w_); }
#define PABLK(c) { float4 ta0 = lds4(sw+AB2_O+(c)*8); float4 ta1 = lds4(sw+AB2_O+(c)*8+4); \
    float4 tb0 = ta0, tb1 = ta1; \
    PA2Q(c,0,qa0,qb0) PA2Q(c,4,qa1,qb1) PA2Q(c,8,qa2,qb2) PA2Q(c,12,qa3,qb3) \
    PA2Q(c,16,qa4,qb4) PA2Q(c,20,qa5,qb5) PA2Q(c,24,qa6,qb6) PA2Q(c,28,qa7,qb7) \
    PA3F(c,0,ta0.x,tb0.x) PA3F(c,1,ta0.y,tb0.y) PA3F(c,2,ta0.z,tb0.z) PA3F(c,3,ta0.w,tb0.w) \
    PA3F(c,4,ta1.x,tb1.x) PA3F(c,5,ta1.y,tb1.y) PA3F(c,6,ta1.z,tb1.z) PA3F(c,7,ta1.w,tb1.w) }
    PABLK(0) PABLK(1) PABLK(2) PABLK(3)
#undef PABLK
#undef PA3F
#undef PA2Q
#undef PA2ROW
    float ma = fmaxf(fmaxf(lga.x,lga.y), fmaxf(lga.z,lga.w));
    float ea0 = __expf(lga.x-ma), ea1 = __expf(lga.y-ma), ea2 = __expf(lga.z-ma), ea3 = __expf(lga.w-ma);
    float att1a = ea1 / (ea0+ea1+ea2+ea3);
    float mb = fmaxf(fmaxf(lgb.x,lgb.y), fmaxf(lgb.z,lgb.w));
    float eb0 = __expf(lgb.x-mb), eb1 = __expf(lgb.y-mb), eb2 = __expf(lgb.z-mb), eb3 = __expf(lgb.w-mb);
    float att1b = eb1 / (eb0+eb1+eb2+eb3);

#define PR16(pre,i,sa_,sb_,BASE) { const float* W_ = sw + (BASE) + (i)*16; \
    const float4 w0_=lds4(W_), w1_=lds4(W_+4), w2_=lds4(W_+8), w3_=lds4(W_+12); \
    const float sa=(sa_), sb=(sb_); \
    fma4(pre##a0,sa,w0_); fma4(pre##a1,sa,w1_); fma4(pre##a2,sa,w2_); fma4(pre##a3,sa,w3_); \
    fma4(pre##b0,sb,w0_); fma4(pre##b1,sb,w1_); fma4(pre##b2,sb,w2_); fma4(pre##b3,sb,w3_); }
#define PR16Q(pre,i0,qva,qvb,BASE) PR16(pre,(i0)+0,qva.x,qvb.x,BASE) PR16(pre,(i0)+1,qva.y,qvb.y,BASE) \
                                   PR16(pre,(i0)+2,qva.z,qvb.z,BASE) PR16(pre,(i0)+3,qva.w,qvb.w,BASE)

    // ---- pos net: lat -> 16 -> 16 -> 16 ----
    float4 ua0 = lds4(sw+PB1_O), ua1 = lds4(sw+PB1_O+4), ua2 = lds4(sw+PB1_O+8), ua3 = lds4(sw+PB1_O+12);
    float4 ub0 = ua0, ub1 = ua1, ub2 = ua2, ub3 = ua3;
    PR16Q(u,0,A0,A1,PW1_O) PR16Q(u,4,B0,B1,PW1_O) PR16Q(u,8,C0,C1,PW1_O)
    relu4(ua0); relu4(ua1); relu4(ua2); relu4(ua3);
    relu4(ub0); relu4(ub1); relu4(ub2); relu4(ub3);
    float4 va0 = lds4(sw+PB2_O), va1 = lds4(sw+PB2_O+4), va2 = lds4(sw+PB2_O+8), va3 = lds4(sw+PB2_O+12);
    float4 vb0 = va0, vb1 = va1, vb2 = va2, vb3 = va3;
    PR16Q(v,0,ua0,ub0,PW2_O) PR16Q(v,4,ua1,ub1,PW2_O)
    PR16Q(v,8,ua2,ub2,PW2_O) PR16Q(v,12,ua3,ub3,PW2_O)
    relu4(va0); relu4(va1); relu4(va2); relu4(va3);
    relu4(vb0); relu4(vb1); relu4(vb2); relu4(vb3);
    float4 oa0 = lds4(sw+PB3_O), oa1 = lds4(sw+PB3_O+4), oa2 = lds4(sw+PB3_O+8), oa3 = lds4(sw+PB3_O+12);
    float4 ob0 = oa0, ob1 = oa1, ob2 = oa2, ob3 = oa3;
    PR16Q(o,0,va0,vb0,PW3_O) PR16Q(o,4,va1,vb1,PW3_O)
    PR16Q(o,8,va2,vb2,PW3_O) PR16Q(o,12,va3,vb3,PW3_O)

    // ---- decoder (d1 init = precomputed emb part, SHARED by both samples) ----
    const float4* rdv = (const float4*)(rd + 8);
    float4 da0 = rdv[0], da1 = rdv[1], da2 = rdv[2], da3 = rdv[3];
    float4 db0 = da0, db1 = da1, db2 = da2, db3 = da3;
    PR16(d,0,oa0.y,ob0.y,DW1_O) PR16(d,1,oa0.z,ob0.z,DW1_O) PR16(d,2,oa0.w,ob0.w,DW1_O)
    PR16Q(d,3,oa1,ob1,DW1_O) PR16Q(d,7,oa2,ob2,DW1_O) PR16Q(d,11,oa3,ob3,DW1_O)
    relu4(da0); relu4(da1); relu4(da2); relu4(da3);
    relu4(db0); relu4(db1); relu4(db2); relu4(db3);
    float4 ga0 = lds4(sw+DB2_O), ga1 = lds4(sw+DB2_O+4), ga2 = lds4(sw+DB2_O+8), ga3 = lds4(sw+DB2_O+12);
    float4 gb0 = ga0, gb1 = ga1, gb2 = ga2, gb3 = ga3;
    PR16Q(g,0,da0,db0,DW2_O) PR16Q(g,4,da1,db1,DW2_O)
    PR16Q(g,8,da2,db2,DW2_O) PR16Q(g,12,da3,db3,DW2_O)
    relu4(ga0); relu4(ga1); relu4(ga2); relu4(ga3);
    relu4(gb0); relu4(gb1); relu4(gb2); relu4(gb3);
    float4 ha0 = lds4(sw+DB3_O), ha1 = lds4(sw+DB3_O+4), ha2 = lds4(sw+DB3_O+8), ha3 = lds4(sw+DB3_O+12);
    float4 hb0 = ha0, hb1 = ha1, hb2 = ha2, hb3 = ha3;
    PR16Q(h,0,ga0,gb0,DW3_O) PR16Q(h,4,ga1,gb1,DW3_O)
    PR16Q(h,8,ga2,gb2,DW3_O) PR16Q(h,12,ga3,gb3,DW3_O)
    relu4(ha0); relu4(ha1); relu4(ha2); relu4(ha3);
    relu4(hb0); relu4(hb1); relu4(hb2); relu4(hb3);
    float4 rra = lds4(sw+DB4_O);
    float4 rrb = rra;
#define PR4(i, sa_, sb_) { const float4 w_=lds4(sw + DW4_O + (i)*4); fma4(rra,(sa_),w_); fma4(rrb,(sb_),w_); }
    PR4(0,ha0.x,hb0.x) PR4(1,ha0.y,hb0.y) PR4(2,ha0.z,hb0.z) PR4(3,ha0.w,hb0.w)
    PR4(4,ha1.x,hb1.x) PR4(5,ha1.y,hb1.y) PR4(6,ha1.z,hb1.z) PR4(7,ha1.w,hb1.w)
    PR4(8,ha2.x,hb2.x) PR4(9,ha2.y,hb2.y) PR4(10,ha2.z,hb2.z) PR4(11,ha2.w,hb2.w)
    PR4(12,ha3.x,hb3.x) PR4(13,ha3.y,hb3.y) PR4(14,ha3.z,hb3.z) PR4(15,ha3.w,hb3.w)
#undef PR4
#undef PR16Q
#undef PR16
    {
        float dens = att1a * oa0.x;
        float xsh = dens + ACT_SHIFT_F;
        float sp = (xsh > 0.f) ? xsh + log1pf(__expf(-xsh)) : log1pf(__expf(xsh));
        res0.x = 1.f - __expf(-sp * 0.5f);
        res0.y = 1.f / (1.f + __expf(-att1a * rra.x));
        res0.z = 1.f / (1.f + __expf(-att1a * rra.y));
        res0.w = 1.f / (1.f + __expf(-att1a * rra.z));
    }
    {
        float dens = att1b * ob0.x;
        float xsh = dens + ACT_SHIFT_F;
        float sp = (xsh > 0.f) ? xsh + log1pf(__expf(-xsh)) : log1pf(__expf(xsh));
        res1.x = 1.f - __expf(-sp * 0.5f);
        res1.y = 1.f / (1.f + __expf(-att1b * rrb.x));
        res1.z = 1.f / (1.f + __expf(-att1b * rrb.y));
        res1.w = 1.f / (1.f + __expf(-att1b * rrb.z));
    }
}

// Single-sample chain (fallback paths only)
__device__ __forceinline__ float4 mlp_macro(const float* sw, const float* rd,
                                            float4 A, float4 B, float4 C,
                                            float px, float py, float pz) {
    float4 r0, r1;
    mlp_macro2(sw, rd, A, B, C, A, B, C, px, py, pz, px, py, pz, r0, r1);
    return r0;
}

// =============== SPLIT PATH kernel A: pure trilinear gather -> lat buffer ===============
template <typename T>
__global__ __launch_bounds__(BLK, 4)
void gather_tg_k(KParams<T> P) {
    if (*P.flag != P.want) return;
    const int idx = blockIdx.x * BLK + threadIdx.x;
    const int ray = idx / NSAMP;
    const int s   = idx - ray * NSAMP;
    const float* rd = P.rayData + ray * RAYSTRIDE;
    const float tmin = rd[6], inv_nd = rd[7];
    const float it = fmaf(STEP_F * (float)s, inv_nd, tmin);
    const float px = fmaf(rd[3], it, rd[0]);
    const float py = fmaf(rd[4], it, rd[1]);
    const float pz = fmaf(rd[5], it, rd[2]);
    bool inb = (px >= -1.f) & (px <= 1.f) & (py >= -1.f) & (py <= 1.f)
             & (pz >= -1.f) & (pz <= 1.f);
    if (!inb) return;
    float gx = (px + 1.f) * 79.5f;
    float gy = (py + 1.f) * 79.5f;
    float gz = (pz + 1.f) * 79.5f;
    float fx0 = floorf(gx), fy0 = floorf(gy), fz0 = floorf(gz);
    float frx = gx - fx0, fry = gy - fy0, frz = gz - fz0;
    int x0 = min(max((int)fx0, 0), RESI-1); int x1 = min(x0+1, RESI-1);
    int y0 = min(max((int)fy0, 0), RESI-1); int y1 = min(y0+1, RESI-1);
    int z0 = min(max((int)fz0, 0), RESI-1); int z1 = min(z0+1, RESI-1);
    int bx0 = x0*R2I, bx1 = x1*R2I, by0 = y0*RESI, by1 = y1*RESI;
    float wx0 = 1.f-frx, wy0 = 1.f-fry, wz0 = 1.f-frz;
    float4 LA = make_float4(0.f,0.f,0.f,0.f);
    float4 LB = make_float4(0.f,0.f,0.f,0.f);
    float4 LC = make_float4(0.f,0.f,0.f,0.f);
#define CORNER(OFF, W_) { const unsigned short* vp = P.tgrid + (OFF)*16; \
    uint4 a_ = *(const uint4*)vp; uint2 b_ = *(const uint2*)(vp + 8); const float w = (W_); \
    LA.x = fmaf(w, blo(a_.x), LA.x); LA.y = fmaf(w, bhi(a_.x), LA.y); \
    LA.z = fmaf(w, blo(a_.y), LA.z); LA.w = fmaf(w, bhi(a_.y), LA.w); \
    LB.x = fmaf(w, blo(a_.z), LB.x); LB.y = fmaf(w, bhi(a_.z), LB.y); \
    LB.z = fmaf(w, blo(a_.w), LB.z); LB.w = fmaf(w, bhi(a_.w), LB.w); \
    LC.x = fmaf(w, blo(b_.x), LC.x); LC.y = fmaf(w, bhi(b_.x), LC.y); \
    LC.z = fmaf(w, blo(b_.y), LC.z); LC.w = fmaf(w, bhi(b_.y), LC.w); }
    CORNER(bx0+by0+z0, wx0*wy0*wz0)
    CORNER(bx0+by0+z1, wx0*wy0*frz)
    CORNER(bx0+by1+z0, wx0*fry*wz0)
    CORNER(bx0+by1+z1, wx0*fry*frz)
    CORNER(bx1+by0+z0, frx*wy0*wz0)
    CORNER(bx1+by0+z1, frx*wy0*frz)
    CORNER(bx1+by1+z0, frx*fry*wz0)
    CORNER(bx1+by1+z1, frx*fry*frz)
#undef CORNER
    P.lat[idx]          = LA;
    P.lat[NTOT + idx]   = LB;
    P.lat[2*NTOT + idx] = LC;
}

// =============== SPLIT PATH kernel B: paired streaming MLP (2 samples/thread) ===============
template <typename T>
__global__ __launch_bounds__(BLK, 3)
void mlp2_k(KParams<T> P) {
    if (*P.flag != P.want) return;
    __shared__ float sw[SW2_FLOATS];
    const int tid = threadIdx.x;
    stage_all(sw, P, tid);
    __syncthreads();

    const int gid = blockIdx.x * BLK + tid;      // 0 .. MLP2_THREADS-1
    const int ray = gid / TPR2;
    const int idx0 = gid * 2;                    // = ray*NSAMP + 2*(gid%TPR2)
    const int s0 = idx0 - ray * NSAMP;
    const float* rd = P.rayData + ray * RAYSTRIDE;
    const float tmin = rd[6], inv_nd = rd[7];
    const float it0 = fmaf(STEP_F * (float)s0, inv_nd, tmin);
    const float it1 = fmaf(STEP_F * (float)(s0+1), inv_nd, tmin);
    const float px0 = fmaf(rd[3], it0, rd[0]);
    const float py0 = fmaf(rd[4], it0, rd[1]);
    const float pz0 = fmaf(rd[5], it0, rd[2]);
    const float px1 = fmaf(rd[3], it1, rd[0]);
    const float py1 = fmaf(rd[4], it1, rd[1]);
    const float pz1 = fmaf(rd[5], it1, rd[2]);
    const bool inb0 = (px0 >= -1.f) & (px0 <= 1.f) & (py0 >= -1.f) & (py0 <= 1.f)
                    & (pz0 >= -1.f) & (pz0 <= 1.f);
    const bool inb1 = (px1 >= -1.f) & (px1 <= 1.f) & (py1 >= -1.f) & (py1 <= 1.f)
                    & (pz1 >= -1.f) & (pz1 <= 1.f);
    const float4 z = make_float4(0.f, 0.f, 0.f, 0.f);
    float4 r0 = z, r1 = z;
    if (inb0 | inb1) {
        // lat of a not-gathered sample is unwritten (poison) -> select to 0 before use
        float4 A0 = P.lat[idx0],        A1 = P.lat[idx0+1];
        float4 B0 = P.lat[NTOT+idx0],   B1 = P.lat[NTOT+idx0+1];
        float4 C0 = P.lat[2*NTOT+idx0], C1 = P.lat[2*NTOT+idx0+1];
        if (!inb0) { A0 = z; B0 = z; C0 = z; }
        if (!inb1) { A1 = z; B1 = z; C1 = z; }
        mlp_macro2(sw, rd, A0, B0, C0, A1, B1, C1,
                   px0, py0, pz0, px1, py1, pz1, r0, r1);
        if (!inb0) r0 = z;
        if (!inb1) r1 = z;
    }
    P.samp[idx0]   = r0;
    P.samp[idx0+1] = r1;
}

// =============== Kernel 2 (big path): fused gather + MLP, AoS transposed grid ===============
template <typename T>
__global__ __launch_bounds__(BLK, 3)
void sample_tg_k(KParams<T> P) {
    if (*P.flag != P.want) return;
    __shared__ float sw[SW2_FLOATS];
    const int tid = threadIdx.x;
    stage_all(sw, P, tid);
    __syncthreads();

    const int idx = blockIdx.x * BLK + tid;
    const int ray = idx / NSAMP;
    const int s   = idx - ray * NSAMP;
    const float* rd = P.rayData + ray * RAYSTRIDE;
    const float tmin = rd[6], inv_nd = rd[7];
    const float it = fmaf(STEP_F * (float)s, inv_nd, tmin);
    const float px = fmaf(rd[3], it, rd[0]);
    const float py = fmaf(rd[4], it, rd[1]);
    const float pz = fmaf(rd[5], it, rd[2]);
    bool inb = (px >= -1.f) & (px <= 1.f) & (py >= -1.f) & (py <= 1.f)
             & (pz >= -1.f) & (pz <= 1.f);
    float4 res = make_float4(0.f, 0.f, 0.f, 0.f);
    if (inb) {
        float gx = (px + 1.f) * 79.5f;
        float gy = (py + 1.f) * 79.5f;
        float gz = (pz + 1.f) * 79.5f;
        float fx0 = floorf(gx), fy0 = floorf(gy), fz0 = floorf(gz);
        float frx = gx - fx0, fry = gy - fy0, frz = gz - fz0;
        int x0 = min(max((int)fx0, 0), RESI-1); int x1 = min(x0+1, RESI-1);
        int y0 = min(max((int)fy0, 0), RESI-1); int y1 = min(y0+1, RESI-1);
        int z0 = min(max((int)fz0, 0), RESI-1); int z1 = min(z0+1, RESI-1);
        int bx0 = x0*R2I, bx1 = x1*R2I, by0 = y0*RESI, by1 = y1*RESI;
        float wx0 = 1.f-frx, wy0 = 1.f-fry, wz0 = 1.f-frz;
        float4 LA = make_float4(0.f,0.f,0.f,0.f);
        float4 LB = make_float4(0.f,0.f,0.f,0.f);
        float4 LC = make_float4(0.f,0.f,0.f,0.f);
#define CORNER(OFF, W_) { const unsigned short* vp = P.tgrid + (OFF)*16; \
        uint4 a_ = *(const uint4*)vp; uint2 b_ = *(const uint2*)(vp + 8); const float w = (W_); \
        LA.x = fmaf(w, blo(a_.x), LA.x); LA.y = fmaf(w, bhi(a_.x), LA.y); \
        LA.z = fmaf(w, blo(a_.y), LA.z); LA.w = fmaf(w, bhi(a_.y), LA.w); \
        LB.x = fmaf(w, blo(a_.z), LB.x); LB.y = fmaf(w, bhi(a_.z), LB.y); \
        LB.z = fmaf(w, blo(a_.w), LB.z); LB.w = fmaf(w, bhi(a_.w), LB.w); \
        LC.x = fmaf(w, blo(b_.x), LC.x); LC.y = fmaf(w, bhi(b_.x), LC.y); \
        LC.z = fmaf(w, blo(b_.y), LC.z); LC.w = fmaf(w, bhi(b_.y), LC.w); }
        CORNER(bx0+by0+z0, wx0*wy0*wz0)
        CORNER(bx0+by0+z1, wx0*wy0*frz)
        CORNER(bx0+by1+z0, wx0*fry*wz0)
        CORNER(bx0+by1+z1, wx0*fry*frz)
        CORNER(bx1+by0+z0, frx*wy0*wz0)
        CORNER(bx1+by0+z1, frx*wy0*frz)
        CORNER(bx1+by1+z0, frx*fry*wz0)
        CORNER(bx1+by1+z1, frx*fry*frz)
#undef CORNER
        res = mlp_macro(sw, rd, LA, LB, LC, px, py, pz);
    }
    P.samp[idx] = res;
}

// =============== Kernel 2 (mid fallback): scattered gather from original grid ===============
template <typename T>
__global__ __launch_bounds__(BLK, 3)
void sample_k(KParams<T> P) {
    if (*P.flag != P.want) return;
    __shared__ float sw[SW2_FLOATS];
    const int tid = threadIdx.x;
    stage_all(sw, P, tid);
    __syncthreads();

    const int idx = blockIdx.x * BLK + tid;
    const int ray = idx / NSAMP;
    const int s   = idx - ray * NSAMP;
    const float* rd = P.rayData + ray * RAYSTRIDE;
    const float tmin = rd[6], inv_nd = rd[7];
    const float it = fmaf(STEP_F * (float)s, inv_nd, tmin);
    const float px = fmaf(rd[3], it, rd[0]);
    const float py = fmaf(rd[4], it, rd[1]);
    const float pz = fmaf(rd[5], it, rd[2]);
    bool inb = (px >= -1.f) & (px <= 1.f) & (py >= -1.f) & (py <= 1.f)
             & (pz >= -1.f) & (pz <= 1.f);
    float4 res = make_float4(0.f, 0.f, 0.f, 0.f);
    if (inb) {
        float gx = (px + 1.f) * 79.5f;
        float gy = (py + 1.f) * 79.5f;
        float gz = (pz + 1.f) * 79.5f;
        float fx0 = floorf(gx), fy0 = floorf(gy), fz0 = floorf(gz);
        float frx = gx - fx0, fry = gy - fy0, frz = gz - fz0;
        int x0 = min(max((int)fx0, 0), RESI-1); int x1 = min(x0+1, RESI-1);
        int y0 = min(max((int)fy0, 0), RESI-1); int y1 = min(y0+1, RESI-1);
        int z0 = min(max((int)fz0, 0), RESI-1); int z1 = min(z0+1, RESI-1);
        int bx0 = x0*R2I, bx1 = x1*R2I, by0 = y0*RESI, by1 = y1*RESI;
        int o000 = bx0+by0+z0, o001 = bx0+by0+z1, o010 = bx0+by1+z0, o011 = bx0+by1+z1;
        int o100 = bx1+by0+z0, o101 = bx1+by0+z1, o110 = bx1+by1+z0, o111 = bx1+by1+z1;
        float wx0 = 1.f-frx, wy0 = 1.f-fry, wz0 = 1.f-frz;
        float w000 = wx0*wy0*wz0, w001 = wx0*wy0*frz, w010 = wx0*fry*wz0, w011 = wx0*fry*frz;
        float w100 = frx*wy0*wz0, w101 = frx*wy0*frz, w110 = frx*fry*wz0, w111 = frx*fry*frz;
        float lat[12];
        #pragma unroll
        for (int c = 0; c < 12; ++c) {
            const T* g = P.grid + c*R3I;
            lat[c] = w000*ldv<T>(g,o000) + w001*ldv<T>(g,o001)
                   + w010*ldv<T>(g,o010) + w011*ldv<T>(g,o011)
                   + w100*ldv<T>(g,o100) + w101*ldv<T>(g,o101)
                   + w110*ldv<T>(g,o110) + w111*ldv<T>(g,o111);
        }
        float4 LA = make_float4(lat[0], lat[1], lat[2],  lat[3]);
        float4 LB = make_float4(lat[4], lat[5], lat[6],  lat[7]);
        float4 LC = make_float4(lat[8], lat[9], lat[10], lat[11]);
        res = mlp_macro(sw, rd, LA, LB, LC, px, py, pz);
    }
    P.samp[idx] = res;
}

// =============== Kernel 3: per-ray composite (one wave per ray) ===============
template <typename T>
__global__ __launch_bounds__(64)
void composite_k(KParams<T> P) {
    if (*P.flag != P.want) return;
    const int ray = blockIdx.x;
    const int lane = threadIdx.x;
    const float base_depth = P.rayData[ray * RAYSTRIDE + 24];
    const float4* sp = P.samp + ray * NSAMP;
    float lp = 1.f, cr = 0.f, cg = 0.f, cb = 0.f, cd = 0.f, ca = 0.f;
    #pragma unroll
    for (int k = 0; k < 9; ++k) {
        int s = lane * 9 + k;
        if (s < NSAMP) {
            float4 sm = sp[s];
            float w = sm.x * lp;
            cr += w * sm.y;
            cg += w * sm.z;
            cb += w * sm.w;
            cd += w * (base_depth + STEP_F * (float)s);
            ca += w;
            lp *= fmaxf(1.f - sm.x, 1e-10f);
        }
    }
    float pincl = lp;
    #pragma unroll
    for (int off = 1; off < 64; off <<= 1) {
        float v = __shfl_up(pincl, off, 64);
        if (lane >= off) pincl *= v;
    }
    float Tf = __shfl(pincl, 63, 64);
    float excl = __shfl_up(pincl, 1, 64);
    if (lane == 0) excl = 1.f;
    cr *= excl; cg *= excl; cb *= excl; cd *= excl; ca *= excl;
    #pragma unroll
    for (int off = 32; off > 0; off >>= 1) {
        cr += __shfl_down(cr, off, 64);
        cg += __shfl_down(cg, off, 64);
        cb += __shfl_down(cb, off, 64);
        cd += __shfl_down(cd, off, 64);
        ca += __shfl_down(ca, off, 64);
    }
    if (lane == 0) {
        float depth_m = cd + Tf * 3.5f;
        T* o = P.out + ray*6;
        o[0] = cvt_out<T>(cr + Tf);
        o[1] = cvt_out<T>(cg + Tf);
        o[2] = cvt_out<T>(cb + Tf);
        o[3] = cvt_out<T>(depth_m);
        o[4] = cvt_out<T>(1.f / depth_m);
        o[5] = cvt_out<T>(ca);
    }
}

template <typename T>
static void fill_params(KParams<T>& P, void* const* d_in, void* d_out, void* d_ws, int want) {
    P.rays_o   = (const T*)d_in[0];
    P.rays_d   = (const T*)d_in[1];
    P.viewdirs = (const T*)d_in[2];
    P.grid     = (const T*)d_in[3];
    P.aw1 = (const T*)d_in[4];  P.ab1 = (const T*)d_in[5];
    P.aw2 = (const T*)d_in[6];  P.ab2 = (const T*)d_in[7];
    P.aw3 = (const T*)d_in[8];  P.ab3 = (const T*)d_in[9];
    P.pw1 = (const T*)d_in[10]; P.pb1 = (const T*)d_in[11];
    P.pw2 = (const T*)d_in[12]; P.pb2 = (const T*)d_in[13];
    P.pw3 = (const T*)d_in[14]; P.pb3 = (const T*)d_in[15];
    P.dw1 = (const T*)d_in[16]; P.db1 = (const T*)d_in[17];
    P.dw2 = (const T*)d_in[18]; P.db2 = (const T*)d_in[19];
    P.dw3 = (const T*)d_in[20]; P.db3 = (const T*)d_in[21];
    P.dw4 = (const T*)d_in[22]; P.db4 = (const T*)d_in[23];
    P.out = (T*)d_out;
    P.flag = (const int*)d_ws;
    P.rayData = (float*)((char*)d_ws + RAYDATA_OFF);
    P.samp = (float4*)((char*)d_ws + SAMP_OFF);
    P.tgrid = (unsigned short*)((char*)d_ws + TG_OFF);
    P.lat = (float4*)((char*)d_ws + LAT_OFF);
    P.want = want;
}

extern "C" void kernel_launch(void* const* d_in, const int* in_sizes, int n_in,
                              void* d_out, int out_size, void* d_ws, size_t ws_size,
                              hipStream_t stream) {
    int* flag = (int*)d_ws;
    hipLaunchKernelGGL(detect_dtype, dim3(1), dim3(64), 0, stream, d_in[2], flag);

    KParams<float> Pf;
    fill_params<float>(Pf, d_in, d_out, d_ws, 0);
    KParams<__hip_bfloat16> Pb;
    fill_params<__hip_bfloat16>(Pb, d_in, d_out, d_ws, 1);

    hipLaunchKernelGGL(prep_k<float>, dim3((NRAYS + BLK - 1)/BLK), dim3(BLK), 0, stream, Pf);
    hipLaunchKernelGGL(prep_k<__hip_bfloat16>, dim3((NRAYS + BLK - 1)/BLK), dim3(BLK), 0, stream, Pb);

    if (ws_size >= WS_SPLIT) {
        hipLaunchKernelGGL(transpose_k<float>, dim3(TG_BLOCKS), dim3(BLK), 0, stream, Pf);
        hipLaunchKernelGGL(transpose_k<__hip_bfloat16>, dim3(TG_BLOCKS), dim3(BLK), 0, stream, Pb);
        hipLaunchKernelGGL(gather_tg_k<float>, dim3(SAMP_BLOCKS), dim3(BLK), 0, stream, Pf);
        hipLaunchKernelGGL(gather_tg_k<__hip_bfloat16>, dim3(SAMP_BLOCKS), dim3(BLK), 0, stream, Pb);
        hipLaunchKernelGGL(mlp2_k<float>, dim3(MLP2_BLOCKS), dim3(BLK), 0, stream, Pf);
        hipLaunchKernelGGL(mlp2_k<__hip_bfloat16>, dim3(MLP2_BLOCKS), dim3(BLK), 0, stream, Pb);
    } else if (ws_size >= WS_BIG) {
        hipLaunchKernelGGL(transpose_k<float>, dim3(TG_BLOCKS), dim3(BLK), 0, stream, Pf);
        hipLaunchKernelGGL(transpose_k<__hip_bfloat16>, dim3(TG_BLOCKS), dim3(BLK), 0, stream, Pb);
        hipLaunchKernelGGL(sample_tg_k<float>, dim3(SAMP_BLOCKS), dim3(BLK), 0, stream, Pf);
        hipLaunchKernelGGL(sample_tg_k<__hip_bfloat16>, dim3(SAMP_BLOCKS), dim3(BLK), 0, stream, Pb);
    } else {
        hipLaunchKernelGGL(sample_k<float>, dim3(SAMP_BLOCKS), dim3(BLK), 0, stream, Pf);
        hipLaunchKernelGGL(sample_k<__hip_bfloat16>, dim3(SAMP_BLOCKS), dim3(BLK), 0, stream, Pb);
    }
    hipLaunchKernelGGL(composite_k<float>, dim3(NRAYS), dim3(64), 0, stream, Pf);
    hipLaunchKernelGGL(composite_k<__hip_bfloat16>, dim3(NRAYS), dim3(64), 0, stream, Pb);
}

// Round 4
// 2247.518 us; speedup vs baseline: 1.1623x; 1.1623x over previous
//
#include <hip/hip_runtime.h>
#include <hip/hip_bf16.h>

#define BLK   256
#define NSAMP 558
#define NRAYS 2048
#define RESI  160
#define R2I   25600
#define R3I   4096000
#define NTOT  (NRAYS * NSAMP)          // 1,142,784
#define SAMP_BLOCKS (NTOT / BLK)       // 4464 exact
#define RAYSTRIDE 32
#define NVOX  4096000                  // 160^3
#define TG_BLOCKS (NVOX / BLK)         // 16000 exact
#define TPR2  279                      // threads per ray at K=2 (558/2)
#define HALF_RAYS 1024
#define MLP1H_BLOCKS (HALF_RAYS * NSAMP / BLK)   // 2232 exact
#define MLP2H_BLOCKS (HALF_RAYS * TPR2 / BLK)    // 1116 exact

#define ACT_SHIFT_F (-4.5951198501345896f)
#define STEP_F 0.00625f   // STEPSIZE * VOXEL

// ---------------- ws layout ----------------
#define RAYDATA_OFF 256
#define SAMP_OFF    (RAYDATA_OFF + NRAYS * RAYSTRIDE * 4)
#define TG_OFF      (SAMP_OFF + (size_t)NTOT * 16)
#define WS_BIG      (TG_OFF + (size_t)NVOX * 32)
#define LAT_OFF     WS_BIG
#define WS_SPLIT    (LAT_OFF + (size_t)NTOT * 48)

template <typename T> __device__ __forceinline__ float ldv(const T* p, int i);
template <> __device__ __forceinline__ float ldv<float>(const float* p, int i) { return p[i]; }
template <> __device__ __forceinline__ float ldv<__hip_bfloat16>(const __hip_bfloat16* p, int i) {
    return __bfloat162float(p[i]);
}
template <typename T> __device__ __forceinline__ T cvt_out(float v);
template <> __device__ __forceinline__ float cvt_out<float>(float v) { return v; }
template <> __device__ __forceinline__ __hip_bfloat16 cvt_out<__hip_bfloat16>(float v) {
    return __float2bfloat16(v);
}
__device__ __forceinline__ float b2f(unsigned short u) {
    union { float f; unsigned int i; } c; c.i = ((unsigned int)u) << 16; return c.f;
}
__device__ __forceinline__ float blo(unsigned int u) {
    union { float f; unsigned int i; } c; c.i = u << 16; return c.f;
}
__device__ __forceinline__ float bhi(unsigned int u) {
    union { float f; unsigned int i; } c; c.i = u & 0xffff0000u; return c.f;
}
__device__ __forceinline__ unsigned short f2b(float v) {
    __hip_bfloat16 h = __float2bfloat16(v);
    unsigned short u;
    __builtin_memcpy(&u, &h, sizeof(u));
    return u;
}

template <typename T>
struct KParams {
    const T *rays_o, *rays_d, *viewdirs, *grid;
    const T *aw1,*ab1,*aw2,*ab2,*aw3,*ab3;
    const T *pw1,*pb1,*pw2,*pb2,*pw3,*pb3;
    const T *dw1,*db1,*dw2,*db2,*dw3,*db3,*dw4,*db4;
    T *out;
    const int* flag;
    float* rayData;
    float4* samp;
    unsigned short* tgrid;
    float4* lat;     // [3*NTOT]: A=lat[idx], B=lat[NTOT+idx], C=lat[2*NTOT+idx]
    int want;
};

// ---- dtype detector ----
__global__ void detect_dtype(const void* vd, int* flag) {
    if (threadIdx.x == 0 && blockIdx.x == 0) {
        const float* f = (const float*)vd;
        const __hip_bfloat16* h = (const __hip_bfloat16*)vd;
        float sf = 0.f, sb = 0.f;
        for (int r = 0; r < 8; ++r) {
            float a = f[r*3], b = f[r*3+1], c = f[r*3+2];
            float d = (a*a + b*b + c*c) - 1.f;
            sf += d*d;
            float a2 = __bfloat162float(h[r*3]);
            float b2 = __bfloat162float(h[r*3+1]);
            float c2 = __bfloat162float(h[r*3+2]);
            float d2 = (a2*a2 + b2*b2 + c2*c2) - 1.f;
            sb += d2*d2;
        }
        bool sf_ok = (sf == sf) && (sf < 1e30f);
        bool sb_ok = (sb == sb) && (sb < 1e30f);
        int fl = 0;
        if (sb_ok && (!sf_ok || sb < sf)) fl = 1;
        *flag = fl;
    }
}

// =============== Transpose: (12, X, Y, Z) -> voxel-major [X][Y][Z][16ch] bf16 ===============
template <typename T>
__global__ __launch_bounds__(BLK)
void transpose_k(KParams<T> P) {
    if (*P.flag != P.want) return;
    const int i = blockIdx.x * BLK + threadIdx.x;
    unsigned short r[16];
    #pragma unroll
    for (int c = 0; c < 12; ++c) r[c] = f2b(ldv<T>(P.grid, c * R3I + i));
    #pragma unroll
    for (int c = 12; c < 16; ++c) r[c] = 0;
    uint4* dst = (uint4*)(P.tgrid + (size_t)i * 16);
    uint4 w0, w1;
    w0.x = (unsigned int)r[0] | ((unsigned int)r[1] << 16);
    w0.y = (unsigned int)r[2] | ((unsigned int)r[3] << 16);
    w0.z = (unsigned int)r[4] | ((unsigned int)r[5] << 16);
    w0.w = (unsigned int)r[6] | ((unsigned int)r[7] << 16);
    w1.x = (unsigned int)r[8] | ((unsigned int)r[9] << 16);
    w1.y = (unsigned int)r[10] | ((unsigned int)r[11] << 16);
    w1.z = 0; w1.w = 0;
    dst[0] = w0; dst[1] = w1;
}

// =============== Kernel 1: per-ray prep ===============
template <typename T>
__global__ __launch_bounds__(BLK)
void prep_k(KParams<T> P) {
    if (*P.flag != P.want) return;
    __shared__ float semb[BLK * 39];
    const int tid = threadIdx.x;
    const int ray = blockIdx.x * BLK + tid;
    if (ray >= NRAYS) return;
    const float ox = ldv<T>(P.rays_o, ray*3+0);
    const float oy = ldv<T>(P.rays_o, ray*3+1);
    const float oz = ldv<T>(P.rays_o, ray*3+2);
    const float dx = ldv<T>(P.rays_d, ray*3+0);
    const float dy = ldv<T>(P.rays_d, ray*3+1);
    const float dz = ldv<T>(P.rays_d, ray*3+2);
    const float vx = (dx == 0.f) ? 1e-6f : dx;
    const float vy = (dy == 0.f) ? 1e-6f : dy;
    const float vz = (dz == 0.f) ? 1e-6f : dz;
    const float rax = (1.f - ox) / vx, rbx = (-1.f - ox) / vx;
    const float ray_ = (1.f - oy) / vy, rby = (-1.f - oy) / vy;
    const float raz = (1.f - oz) / vz, rbz = (-1.f - oz) / vz;
    float tmin = fmaxf(fmaxf(fminf(rax, rbx), fminf(ray_, rby)), fminf(raz, rbz));
    float tmax = fminf(fminf(fmaxf(rax, rbx), fmaxf(ray_, rby)), fmaxf(raz, rbz));
    tmin = fminf(fmaxf(tmin, 0.05f), 3.5f);
    tmax = fminf(fmaxf(tmax, 0.05f), 3.5f);
    const bool mask_ray = (tmax <= tmin);
    const float norm_d = sqrtf(dx*dx + dy*dy + dz*dz);
    const float inv_nd = 1.f / norm_d;
    {
        float v0 = ldv<T>(P.viewdirs, ray*3+0);
        float v1 = ldv<T>(P.viewdirs, ray*3+1);
        float v2 = ldv<T>(P.viewdirs, ray*3+2);
        float* e = semb + tid*39;
        e[0] = v0; e[1] = v1; e[2] = v2;
        #pragma unroll
        for (int l = 0; l < 6; ++l) {
            float f = (float)(1 << l);
            e[3 + l*6 + 0] = __sinf(v0*f);
            e[3 + l*6 + 1] = __sinf(v1*f);
            e[3 + l*6 + 2] = __sinf(v2*f);
            e[3 + l*6 + 3] = __cosf(v0*f);
            e[3 + l*6 + 4] = __cosf(v1*f);
            e[3 + l*6 + 5] = __cosf(v2*f);
        }
    }
    float acc[16];
    #pragma unroll
    for (int j = 0; j < 16; ++j) acc[j] = ldv<T>(P.db1, j);
    const float* e = semb + tid*39;
    for (int i = 0; i < 39; ++i) {
        float xi = e[i];
        #pragma unroll
        for (int j = 0; j < 16; ++j) acc[j] = fmaf(xi, ldv<T>(P.dw1, (15+i)*16 + j), acc[j]);
    }
    float* rd = P.rayData + ray * RAYSTRIDE;
    rd[0] = ox; rd[1] = oy; rd[2] = oz;
    rd[3] = dx; rd[4] = dy; rd[5] = dz;
    rd[6] = mask_ray ? __int_as_float(0x7fc00000) : tmin;
    rd[7] = inv_nd;
    #pragma unroll
    for (int j = 0; j < 16; ++j) rd[8 + j] = acc[j];
    rd[24] = tmin * norm_d;
}

// =============== shared LDS weight layout for sample kernels ===============
#define AW1_O 0
#define AB1_O 480
#define AW2_O 512
#define AB2_O 1536
#define AW3_O 1568
#define AB3_O 1696
#define PW1_O 1700
#define PB1_O 1892
#define PW2_O 1908
#define PB2_O 2164
#define PW3_O 2180
#define PB3_O 2436
#define DW1_O 2452   /* rows 0..14 only: 240 */
#define DW2_O 2692
#define DB2_O 2948
#define DW3_O 2964
#define DB3_O 3220
#define DW4_O 3236   /* PADDED: 16 rows x 4 floats (col 3 = 0) */
#define DB4_O 3300   /* PADDED: 4 floats (last = 0) */
#define SW2_FLOATS 3304

template <typename T>
__device__ __forceinline__ void stage_w(float* dst, const T* src, int n, int tid) {
    for (int i = tid; i < n; i += BLK) dst[i] = ldv<T>(src, i);
}

template <typename T>
__device__ __forceinline__ void stage_all(float* sw, const KParams<T>& P, int tid) {
    stage_w(sw + AW1_O, P.aw1, 480, tid);
    stage_w(sw + AB1_O, P.ab1, 32, tid);
    stage_w(sw + AW2_O, P.aw2, 1024, tid);
    stage_w(sw + AB2_O, P.ab2, 32, tid);
    stage_w(sw + AW3_O, P.aw3, 128, tid);
    stage_w(sw + AB3_O, P.ab3, 4, tid);
    stage_w(sw + PW1_O, P.pw1, 192, tid);
    stage_w(sw + PB1_O, P.pb1, 16, tid);
    stage_w(sw + PW2_O, P.pw2, 256, tid);
    stage_w(sw + PB2_O, P.pb2, 16, tid);
    stage_w(sw + PW3_O, P.pw3, 256, tid);
    stage_w(sw + PB3_O, P.pb3, 16, tid);
    stage_w(sw + DW1_O, P.dw1, 240, tid);
    stage_w(sw + DW2_O, P.dw2, 256, tid);
    stage_w(sw + DB2_O, P.db2, 16, tid);
    stage_w(sw + DW3_O, P.dw3, 256, tid);
    stage_w(sw + DB3_O, P.db3, 16, tid);
    for (int i = tid; i < 64; i += BLK) {
        int r = i >> 2, c = i & 3;
        sw[DW4_O + i] = (c < 3) ? ldv<T>(P.dw4, r*3 + c) : 0.f;
    }
    if (tid < 4) sw[DB4_O + tid] = (tid < 3) ? ldv<T>(P.db4, tid) : 0.f;
}

// ---- register-resident float4 helpers ----
__device__ __forceinline__ float4 lds4(const float* p) { return *(const float4*)p; }
__device__ __forceinline__ void fma4(float4& a, float s, float4 w) {
    a.x = fmaf(s, w.x, a.x); a.y = fmaf(s, w.y, a.y);
    a.z = fmaf(s, w.z, a.z); a.w = fmaf(s, w.w, a.w);
}
__device__ __forceinline__ void relu4(float4& a) {
    a.x = fmaxf(a.x, 0.f); a.y = fmaxf(a.y, 0.f);
    a.z = fmaxf(a.z, 0.f); a.w = fmaxf(a.w, 0.f);
}

// ================= SINGLE-SAMPLE MLP (true K=1 implementation) =================
__device__ __forceinline__ float4 mlp_macro1(const float* sw, const float* rd,
                                             float4 A, float4 B, float4 C,
                                             float px, float py, float pz) {
    float4 q0 = lds4(sw+AB1_O+0),  q1 = lds4(sw+AB1_O+4),
           q2 = lds4(sw+AB1_O+8),  q3 = lds4(sw+AB1_O+12),
           q4 = lds4(sw+AB1_O+16), q5 = lds4(sw+AB1_O+20),
           q6 = lds4(sw+AB1_O+24), q7 = lds4(sw+AB1_O+28);
#define L1ROW(i, s_) { const float* W_ = sw + AW1_O + (i)*32; const float s = (s_); \
    fma4(q0,s,lds4(W_+0));  fma4(q1,s,lds4(W_+4));  fma4(q2,s,lds4(W_+8));  fma4(q3,s,lds4(W_+12)); \
    fma4(q4,s,lds4(W_+16)); fma4(q5,s,lds4(W_+20)); fma4(q6,s,lds4(W_+24)); fma4(q7,s,lds4(W_+28)); }
    L1ROW(0,pz) L1ROW(1,py) L1ROW(2,px)
    L1ROW(3,A.x) L1ROW(4,A.y) L1ROW(5,A.z) L1ROW(6,A.w)
    L1ROW(7,B.x) L1ROW(8,B.y) L1ROW(9,B.z) L1ROW(10,B.w)
    L1ROW(11,C.x) L1ROW(12,C.y) L1ROW(13,C.z) L1ROW(14,C.w)
#undef L1ROW
    relu4(q0); relu4(q1); relu4(q2); relu4(q3);
    relu4(q4); relu4(q5); relu4(q6); relu4(q7);
    float4 lg = lds4(sw+AB3_O);
#define A2ROW(c,i,s_) { const float* W_ = sw + AW2_O + (i)*32 + (c)*8; const float s = (s_); \
    fma4(t0,s,lds4(W_)); fma4(t1,s,lds4(W_+4)); }
#define A2Q(c,i0,qv) A2ROW(c,(i0)+0,qv.x) A2ROW(c,(i0)+1,qv.y) A2ROW(c,(i0)+2,qv.z) A2ROW(c,(i0)+3,qv.w)
#define A3F(c,j,t_) { const float s = fmaxf((t_),0.f); fma4(lg,s,lds4(sw + AW3_O + ((c)*8+(j))*4)); }
#define ABLK(c) { float4 t0 = lds4(sw+AB2_O+(c)*8); float4 t1 = lds4(sw+AB2_O+(c)*8+4); \
    A2Q(c,0,q0) A2Q(c,4,q1) A2Q(c,8,q2) A2Q(c,12,q3) \
    A2Q(c,16,q4) A2Q(c,20,q5) A2Q(c,24,q6) A2Q(c,28,q7) \
    A3F(c,0,t0.x) A3F(c,1,t0.y) A3F(c,2,t0.z) A3F(c,3,t0.w) \
    A3F(c,4,t1.x) A3F(c,5,t1.y) A3F(c,6,t1.z) A3F(c,7,t1.w) }
    ABLK(0) ABLK(1) ABLK(2) ABLK(3)
#undef ABLK
#undef A3F
#undef A2Q
#undef A2ROW
    float m = fmaxf(fmaxf(lg.x,lg.y), fmaxf(lg.z,lg.w));
    float e0 = __expf(lg.x-m), e1 = __expf(lg.y-m), e2 = __expf(lg.z-m), e3 = __expf(lg.w-m);
    float att1 = e1 / (e0+e1+e2+e3);
#define R16(i, s_, BASE, r0,r1,r2,r3) { const float* W_ = sw + (BASE) + (i)*16; const float s = (s_); \
    fma4(r0,s,lds4(W_)); fma4(r1,s,lds4(W_+4)); fma4(r2,s,lds4(W_+8)); fma4(r3,s,lds4(W_+12)); }
#define R16Q(i0, qv, BASE, r0,r1,r2,r3) \
    R16((i0)+0,qv.x,BASE,r0,r1,r2,r3) R16((i0)+1,qv.y,BASE,r0,r1,r2,r3) \
    R16((i0)+2,qv.z,BASE,r0,r1,r2,r3) R16((i0)+3,qv.w,BASE,r0,r1,r2,r3)
    float4 u0 = lds4(sw+PB1_O), u1 = lds4(sw+PB1_O+4), u2 = lds4(sw+PB1_O+8), u3 = lds4(sw+PB1_O+12);
    R16Q(0,A,PW1_O,u0,u1,u2,u3) R16Q(4,B,PW1_O,u0,u1,u2,u3) R16Q(8,C,PW1_O,u0,u1,u2,u3)
    relu4(u0); relu4(u1); relu4(u2); relu4(u3);
    float4 v0 = lds4(sw+PB2_O), v1 = lds4(sw+PB2_O+4), v2 = lds4(sw+PB2_O+8), v3 = lds4(sw+PB2_O+12);
    R16Q(0,u0,PW2_O,v0,v1,v2,v3) R16Q(4,u1,PW2_O,v0,v1,v2,v3)
    R16Q(8,u2,PW2_O,v0,v1,v2,v3) R16Q(12,u3,PW2_O,v0,v1,v2,v3)
    relu4(v0); relu4(v1); relu4(v2); relu4(v3);
    float4 o0 = lds4(sw+PB3_O), o1 = lds4(sw+PB3_O+4), o2 = lds4(sw+PB3_O+8), o3 = lds4(sw+PB3_O+12);
    R16Q(0,v0,PW3_O,o0,o1,o2,o3) R16Q(4,v1,PW3_O,o0,o1,o2,o3)
    R16Q(8,v2,PW3_O,o0,o1,o2,o3) R16Q(12,v3,PW3_O,o0,o1,o2,o3)
    const float4* rdv = (const float4*)(rd + 8);
    float4 d0 = rdv[0], d1 = rdv[1], d2 = rdv[2], d3 = rdv[3];
    R16(0,o0.y,DW1_O,d0,d1,d2,d3) R16(1,o0.z,DW1_O,d0,d1,d2,d3) R16(2,o0.w,DW1_O,d0,d1,d2,d3)
    R16Q(3,o1,DW1_O,d0,d1,d2,d3) R16Q(7,o2,DW1_O,d0,d1,d2,d3) R16Q(11,o3,DW1_O,d0,d1,d2,d3)
    relu4(d0); relu4(d1); relu4(d2); relu4(d3);
    float4 g0 = lds4(sw+DB2_O), g1 = lds4(sw+DB2_O+4), g2 = lds4(sw+DB2_O+8), g3 = lds4(sw+DB2_O+12);
    R16Q(0,d0,DW2_O,g0,g1,g2,g3) R16Q(4,d1,DW2_O,g0,g1,g2,g3)
    R16Q(8,d2,DW2_O,g0,g1,g2,g3) R16Q(12,d3,DW2_O,g0,g1,g2,g3)
    relu4(g0); relu4(g1); relu4(g2); relu4(g3);
    float4 h0 = lds4(sw+DB3_O), h1 = lds4(sw+DB3_O+4), h2 = lds4(sw+DB3_O+8), h3 = lds4(sw+DB3_O+12);
    R16Q(0,g0,DW3_O,h0,h1,h2,h3) R16Q(4,g1,DW3_O,h0,h1,h2,h3)
    R16Q(8,g2,DW3_O,h0,h1,h2,h3) R16Q(12,g3,DW3_O,h0,h1,h2,h3)
    relu4(h0); relu4(h1); relu4(h2); relu4(h3);
    float4 rr = lds4(sw+DB4_O);
#define R4(i, s_) { fma4(rr,(s_),lds4(sw + DW4_O + (i)*4)); }
    R4(0,h0.x) R4(1,h0.y) R4(2,h0.z) R4(3,h0.w)
    R4(4,h1.x) R4(5,h1.y) R4(6,h1.z) R4(7,h1.w)
    R4(8,h2.x) R4(9,h2.y) R4(10,h2.z) R4(11,h2.w)
    R4(12,h3.x) R4(13,h3.y) R4(14,h3.z) R4(15,h3.w)
#undef R4
#undef R16Q
#undef R16
    float dens = att1 * o0.x;
    float xsh = dens + ACT_SHIFT_F;
    float sp = (xsh > 0.f) ? xsh + log1pf(__expf(-xsh)) : log1pf(__expf(xsh));
    float4 res;
    res.x = 1.f - __expf(-sp * 0.5f);
    res.y = 1.f / (1.f + __expf(-att1 * rr.x));
    res.z = 1.f / (1.f + __expf(-att1 * rr.y));
    res.w = 1.f / (1.f + __expf(-att1 * rr.z));
    return res;
}

// ================= PAIRED MLP (K=2; each LDS load feeds 2 samples) =================
__device__ __forceinline__ void mlp_macro2(const float* sw, const float* rd,
        float4 A0, float4 B0, float4 C0, float4 A1, float4 B1, float4 C1,
        float px0, float py0, float pz0, float px1, float py1, float pz1,
        float4& res0, float4& res1) {
    float4 qa0 = lds4(sw+AB1_O+0),  qa1 = lds4(sw+AB1_O+4),
           qa2 = lds4(sw+AB1_O+8),  qa3 = lds4(sw+AB1_O+12),
           qa4 = lds4(sw+AB1_O+16), qa5 = lds4(sw+AB1_O+20),
           qa6 = lds4(sw+AB1_O+24), qa7 = lds4(sw+AB1_O+28);
    float4 qb0 = qa0, qb1 = qa1, qb2 = qa2, qb3 = qa3,
           qb4 = qa4, qb5 = qa5, qb6 = qa6, qb7 = qa7;
#define PL1ROW(i, sa_, sb_) { const float* W_ = sw + AW1_O + (i)*32; const float sa=(sa_), sb=(sb_); \
    { const float4 w_=lds4(W_+0);  fma4(qa0,sa,w_); fma4(qb0,sb,w_); } \
    { const float4 w_=lds4(W_+4);  fma4(qa1,sa,w_); fma4(qb1,sb,w_); } \
    { const float4 w_=lds4(W_+8);  fma4(qa2,sa,w_); fma4(qb2,sb,w_); } \
    { const float4 w_=lds4(W_+12); fma4(qa3,sa,w_); fma4(qb3,sb,w_); } \
    { const float4 w_=lds4(W_+16); fma4(qa4,sa,w_); fma4(qb4,sb,w_); } \
    { const float4 w_=lds4(W_+20); fma4(qa5,sa,w_); fma4(qb5,sb,w_); } \
    { const float4 w_=lds4(W_+24); fma4(qa6,sa,w_); fma4(qb6,sb,w_); } \
    { const float4 w_=lds4(W_+28); fma4(qa7,sa,w_); fma4(qb7,sb,w_); } }
    PL1ROW(0,pz0,pz1) PL1ROW(1,py0,py1) PL1ROW(2,px0,px1)
    PL1ROW(3,A0.x,A1.x) PL1ROW(4,A0.y,A1.y) PL1ROW(5,A0.z,A1.z) PL1ROW(6,A0.w,A1.w)
    PL1ROW(7,B0.x,B1.x) PL1ROW(8,B0.y,B1.y) PL1ROW(9,B0.z,B1.z) PL1ROW(10,B0.w,B1.w)
    PL1ROW(11,C0.x,C1.x) PL1ROW(12,C0.y,C1.y) PL1ROW(13,C0.z,C1.z) PL1ROW(14,C0.w,C1.w)
#undef PL1ROW
    relu4(qa0); relu4(qa1); relu4(qa2); relu4(qa3);
    relu4(qa4); relu4(qa5); relu4(qa6); relu4(qa7);
    relu4(qb0); relu4(qb1); relu4(qb2); relu4(qb3);
    relu4(qb4); relu4(qb5); relu4(qb6); relu4(qb7);
    float4 lga = lds4(sw+AB3_O);
    float4 lgb = lga;
#define PA2ROW(c,i,sa_,sb_) { const float* W_ = sw + AW2_O + (i)*32 + (c)*8; \
    const float4 w0_=lds4(W_), w1_=lds4(W_+4); const float sa=(sa_), sb=(sb_); \
    fma4(ta0,sa,w0_); fma4(ta1,sa,w1_); fma4(tb0,sb,w0_); fma4(tb1,sb,w1_); }
#define PA2Q(c,i0,qva,qvb) PA2ROW(c,(i0)+0,qva.x,qvb.x) PA2ROW(c,(i0)+1,qva.y,qvb.y) \
                           PA2ROW(c,(i0)+2,qva.z,qvb.z) PA2ROW(c,(i0)+3,qva.w,qvb.w)
#define PA3F(c,j,ta_,tb_) { const float4 w_=lds4(sw + AW3_O + ((c)*8+(j))*4); \
    fma4(lga, fmaxf((ta_),0.f), w_); fma4(lgb, fmaxf((tb_),0.f), w_); }
#define PABLK(c) { float4 ta0 = lds4(sw+AB2_O+(c)*8); float4 ta1 = lds4(sw+AB2_O+(c)*8+4); \
    float4 tb0 = ta0, tb1 = ta1; \
    PA2Q(c,0,qa0,qb0) PA2Q(c,4,qa1,qb1) PA2Q(c,8,qa2,qb2) PA2Q(c,12,qa3,qb3) \
    PA2Q(c,16,qa4,qb4) PA2Q(c,20,qa5,qb5) PA2Q(c,24,qa6,qb6) PA2Q(c,28,qa7,qb7) \
    PA3F(c,0,ta0.x,tb0.x) PA3F(c,1,ta0.y,tb0.y) PA3F(c,2,ta0.z,tb0.z) PA3F(c,3,ta0.w,tb0.w) \
    PA3F(c,4,ta1.x,tb1.x) PA3F(c,5,ta1.y,tb1.y) PA3F(c,6,ta1.z,tb1.z) PA3F(c,7,ta1.w,tb1.w) }
    PABLK(0) PABLK(1) PABLK(2) PABLK(3)
#undef PABLK
#undef PA3F
#undef PA2Q
#undef PA2ROW
    float ma = fmaxf(fmaxf(lga.x,lga.y), fmaxf(lga.z,lga.w));
    float ea0 = __expf(lga.x-ma), ea1 = __expf(lga.y-ma), ea2 = __expf(lga.z-ma), ea3 = __expf(lga.w-ma);
    float att1a = ea1 / (ea0+ea1+ea2+ea3);
    float mb = fmaxf(fmaxf(lgb.x,lgb.y), fmaxf(lgb.z,lgb.w));
    float eb0 = __expf(lgb.x-mb), eb1 = __expf(lgb.y-mb), eb2 = __expf(lgb.z-mb), eb3 = __expf(lgb.w-mb);
    float att1b = eb1 / (eb0+eb1+eb2+eb3);
#define PR16(pre,i,sa_,sb_,BASE) { const float* W_ = sw + (BASE) + (i)*16; \
    const float4 w0_=lds4(W_), w1_=lds4(W_+4), w2_=lds4(W_+8), w3_=lds4(W_+12); \
    const float sa=(sa_), sb=(sb_); \
    fma4(pre##a0,sa,w0_); fma4(pre##a1,sa,w1_); fma4(pre##a2,sa,w2_); fma4(pre##a3,sa,w3_); \
    fma4(pre##b0,sb,w0_); fma4(pre##b1,sb,w1_); fma4(pre##b2,sb,w2_); fma4(pre##b3,sb,w3_); }
#define PR16Q(pre,i0,qva,qvb,BASE) PR16(pre,(i0)+0,qva.x,qvb.x,BASE) PR16(pre,(i0)+1,qva.y,qvb.y,BASE) \
                                   PR16(pre,(i0)+2,qva.z,qvb.z,BASE) PR16(pre,(i0)+3,qva.w,qvb.w,BASE)
    float4 ua0 = lds4(sw+PB1_O), ua1 = lds4(sw+PB1_O+4), ua2 = lds4(sw+PB1_O+8), ua3 = lds4(sw+PB1_O+12);
    float4 ub0 = ua0, ub1 = ua1, ub2 = ua2, ub3 = ua3;
    PR16Q(u,0,A0,A1,PW1_O) PR16Q(u,4,B0,B1,PW1_O) PR16Q(u,8,C0,C1,PW1_O)
    relu4(ua0); relu4(ua1); relu4(ua2); relu4(ua3);
    relu4(ub0); relu4(ub1); relu4(ub2); relu4(ub3);
    float4 va0 = lds4(sw+PB2_O), va1 = lds4(sw+PB2_O+4), va2 = lds4(sw+PB2_O+8), va3 = lds4(sw+PB2_O+12);
    float4 vb0 = va0, vb1 = va1, vb2 = va2, vb3 = va3;
    PR16Q(v,0,ua0,ub0,PW2_O) PR16Q(v,4,ua1,ub1,PW2_O)
    PR16Q(v,8,ua2,ub2,PW2_O) PR16Q(v,12,ua3,ub3,PW2_O)
    relu4(va0); relu4(va1); relu4(va2); relu4(va3);
    relu4(vb0); relu4(vb1); relu4(vb2); relu4(vb3);
    float4 oa0 = lds4(sw+PB3_O), oa1 = lds4(sw+PB3_O+4), oa2 = lds4(sw+PB3_O+8), oa3 = lds4(sw+PB3_O+12);
    float4 ob0 = oa0, ob1 = oa1, ob2 = oa2, ob3 = oa3;
    PR16Q(o,0,va0,vb0,PW3_O) PR16Q(o,4,va1,vb1,PW3_O)
    PR16Q(o,8,va2,vb2,PW3_O) PR16Q(o,12,va3,vb3,PW3_O)
    const float4* rdv = (const float4*)(rd + 8);
    float4 da0 = rdv[0], da1 = rdv[1], da2 = rdv[2], da3 = rdv[3];
    float4 db0 = da0, db1 = da1, db2 = da2, db3 = da3;
    PR16(d,0,oa0.y,ob0.y,DW1_O) PR16(d,1,oa0.z,ob0.z,DW1_O) PR16(d,2,oa0.w,ob0.w,DW1_O)
    PR16Q(d,3,oa1,ob1,DW1_O) PR16Q(d,7,oa2,ob2,DW1_O) PR16Q(d,11,oa3,ob3,DW1_O)
    relu4(da0); relu4(da1); relu4(da2); relu4(da3);
    relu4(db0); relu4(db1); relu4(db2); relu4(db3);
    float4 ga0 = lds4(sw+DB2_O), ga1 = lds4(sw+DB2_O+4), ga2 = lds4(sw+DB2_O+8), ga3 = lds4(sw+DB2_O+12);
    float4 gb0 = ga0, gb1 = ga1, gb2 = ga2, gb3 = ga3;
    PR16Q(g,0,da0,db0,DW2_O) PR16Q(g,4,da1,db1,DW2_O)
    PR16Q(g,8,da2,db2,DW2_O) PR16Q(g,12,da3,db3,DW2_O)
    relu4(ga0); relu4(ga1); relu4(ga2); relu4(ga3);
    relu4(gb0); relu4(gb1); relu4(gb2); relu4(gb3);
    float4 ha0 = lds4(sw+DB3_O), ha1 = lds4(sw+DB3_O+4), ha2 = lds4(sw+DB3_O+8), ha3 = lds4(sw+DB3_O+12);
    float4 hb0 = ha0, hb1 = ha1, hb2 = ha2, hb3 = ha3;
    PR16Q(h,0,ga0,gb0,DW3_O) PR16Q(h,4,ga1,gb1,DW3_O)
    PR16Q(h,8,ga2,gb2,DW3_O) PR16Q(h,12,ga3,gb3,DW3_O)
    relu4(ha0); relu4(ha1); relu4(ha2); relu4(ha3);
    relu4(hb0); relu4(hb1); relu4(hb2); relu4(hb3);
    float4 rra = lds4(sw+DB4_O);
    float4 rrb = rra;
#define PR4(i, sa_, sb_) { const float4 w_=lds4(sw + DW4_O + (i)*4); fma4(rra,(sa_),w_); fma4(rrb,(sb_),w_); }
    PR4(0,ha0.x,hb0.x) PR4(1,ha0.y,hb0.y) PR4(2,ha0.z,hb0.z) PR4(3,ha0.w,hb0.w)
    PR4(4,ha1.x,hb1.x) PR4(5,ha1.y,hb1.y) PR4(6,ha1.z,hb1.z) PR4(7,ha1.w,hb1.w)
    PR4(8,ha2.x,hb2.x) PR4(9,ha2.y,hb2.y) PR4(10,ha2.z,hb2.z) PR4(11,ha2.w,hb2.w)
    PR4(12,ha3.x,hb3.x) PR4(13,ha3.y,hb3.y) PR4(14,ha3.z,hb3.z) PR4(15,ha3.w,hb3.w)
#undef PR4
#undef PR16Q
#undef PR16
    {
        float dens = att1a * oa0.x;
        float xsh = dens + ACT_SHIFT_F;
        float sp = (xsh > 0.f) ? xsh + log1pf(__expf(-xsh)) : log1pf(__expf(xsh));
        res0.x = 1.f - __expf(-sp * 0.5f);
        res0.y = 1.f / (1.f + __expf(-att1a * rra.x));
        res0.z = 1.f / (1.f + __expf(-att1a * rra.y));
        res0.w = 1.f / (1.f + __expf(-att1a * rra.z));
    }
    {
        float dens = att1b * ob0.x;
        float xsh = dens + ACT_SHIFT_F;
        float sp = (xsh > 0.f) ? xsh + log1pf(__expf(-xsh)) : log1pf(__expf(xsh));
        res1.x = 1.f - __expf(-sp * 0.5f);
        res1.y = 1.f / (1.f + __expf(-att1b * rrb.x));
        res1.z = 1.f / (1.f + __expf(-att1b * rrb.y));
        res1.w = 1.f / (1.f + __expf(-att1b * rrb.z));
    }
}

// =============== SPLIT PATH kernel A: pure trilinear gather -> lat buffer ===============
template <typename T>
__global__ __launch_bounds__(BLK, 4)
void gather_tg_k(KParams<T> P) {
    if (*P.flag != P.want) return;
    const int idx = blockIdx.x * BLK + threadIdx.x;
    const int ray = idx / NSAMP;
    const int s   = idx - ray * NSAMP;
    const float* rd = P.rayData + ray * RAYSTRIDE;
    const float tmin = rd[6], inv_nd = rd[7];
    const float it = fmaf(STEP_F * (float)s, inv_nd, tmin);
    const float px = fmaf(rd[3], it, rd[0]);
    const float py = fmaf(rd[4], it, rd[1]);
    const float pz = fmaf(rd[5], it, rd[2]);
    bool inb = (px >= -1.f) & (px <= 1.f) & (py >= -1.f) & (py <= 1.f)
             & (pz >= -1.f) & (pz <= 1.f);
    if (!inb) return;
    float gx = (px + 1.f) * 79.5f;
    float gy = (py + 1.f) * 79.5f;
    float gz = (pz + 1.f) * 79.5f;
    float fx0 = floorf(gx), fy0 = floorf(gy), fz0 = floorf(gz);
    float frx = gx - fx0, fry = gy - fy0, frz = gz - fz0;
    int x0 = min(max((int)fx0, 0), RESI-1); int x1 = min(x0+1, RESI-1);
    int y0 = min(max((int)fy0, 0), RESI-1); int y1 = min(y0+1, RESI-1);
    int z0 = min(max((int)fz0, 0), RESI-1); int z1 = min(z0+1, RESI-1);
    int bx0 = x0*R2I, bx1 = x1*R2I, by0 = y0*RESI, by1 = y1*RESI;
    float wx0 = 1.f-frx, wy0 = 1.f-fry, wz0 = 1.f-frz;
    float4 LA = make_float4(0.f,0.f,0.f,0.f);
    float4 LB = make_float4(0.f,0.f,0.f,0.f);
    float4 LC = make_float4(0.f,0.f,0.f,0.f);
#define CORNER(OFF, W_) { const unsigned short* vp = P.tgrid + (OFF)*16; \
    uint4 a_ = *(const uint4*)vp; uint2 b_ = *(const uint2*)(vp + 8); const float w = (W_); \
    LA.x = fmaf(w, blo(a_.x), LA.x); LA.y = fmaf(w, bhi(a_.x), LA.y); \
    LA.z = fmaf(w, blo(a_.y), LA.z); LA.w = fmaf(w, bhi(a_.y), LA.w); \
    LB.x = fmaf(w, blo(a_.z), LB.x); LB.y = fmaf(w, bhi(a_.z), LB.y); \
    LB.z = fmaf(w, blo(a_.w), LB.z); LB.w = fmaf(w, bhi(a_.w), LB.w); \
    LC.x = fmaf(w, blo(b_.x), LC.x); LC.y = fmaf(w, bhi(b_.x), LC.y); \
    LC.z = fmaf(w, blo(b_.y), LC.z); LC.w = fmaf(w, bhi(b_.y), LC.w); }
    CORNER(bx0+by0+z0, wx0*wy0*wz0)
    CORNER(bx0+by0+z1, wx0*wy0*frz)
    CORNER(bx0+by1+z0, wx0*fry*wz0)
    CORNER(bx0+by1+z1, wx0*fry*frz)
    CORNER(bx1+by0+z0, frx*wy0*wz0)
    CORNER(bx1+by0+z1, frx*wy0*frz)
    CORNER(bx1+by1+z0, frx*fry*wz0)
    CORNER(bx1+by1+z1, frx*fry*frz)
#undef CORNER
    P.lat[idx]          = LA;
    P.lat[NTOT + idx]   = LB;
    P.lat[2*NTOT + idx] = LC;
}

// =============== SPLIT PATH kernel B1: single-sample MLP over rays [0, 1024) ===============
template <typename T>
__global__ __launch_bounds__(BLK, 2)
void mlp1h_k(KParams<T> P) {
    if (*P.flag != P.want) return;
    __shared__ float sw[SW2_FLOATS];
    const int tid = threadIdx.x;
    stage_all(sw, P, tid);
    __syncthreads();

    const int idx = blockIdx.x * BLK + tid;      // 0 .. HALF_RAYS*NSAMP-1 (ray in [0,1024))
    const int ray = idx / NSAMP;
    const int s   = idx - ray * NSAMP;
    const float* rd = P.rayData + ray * RAYSTRIDE;
    const float tmin = rd[6], inv_nd = rd[7];
    const float it = fmaf(STEP_F * (float)s, inv_nd, tmin);
    const float px = fmaf(rd[3], it, rd[0]);
    const float py = fmaf(rd[4], it, rd[1]);
    const float pz = fmaf(rd[5], it, rd[2]);
    bool inb = (px >= -1.f) & (px <= 1.f) & (py >= -1.f) & (py <= 1.f)
             & (pz >= -1.f) & (pz <= 1.f);
    float4 res = make_float4(0.f, 0.f, 0.f, 0.f);
    if (inb) {
        float4 A = P.lat[idx];
        float4 B = P.lat[NTOT + idx];
        float4 C = P.lat[2*NTOT + idx];
        res = mlp_macro1(sw, rd, A, B, C, px, py, pz);
    }
    P.samp[idx] = res;
}

// =============== SPLIT PATH kernel B2: paired MLP over rays [1024, 2048) ===============
template <typename T>
__global__ __launch_bounds__(BLK, 2)
void mlp2h_k(KParams<T> P) {
    if (*P.flag != P.want) return;
    __shared__ float sw[SW2_FLOATS];
    const int tid = threadIdx.x;
    stage_all(sw, P, tid);
    __syncthreads();

    const int gid = blockIdx.x * BLK + tid;      // 0 .. HALF_RAYS*TPR2-1
    const int rl  = gid / TPR2;
    const int ray = HALF_RAYS + rl;
    const int s0  = 2 * (gid - rl * TPR2);
    const int idx0 = ray * NSAMP + s0;
    const float* rd = P.rayData + ray * RAYSTRIDE;
    const float tmin = rd[6], inv_nd = rd[7];
    const float it0 = fmaf(STEP_F * (float)s0, inv_nd, tmin);
    const float it1 = fmaf(STEP_F * (float)(s0+1), inv_nd, tmin);
    const float px0 = fmaf(rd[3], it0, rd[0]);
    const float py0 = fmaf(rd[4], it0, rd[1]);
    const float pz0 = fmaf(rd[5], it0, rd[2]);
    const float px1 = fmaf(rd[3], it1, rd[0]);
    const float py1 = fmaf(rd[4], it1, rd[1]);
    const float pz1 = fmaf(rd[5], it1, rd[2]);
    const bool inb0 = (px0 >= -1.f) & (px0 <= 1.f) & (py0 >= -1.f) & (py0 <= 1.f)
                    & (pz0 >= -1.f) & (pz0 <= 1.f);
    const bool inb1 = (px1 >= -1.f) & (px1 <= 1.f) & (py1 >= -1.f) & (py1 <= 1.f)
                    & (pz1 >= -1.f) & (pz1 <= 1.f);
    const float4 z = make_float4(0.f, 0.f, 0.f, 0.f);
    float4 r0 = z, r1 = z;
    if (inb0 | inb1) {
        float4 A0 = P.lat[idx0],        A1 = P.lat[idx0+1];
        float4 B0 = P.lat[NTOT+idx0],   B1 = P.lat[NTOT+idx0+1];
        float4 C0 = P.lat[2*NTOT+idx0], C1 = P.lat[2*NTOT+idx0+1];
        if (!inb0) { A0 = z; B0 = z; C0 = z; }
        if (!inb1) { A1 = z; B1 = z; C1 = z; }
        mlp_macro2(sw, rd, A0, B0, C0, A1, B1, C1,
                   px0, py0, pz0, px1, py1, pz1, r0, r1);
        if (!inb0) r0 = z;
        if (!inb1) r1 = z;
    }
    P.samp[idx0]   = r0;
    P.samp[idx0+1] = r1;
}

// =============== Kernel 2 (big path): fused gather + MLP, AoS transposed grid ===============
template <typename T>
__global__ __launch_bounds__(BLK, 3)
void sample_tg_k(KParams<T> P) {
    if (*P.flag != P.want) return;
    __shared__ float sw[SW2_FLOATS];
    const int tid = threadIdx.x;
    stage_all(sw, P, tid);
    __syncthreads();

    const int idx = blockIdx.x * BLK + tid;
    const int ray = idx / NSAMP;
    const int s   = idx - ray * NSAMP;
    const float* rd = P.rayData + ray * RAYSTRIDE;
    const float tmin = rd[6], inv_nd = rd[7];
    const float it = fmaf(STEP_F * (float)s, inv_nd, tmin);
    const float px = fmaf(rd[3], it, rd[0]);
    const float py = fmaf(rd[4], it, rd[1]);
    const float pz = fmaf(rd[5], it, rd[2]);
    bool inb = (px >= -1.f) & (px <= 1.f) & (py >= -1.f) & (py <= 1.f)
             & (pz >= -1.f) & (pz <= 1.f);
    float4 res = make_float4(0.f, 0.f, 0.f, 0.f);
    if (inb) {
        float gx = (px + 1.f) * 79.5f;
        float gy = (py + 1.f) * 79.5f;
        float gz = (pz + 1.f) * 79.5f;
        float fx0 = floorf(gx), fy0 = floorf(gy), fz0 = floorf(gz);
        float frx = gx - fx0, fry = gy - fy0, frz = gz - fz0;
        int x0 = min(max((int)fx0, 0), RESI-1); int x1 = min(x0+1, RESI-1);
        int y0 = min(max((int)fy0, 0), RESI-1); int y1 = min(y0+1, RESI-1);
        int z0 = min(max((int)fz0, 0), RESI-1); int z1 = min(z0+1, RESI-1);
        int bx0 = x0*R2I, bx1 = x1*R2I, by0 = y0*RESI, by1 = y1*RESI;
        float wx0 = 1.f-frx, wy0 = 1.f-fry, wz0 = 1.f-frz;
        float4 LA = make_float4(0.f,0.f,0.f,0.f);
        float4 LB = make_float4(0.f,0.f,0.f,0.f);
        float4 LC = make_float4(0.f,0.f,0.f,0.f);
#define CORNER(OFF, W_) { const unsigned short* vp = P.tgrid + (OFF)*16; \
        uint4 a_ = *(const uint4*)vp; uint2 b_ = *(const uint2*)(vp + 8); const float w = (W_); \
        LA.x = fmaf(w, blo(a_.x), LA.x); LA.y = fmaf(w, bhi(a_.x), LA.y); \
        LA.z = fmaf(w, blo(a_.y), LA.z); LA.w = fmaf(w, bhi(a_.y), LA.w); \
        LB.x = fmaf(w, blo(a_.z), LB.x); LB.y = fmaf(w, bhi(a_.z), LB.y); \
        LB.z = fmaf(w, blo(a_.w), LB.z); LB.w = fmaf(w, bhi(a_.w), LB.w); \
        LC.x = fmaf(w, blo(b_.x), LC.x); LC.y = fmaf(w, bhi(b_.x), LC.y); \
        LC.z = fmaf(w, blo(b_.y), LC.z); LC.w = fmaf(w, bhi(b_.y), LC.w); }
        CORNER(bx0+by0+z0, wx0*wy0*wz0)
        CORNER(bx0+by0+z1, wx0*wy0*frz)
        CORNER(bx0+by1+z0, wx0*fry*wz0)
        CORNER(bx0+by1+z1, wx0*fry*frz)
        CORNER(bx1+by0+z0, frx*wy0*wz0)
        CORNER(bx1+by0+z1, frx*wy0*frz)
        CORNER(bx1+by1+z0, frx*fry*wz0)
        CORNER(bx1+by1+z1, frx*fry*frz)
#undef CORNER
        res = mlp_macro1(sw, rd, LA, LB, LC, px, py, pz);
    }
    P.samp[idx] = res;
}

// =============== Kernel 2 (mid fallback): scattered gather from original grid ===============
template <typename T>
__global__ __launch_bounds__(BLK, 3)
void sample_k(KParams<T> P) {
    if (*P.flag != P.want) return;
    __shared__ float sw[SW2_FLOATS];
    const int tid = threadIdx.x;
    stage_all(sw, P, tid);
    __syncthreads();

    const int idx = blockIdx.x * BLK + tid;
    const int ray = idx / NSAMP;
    const int s   = idx - ray * NSAMP;
    const float* rd = P.rayData + ray * RAYSTRIDE;
    const float tmin = rd[6], inv_nd = rd[7];
    const float it = fmaf(STEP_F * (float)s, inv_nd, tmin);
    const float px = fmaf(rd[3], it, rd[0]);
    const float py = fmaf(rd[4], it, rd[1]);
    const float pz = fmaf(rd[5], it, rd[2]);
    bool inb = (px >= -1.f) & (px <= 1.f) & (py >= -1.f) & (py <= 1.f)
             & (pz >= -1.f) & (pz <= 1.f);
    float4 res = make_float4(0.f, 0.f, 0.f, 0.f);
    if (inb) {
        float gx = (px + 1.f) * 79.5f;
        float gy = (py + 1.f) * 79.5f;
        float gz = (pz + 1.f) * 79.5f;
        float fx0 = floorf(gx), fy0 = floorf(gy), fz0 = floorf(gz);
        float frx = gx - fx0, fry = gy - fy0, frz = gz - fz0;
        int x0 = min(max((int)fx0, 0), RESI-1); int x1 = min(x0+1, RESI-1);
        int y0 = min(max((int)fy0, 0), RESI-1); int y1 = min(y0+1, RESI-1);
        int z0 = min(max((int)fz0, 0), RESI-1); int z1 = min(z0+1, RESI-1);
        int bx0 = x0*R2I, bx1 = x1*R2I, by0 = y0*RESI, by1 = y1*RESI;
        int o000 = bx0+by0+z0, o001 = bx0+by0+z1, o010 = bx0+by1+z0, o011 = bx0+by1+z1;
        int o100 = bx1+by0+z0, o101 = bx1+by0+z1, o110 = bx1+by1+z0, o111 = bx1+by1+z1;
        float wx0 = 1.f-frx, wy0 = 1.f-fry, wz0 = 1.f-frz;
        float w000 = wx0*wy0*wz0, w001 = wx0*wy0*frz, w010 = wx0*fry*wz0, w011 = wx0*fry*frz;
        float w100 = frx*wy0*wz0, w101 = frx*wy0*frz, w110 = frx*fry*wz0, w111 = frx*fry*frz;
        float lat[12];
        #pragma unroll
        for (int c = 0; c < 12; ++c) {
            const T* g = P.grid + c*R3I;
            lat[c] = w000*ldv<T>(g,o000) + w001*ldv<T>(g,o001)
                   + w010*ldv<T>(g,o010) + w011*ldv<T>(g,o011)
                   + w100*ldv<T>(g,o100) + w101*ldv<T>(g,o101)
                   + w110*ldv<T>(g,o110) + w111*ldv<T>(g,o111);
        }
        float4 LA = make_float4(lat[0], lat[1], lat[2],  lat[3]);
        float4 LB = make_float4(lat[4], lat[5], lat[6],  lat[7]);
        float4 LC = make_float4(lat[8], lat[9], lat[10], lat[11]);
        res = mlp_macro1(sw, rd, LA, LB, LC, px, py, pz);
    }
    P.samp[idx] = res;
}

// =============== Kernel 3: per-ray composite (one wave per ray) ===============
template <typename T>
__global__ __launch_bounds__(64)
void composite_k(KParams<T> P) {
    if (*P.flag != P.want) return;
    const int ray = blockIdx.x;
    const int lane = threadIdx.x;
    const float base_depth = P.rayData[ray * RAYSTRIDE + 24];
    const float4* sp = P.samp + ray * NSAMP;
    float lp = 1.f, cr = 0.f, cg = 0.f, cb = 0.f, cd = 0.f, ca = 0.f;
    #pragma unroll
    for (int k = 0; k < 9; ++k) {
        int s = lane * 9 + k;
        if (s < NSAMP) {
            float4 sm = sp[s];
            float w = sm.x * lp;
            cr += w * sm.y;
            cg += w * sm.z;
            cb += w * sm.w;
            cd += w * (base_depth + STEP_F * (float)s);
            ca += w;
            lp *= fmaxf(1.f - sm.x, 1e-10f);
        }
    }
    float pincl = lp;
    #pragma unroll
    for (int off = 1; off < 64; off <<= 1) {
        float v = __shfl_up(pincl, off, 64);
        if (lane >= off) pincl *= v;
    }
    float Tf = __shfl(pincl, 63, 64);
    float excl = __shfl_up(pincl, 1, 64);
    if (lane == 0) excl = 1.f;
    cr *= excl; cg *= excl; cb *= excl; cd *= excl; ca *= excl;
    #pragma unroll
    for (int off = 32; off > 0; off >>= 1) {
        cr += __shfl_down(cr, off, 64);
        cg += __shfl_down(cg, off, 64);
        cb += __shfl_down(cb, off, 64);
        cd += __shfl_down(cd, off, 64);
        ca += __shfl_down(ca, off, 64);
    }
    if (lane == 0) {
        float depth_m = cd + Tf * 3.5f;
        T* o = P.out + ray*6;
        o[0] = cvt_out<T>(cr + Tf);
        o[1] = cvt_out<T>(cg + Tf);
        o[2] = cvt_out<T>(cb + Tf);
        o[3] = cvt_out<T>(depth_m);
        o[4] = cvt_out<T>(1.f / depth_m);
        o[5] = cvt_out<T>(ca);
    }
}

template <typename T>
static void fill_params(KParams<T>& P, void* const* d_in, void* d_out, void* d_ws, int want) {
    P.rays_o   = (const T*)d_in[0];
    P.rays_d   = (const T*)d_in[1];
    P.viewdirs = (const T*)d_in[2];
    P.grid     = (const T*)d_in[3];
    P.aw1 = (const T*)d_in[4];  P.ab1 = (const T*)d_in[5];
    P.aw2 = (const T*)d_in[6];  P.ab2 = (const T*)d_in[7];
    P.aw3 = (const T*)d_in[8];  P.ab3 = (const T*)d_in[9];
    P.pw1 = (const T*)d_in[10]; P.pb1 = (const T*)d_in[11];
    P.pw2 = (const T*)d_in[12]; P.pb2 = (const T*)d_in[13];
    P.pw3 = (const T*)d_in[14]; P.pb3 = (const T*)d_in[15];
    P.dw1 = (const T*)d_in[16]; P.db1 = (const T*)d_in[17];
    P.dw2 = (const T*)d_in[18]; P.db2 = (const T*)d_in[19];
    P.dw3 = (const T*)d_in[20]; P.db3 = (const T*)d_in[21];
    P.dw4 = (const T*)d_in[22]; P.db4 = (const T*)d_in[23];
    P.out = (T*)d_out;
    P.flag = (const int*)d_ws;
    P.rayData = (float*)((char*)d_ws + RAYDATA_OFF);
    P.samp = (float4*)((char*)d_ws + SAMP_OFF);
    P.tgrid = (unsigned short*)((char*)d_ws + TG_OFF);
    P.lat = (float4*)((char*)d_ws + LAT_OFF);
    P.want = want;
}

extern "C" void kernel_launch(void* const* d_in, const int* in_sizes, int n_in,
                              void* d_out, int out_size, void* d_ws, size_t ws_size,
                              hipStream_t stream) {
    int* flag = (int*)d_ws;
    hipLaunchKernelGGL(detect_dtype, dim3(1), dim3(64), 0, stream, d_in[2], flag);

    KParams<float> Pf;
    fill_params<float>(Pf, d_in, d_out, d_ws, 0);
    KParams<__hip_bfloat16> Pb;
    fill_params<__hip_bfloat16>(Pb, d_in, d_out, d_ws, 1);

    hipLaunchKernelGGL(prep_k<float>, dim3((NRAYS + BLK - 1)/BLK), dim3(BLK), 0, stream, Pf);
    hipLaunchKernelGGL(prep_k<__hip_bfloat16>, dim3((NRAYS + BLK - 1)/BLK), dim3(BLK), 0, stream, Pb);

    if (ws_size >= WS_SPLIT) {
        hipLaunchKernelGGL(transpose_k<float>, dim3(TG_BLOCKS), dim3(BLK), 0, stream, Pf);
        hipLaunchKernelGGL(transpose_k<__hip_bfloat16>, dim3(TG_BLOCKS), dim3(BLK), 0, stream, Pb);
        hipLaunchKernelGGL(gather_tg_k<float>, dim3(SAMP_BLOCKS), dim3(BLK), 0, stream, Pf);
        hipLaunchKernelGGL(gather_tg_k<__hip_bfloat16>, dim3(SAMP_BLOCKS), dim3(BLK), 0, stream, Pb);
        // A/B split: rays [0,1024) single-sample, rays [1024,2048) paired
        hipLaunchKernelGGL(mlp1h_k<float>, dim3(MLP1H_BLOCKS), dim3(BLK), 0, stream, Pf);
        hipLaunchKernelGGL(mlp1h_k<__hip_bfloat16>, dim3(MLP1H_BLOCKS), dim3(BLK), 0, stream, Pb);
        hipLaunchKernelGGL(mlp2h_k<float>, dim3(MLP2H_BLOCKS), dim3(BLK), 0, stream, Pf);
        hipLaunchKernelGGL(mlp2h_k<__hip_bfloat16>, dim3(MLP2H_BLOCKS), dim3(BLK), 0, stream, Pb);
    } else if (ws_size >= WS_BIG) {
        hipLaunchKernelGGL(transpose_k<float>, dim3(TG_BLOCKS), dim3(BLK), 0, stream, Pf);
        hipLaunchKernelGGL(transpose_k<__hip_bfloat16>, dim3(TG_BLOCKS), dim3(BLK), 0, stream, Pb);
        hipLaunchKernelGGL(sample_tg_k<float>, dim3(SAMP_BLOCKS), dim3(BLK), 0, stream, Pf);
        hipLaunchKernelGGL(sample_tg_k<__hip_bfloat16>, dim3(SAMP_BLOCKS), dim3(BLK), 0, stream, Pb);
    } else {
        hipLaunchKernelGGL(sample_k<float>, dim3(SAMP_BLOCKS), dim3(BLK), 0, stream, Pf);
        hipLaunchKernelGGL(sample_k<__hip_bfloat16>, dim3(SAMP_BLOCKS), dim3(BLK), 0, stream, Pb);
    }
    hipLaunchKernelGGL(composite_k<float>, dim3(NRAYS), dim3(64), 0, stream, Pf);
    hipLaunchKernelGGL(composite_k<__hip_bfloat16>, dim3(NRAYS), dim3(64), 0, stream, Pb);
}

// Round 5
// 1078.930 us; speedup vs baseline: 2.4213x; 2.0831x over previous
//
#include <hip/hip_runtime.h>
#include <hip/hip_bf16.h>

#define BLK   256
#define NSAMP 558
#define NRAYS 2048
#define RESI  160
#define R2I   25600
#define R3I   4096000
#define NTOT  (NRAYS * NSAMP)          // 1,142,784
#define SAMP_BLOCKS (NTOT / BLK)       // 4464 exact
#define RAYSTRIDE 32
#define NVOX  4096000                  // 160^3
#define TG_BLOCKS (NVOX / BLK)         // 16000 exact
#define HALF_RAYS 1024
#define MLPH_BLOCKS (HALF_RAYS * NSAMP / BLK)    // 2232 exact

#define ACT_SHIFT_F (-4.5951198501345896f)
#define STEP_F 0.00625f   // STEPSIZE * VOXEL

// ---------------- ws layout ----------------
#define RAYDATA_OFF 256
#define SAMP_OFF    (RAYDATA_OFF + NRAYS * RAYSTRIDE * 4)
#define TG_OFF      (SAMP_OFF + (size_t)NTOT * 16)
#define WS_BIG      (TG_OFF + (size_t)NVOX * 32)
#define LAT_OFF     WS_BIG
#define WS_SPLIT    (LAT_OFF + (size_t)NTOT * 48)
#define WSW_OFF     WS_SPLIT                       // f32 weight buffer (13.3 KB)
#define WS_SPLIT2   (WSW_OFF + 16384)

template <typename T> __device__ __forceinline__ float ldv(const T* p, int i);
template <> __device__ __forceinline__ float ldv<float>(const float* p, int i) { return p[i]; }
template <> __device__ __forceinline__ float ldv<__hip_bfloat16>(const __hip_bfloat16* p, int i) {
    return __bfloat162float(p[i]);
}
template <typename T> __device__ __forceinline__ T cvt_out(float v);
template <> __device__ __forceinline__ float cvt_out<float>(float v) { return v; }
template <> __device__ __forceinline__ __hip_bfloat16 cvt_out<__hip_bfloat16>(float v) {
    return __float2bfloat16(v);
}
__device__ __forceinline__ float b2f(unsigned short u) {
    union { float f; unsigned int i; } c; c.i = ((unsigned int)u) << 16; return c.f;
}
__device__ __forceinline__ float blo(unsigned int u) {
    union { float f; unsigned int i; } c; c.i = u << 16; return c.f;
}
__device__ __forceinline__ float bhi(unsigned int u) {
    union { float f; unsigned int i; } c; c.i = u & 0xffff0000u; return c.f;
}
__device__ __forceinline__ unsigned short f2b(float v) {
    __hip_bfloat16 h = __float2bfloat16(v);
    unsigned short u;
    __builtin_memcpy(&u, &h, sizeof(u));
    return u;
}

template <typename T>
struct KParams {
    const T *rays_o, *rays_d, *viewdirs, *grid;
    const T *aw1,*ab1,*aw2,*ab2,*aw3,*ab3;
    const T *pw1,*pb1,*pw2,*pb2,*pw3,*pb3;
    const T *dw1,*db1,*dw2,*db2,*dw3,*db3,*dw4,*db4;
    T *out;
    const int* flag;
    float* rayData;
    float4* samp;
    unsigned short* tgrid;
    float4* lat;     // [3*NTOT]
    float* wsW;      // staged f32 weights (global, wave-uniform reads -> s_load)
    int want;
    int rayBase;     // first ray handled by this launch
};

// ---- dtype detector ----
__global__ void detect_dtype(const void* vd, int* flag) {
    if (threadIdx.x == 0 && blockIdx.x == 0) {
        const float* f = (const float*)vd;
        const __hip_bfloat16* h = (const __hip_bfloat16*)vd;
        float sf = 0.f, sb = 0.f;
        for (int r = 0; r < 8; ++r) {
            float a = f[r*3], b = f[r*3+1], c = f[r*3+2];
            float d = (a*a + b*b + c*c) - 1.f;
            sf += d*d;
            float a2 = __bfloat162float(h[r*3]);
            float b2 = __bfloat162float(h[r*3+1]);
            float c2 = __bfloat162float(h[r*3+2]);
            float d2 = (a2*a2 + b2*b2 + c2*c2) - 1.f;
            sb += d2*d2;
        }
        bool sf_ok = (sf == sf) && (sf < 1e30f);
        bool sb_ok = (sb == sb) && (sb < 1e30f);
        int fl = 0;
        if (sb_ok && (!sf_ok || sb < sf)) fl = 1;
        *flag = fl;
    }
}

// =============== Transpose: (12, X, Y, Z) -> voxel-major [X][Y][Z][16ch] bf16 ===============
template <typename T>
__global__ __launch_bounds__(BLK)
void transpose_k(KParams<T> P) {
    if (*P.flag != P.want) return;
    const int i = blockIdx.x * BLK + threadIdx.x;
    unsigned short r[16];
    #pragma unroll
    for (int c = 0; c < 12; ++c) r[c] = f2b(ldv<T>(P.grid, c * R3I + i));
    #pragma unroll
    for (int c = 12; c < 16; ++c) r[c] = 0;
    uint4* dst = (uint4*)(P.tgrid + (size_t)i * 16);
    uint4 w0, w1;
    w0.x = (unsigned int)r[0] | ((unsigned int)r[1] << 16);
    w0.y = (unsigned int)r[2] | ((unsigned int)r[3] << 16);
    w0.z = (unsigned int)r[4] | ((unsigned int)r[5] << 16);
    w0.w = (unsigned int)r[6] | ((unsigned int)r[7] << 16);
    w1.x = (unsigned int)r[8] | ((unsigned int)r[9] << 16);
    w1.y = (unsigned int)r[10] | ((unsigned int)r[11] << 16);
    w1.z = 0; w1.w = 0;
    dst[0] = w0; dst[1] = w1;
}

// =============== Kernel 1: per-ray prep ===============
template <typename T>
__global__ __launch_bounds__(BLK)
void prep_k(KParams<T> P) {
    if (*P.flag != P.want) return;
    __shared__ float semb[BLK * 39];
    const int tid = threadIdx.x;
    const int ray = blockIdx.x * BLK + tid;
    if (ray >= NRAYS) return;
    const float ox = ldv<T>(P.rays_o, ray*3+0);
    const float oy = ldv<T>(P.rays_o, ray*3+1);
    const float oz = ldv<T>(P.rays_o, ray*3+2);
    const float dx = ldv<T>(P.rays_d, ray*3+0);
    const float dy = ldv<T>(P.rays_d, ray*3+1);
    const float dz = ldv<T>(P.rays_d, ray*3+2);
    const float vx = (dx == 0.f) ? 1e-6f : dx;
    const float vy = (dy == 0.f) ? 1e-6f : dy;
    const float vz = (dz == 0.f) ? 1e-6f : dz;
    const float rax = (1.f - ox) / vx, rbx = (-1.f - ox) / vx;
    const float ray_ = (1.f - oy) / vy, rby = (-1.f - oy) / vy;
    const float raz = (1.f - oz) / vz, rbz = (-1.f - oz) / vz;
    float tmin = fmaxf(fmaxf(fminf(rax, rbx), fminf(ray_, rby)), fminf(raz, rbz));
    float tmax = fminf(fminf(fmaxf(rax, rbx), fmaxf(ray_, rby)), fmaxf(raz, rbz));
    tmin = fminf(fmaxf(tmin, 0.05f), 3.5f);
    tmax = fminf(fmaxf(tmax, 0.05f), 3.5f);
    const bool mask_ray = (tmax <= tmin);
    const float norm_d = sqrtf(dx*dx + dy*dy + dz*dz);
    const float inv_nd = 1.f / norm_d;
    {
        float v0 = ldv<T>(P.viewdirs, ray*3+0);
        float v1 = ldv<T>(P.viewdirs, ray*3+1);
        float v2 = ldv<T>(P.viewdirs, ray*3+2);
        float* e = semb + tid*39;
        e[0] = v0; e[1] = v1; e[2] = v2;
        #pragma unroll
        for (int l = 0; l < 6; ++l) {
            float f = (float)(1 << l);
            e[3 + l*6 + 0] = __sinf(v0*f);
            e[3 + l*6 + 1] = __sinf(v1*f);
            e[3 + l*6 + 2] = __sinf(v2*f);
            e[3 + l*6 + 3] = __cosf(v0*f);
            e[3 + l*6 + 4] = __cosf(v1*f);
            e[3 + l*6 + 5] = __cosf(v2*f);
        }
    }
    float acc[16];
    #pragma unroll
    for (int j = 0; j < 16; ++j) acc[j] = ldv<T>(P.db1, j);
    const float* e = semb + tid*39;
    for (int i = 0; i < 39; ++i) {
        float xi = e[i];
        #pragma unroll
        for (int j = 0; j < 16; ++j) acc[j] = fmaf(xi, ldv<T>(P.dw1, (15+i)*16 + j), acc[j]);
    }
    float* rd = P.rayData + ray * RAYSTRIDE;
    rd[0] = ox; rd[1] = oy; rd[2] = oz;
    rd[3] = dx; rd[4] = dy; rd[5] = dz;
    rd[6] = mask_ray ? __int_as_float(0x7fc00000) : tmin;
    rd[7] = inv_nd;
    #pragma unroll
    for (int j = 0; j < 16; ++j) rd[8 + j] = acc[j];
    rd[24] = tmin * norm_d;
}

// =============== shared weight layout (LDS or staged-global, same offsets) ===============
#define AW1_O 0
#define AB1_O 480
#define AW2_O 512
#define AB2_O 1536
#define AW3_O 1568
#define AB3_O 1696
#define PW1_O 1700
#define PB1_O 1892
#define PW2_O 1908
#define PB2_O 2164
#define PW3_O 2180
#define PB3_O 2436
#define DW1_O 2452   /* rows 0..14 only: 240 */
#define DW2_O 2692
#define DB2_O 2948
#define DW3_O 2964
#define DB3_O 3220
#define DW4_O 3236   /* PADDED: 16 rows x 4 floats (col 3 = 0) */
#define DB4_O 3300   /* PADDED: 4 floats (last = 0) */
#define SW2_FLOATS 3304

template <typename T>
__device__ __forceinline__ void stage_w(float* dst, const T* src, int n, int tid) {
    for (int i = tid; i < n; i += BLK) dst[i] = ldv<T>(src, i);
}

template <typename T>
__device__ __forceinline__ void stage_all(float* sw, const KParams<T>& P, int tid) {
    stage_w(sw + AW1_O, P.aw1, 480, tid);
    stage_w(sw + AB1_O, P.ab1, 32, tid);
    stage_w(sw + AW2_O, P.aw2, 1024, tid);
    stage_w(sw + AB2_O, P.ab2, 32, tid);
    stage_w(sw + AW3_O, P.aw3, 128, tid);
    stage_w(sw + AB3_O, P.ab3, 4, tid);
    stage_w(sw + PW1_O, P.pw1, 192, tid);
    stage_w(sw + PB1_O, P.pb1, 16, tid);
    stage_w(sw + PW2_O, P.pw2, 256, tid);
    stage_w(sw + PB2_O, P.pb2, 16, tid);
    stage_w(sw + PW3_O, P.pw3, 256, tid);
    stage_w(sw + PB3_O, P.pb3, 16, tid);
    stage_w(sw + DW1_O, P.dw1, 240, tid);
    stage_w(sw + DW2_O, P.dw2, 256, tid);
    stage_w(sw + DB2_O, P.db2, 16, tid);
    stage_w(sw + DW3_O, P.dw3, 256, tid);
    stage_w(sw + DB3_O, P.db3, 16, tid);
    for (int i = tid; i < 64; i += BLK) {
        int r = i >> 2, c = i & 3;
        sw[DW4_O + i] = (c < 3) ? ldv<T>(P.dw4, r*3 + c) : 0.f;
    }
    if (tid < 4) sw[DB4_O + tid] = (tid < 3) ? ldv<T>(P.db4, tid) : 0.f;
}

// one-block kernel: stage converted f32 weights into global wsW
template <typename T>
__global__ __launch_bounds__(BLK)
void stagew_k(KParams<T> P) {
    if (*P.flag != P.want) return;
    stage_all(P.wsW, P, threadIdx.x);
}

// ---- register-resident float4 helpers ----
__device__ __forceinline__ float4 lds4(const float* p) { return *(const float4*)p; }
__device__ __forceinline__ void fma4(float4& a, float s, float4 w) {
    a.x = fmaf(s, w.x, a.x); a.y = fmaf(s, w.y, a.y);
    a.z = fmaf(s, w.z, a.z); a.w = fmaf(s, w.w, a.w);
}
__device__ __forceinline__ void relu4(float4& a) {
    a.x = fmaxf(a.x, 0.f); a.y = fmaxf(a.y, 0.f);
    a.z = fmaxf(a.z, 0.f); a.w = fmaxf(a.w, 0.f);
}

// ================= SINGLE-SAMPLE MLP (transport-agnostic: sw may be LDS or global) ======
__device__ __forceinline__ float4 mlp_macro1(const float* __restrict__ sw, const float* rd,
                                             float4 A, float4 B, float4 C,
                                             float px, float py, float pz) {
    float4 q0 = lds4(sw+AB1_O+0),  q1 = lds4(sw+AB1_O+4),
           q2 = lds4(sw+AB1_O+8),  q3 = lds4(sw+AB1_O+12),
           q4 = lds4(sw+AB1_O+16), q5 = lds4(sw+AB1_O+20),
           q6 = lds4(sw+AB1_O+24), q7 = lds4(sw+AB1_O+28);
#define L1ROW(i, s_) { const float* W_ = sw + AW1_O + (i)*32; const float s = (s_); \
    fma4(q0,s,lds4(W_+0));  fma4(q1,s,lds4(W_+4));  fma4(q2,s,lds4(W_+8));  fma4(q3,s,lds4(W_+12)); \
    fma4(q4,s,lds4(W_+16)); fma4(q5,s,lds4(W_+20)); fma4(q6,s,lds4(W_+24)); fma4(q7,s,lds4(W_+28)); }
    L1ROW(0,pz) L1ROW(1,py) L1ROW(2,px)
    L1ROW(3,A.x) L1ROW(4,A.y) L1ROW(5,A.z) L1ROW(6,A.w)
    L1ROW(7,B.x) L1ROW(8,B.y) L1ROW(9,B.z) L1ROW(10,B.w)
    L1ROW(11,C.x) L1ROW(12,C.y) L1ROW(13,C.z) L1ROW(14,C.w)
#undef L1ROW
    relu4(q0); relu4(q1); relu4(q2); relu4(q3);
    relu4(q4); relu4(q5); relu4(q6); relu4(q7);
    float4 lg = lds4(sw+AB3_O);
#define A2ROW(c,i,s_) { const float* W_ = sw + AW2_O + (i)*32 + (c)*8; const float s = (s_); \
    fma4(t0,s,lds4(W_)); fma4(t1,s,lds4(W_+4)); }
#define A2Q(c,i0,qv) A2ROW(c,(i0)+0,qv.x) A2ROW(c,(i0)+1,qv.y) A2ROW(c,(i0)+2,qv.z) A2ROW(c,(i0)+3,qv.w)
#define A3F(c,j,t_) { const float s = fmaxf((t_),0.f); fma4(lg,s,lds4(sw + AW3_O + ((c)*8+(j))*4)); }
#define ABLK(c) { float4 t0 = lds4(sw+AB2_O+(c)*8); float4 t1 = lds4(sw+AB2_O+(c)*8+4); \
    A2Q(c,0,q0) A2Q(c,4,q1) A2Q(c,8,q2) A2Q(c,12,q3) \
    A2Q(c,16,q4) A2Q(c,20,q5) A2Q(c,24,q6) A2Q(c,28,q7) \
    A3F(c,0,t0.x) A3F(c,1,t0.y) A3F(c,2,t0.z) A3F(c,3,t0.w) \
    A3F(c,4,t1.x) A3F(c,5,t1.y) A3F(c,6,t1.z) A3F(c,7,t1.w) }
    ABLK(0) ABLK(1) ABLK(2) ABLK(3)
#undef ABLK
#undef A3F
#undef A2Q
#undef A2ROW
    float m = fmaxf(fmaxf(lg.x,lg.y), fmaxf(lg.z,lg.w));
    float e0 = __expf(lg.x-m), e1 = __expf(lg.y-m), e2 = __expf(lg.z-m), e3 = __expf(lg.w-m);
    float att1 = e1 / (e0+e1+e2+e3);
#define R16(i, s_, BASE, r0,r1,r2,r3) { const float* W_ = sw + (BASE) + (i)*16; const float s = (s_); \
    fma4(r0,s,lds4(W_)); fma4(r1,s,lds4(W_+4)); fma4(r2,s,lds4(W_+8)); fma4(r3,s,lds4(W_+12)); }
#define R16Q(i0, qv, BASE, r0,r1,r2,r3) \
    R16((i0)+0,qv.x,BASE,r0,r1,r2,r3) R16((i0)+1,qv.y,BASE,r0,r1,r2,r3) \
    R16((i0)+2,qv.z,BASE,r0,r1,r2,r3) R16((i0)+3,qv.w,BASE,r0,r1,r2,r3)
    float4 u0 = lds4(sw+PB1_O), u1 = lds4(sw+PB1_O+4), u2 = lds4(sw+PB1_O+8), u3 = lds4(sw+PB1_O+12);
    R16Q(0,A,PW1_O,u0,u1,u2,u3) R16Q(4,B,PW1_O,u0,u1,u2,u3) R16Q(8,C,PW1_O,u0,u1,u2,u3)
    relu4(u0); relu4(u1); relu4(u2); relu4(u3);
    float4 v0 = lds4(sw+PB2_O), v1 = lds4(sw+PB2_O+4), v2 = lds4(sw+PB2_O+8), v3 = lds4(sw+PB2_O+12);
    R16Q(0,u0,PW2_O,v0,v1,v2,v3) R16Q(4,u1,PW2_O,v0,v1,v2,v3)
    R16Q(8,u2,PW2_O,v0,v1,v2,v3) R16Q(12,u3,PW2_O,v0,v1,v2,v3)
    relu4(v0); relu4(v1); relu4(v2); relu4(v3);
    float4 o0 = lds4(sw+PB3_O), o1 = lds4(sw+PB3_O+4), o2 = lds4(sw+PB3_O+8), o3 = lds4(sw+PB3_O+12);
    R16Q(0,v0,PW3_O,o0,o1,o2,o3) R16Q(4,v1,PW3_O,o0,o1,o2,o3)
    R16Q(8,v2,PW3_O,o0,o1,o2,o3) R16Q(12,v3,PW3_O,o0,o1,o2,o3)
    const float4* rdv = (const float4*)(rd + 8);
    float4 d0 = rdv[0], d1 = rdv[1], d2 = rdv[2], d3 = rdv[3];
    R16(0,o0.y,DW1_O,d0,d1,d2,d3) R16(1,o0.z,DW1_O,d0,d1,d2,d3) R16(2,o0.w,DW1_O,d0,d1,d2,d3)
    R16Q(3,o1,DW1_O,d0,d1,d2,d3) R16Q(7,o2,DW1_O,d0,d1,d2,d3) R16Q(11,o3,DW1_O,d0,d1,d2,d3)
    relu4(d0); relu4(d1); relu4(d2); relu4(d3);
    float4 g0 = lds4(sw+DB2_O), g1 = lds4(sw+DB2_O+4), g2 = lds4(sw+DB2_O+8), g3 = lds4(sw+DB2_O+12);
    R16Q(0,d0,DW2_O,g0,g1,g2,g3) R16Q(4,d1,DW2_O,g0,g1,g2,g3)
    R16Q(8,d2,DW2_O,g0,g1,g2,g3) R16Q(12,d3,DW2_O,g0,g1,g2,g3)
    relu4(g0); relu4(g1); relu4(g2); relu4(g3);
    float4 h0 = lds4(sw+DB3_O), h1 = lds4(sw+DB3_O+4), h2 = lds4(sw+DB3_O+8), h3 = lds4(sw+DB3_O+12);
    R16Q(0,g0,DW3_O,h0,h1,h2,h3) R16Q(4,g1,DW3_O,h0,h1,h2,h3)
    R16Q(8,g2,DW3_O,h0,h1,h2,h3) R16Q(12,g3,DW3_O,h0,h1,h2,h3)
    relu4(h0); relu4(h1); relu4(h2); relu4(h3);
    float4 rr = lds4(sw+DB4_O);
#define R4(i, s_) { fma4(rr,(s_),lds4(sw + DW4_O + (i)*4)); }
    R4(0,h0.x) R4(1,h0.y) R4(2,h0.z) R4(3,h0.w)
    R4(4,h1.x) R4(5,h1.y) R4(6,h1.z) R4(7,h1.w)
    R4(8,h2.x) R4(9,h2.y) R4(10,h2.z) R4(11,h2.w)
    R4(12,h3.x) R4(13,h3.y) R4(14,h3.z) R4(15,h3.w)
#undef R4
#undef R16Q
#undef R16
    float dens = att1 * o0.x;
    float xsh = dens + ACT_SHIFT_F;
    float sp = (xsh > 0.f) ? xsh + log1pf(__expf(-xsh)) : log1pf(__expf(xsh));
    float4 res;
    res.x = 1.f - __expf(-sp * 0.5f);
    res.y = 1.f / (1.f + __expf(-att1 * rr.x));
    res.z = 1.f / (1.f + __expf(-att1 * rr.y));
    res.w = 1.f / (1.f + __expf(-att1 * rr.z));
    return res;
}

// =============== SPLIT PATH kernel A: pure trilinear gather -> lat buffer ===============
template <typename T>
__global__ __launch_bounds__(BLK, 4)
void gather_tg_k(KParams<T> P) {
    if (*P.flag != P.want) return;
    const int idx = blockIdx.x * BLK + threadIdx.x;
    const int ray = idx / NSAMP;
    const int s   = idx - ray * NSAMP;
    const float* rd = P.rayData + ray * RAYSTRIDE;
    const float tmin = rd[6], inv_nd = rd[7];
    const float it = fmaf(STEP_F * (float)s, inv_nd, tmin);
    const float px = fmaf(rd[3], it, rd[0]);
    const float py = fmaf(rd[4], it, rd[1]);
    const float pz = fmaf(rd[5], it, rd[2]);
    bool inb = (px >= -1.f) & (px <= 1.f) & (py >= -1.f) & (py <= 1.f)
             & (pz >= -1.f) & (pz <= 1.f);
    if (!inb) return;
    float gx = (px + 1.f) * 79.5f;
    float gy = (py + 1.f) * 79.5f;
    float gz = (pz + 1.f) * 79.5f;
    float fx0 = floorf(gx), fy0 = floorf(gy), fz0 = floorf(gz);
    float frx = gx - fx0, fry = gy - fy0, frz = gz - fz0;
    int x0 = min(max((int)fx0, 0), RESI-1); int x1 = min(x0+1, RESI-1);
    int y0 = min(max((int)fy0, 0), RESI-1); int y1 = min(y0+1, RESI-1);
    int z0 = min(max((int)fz0, 0), RESI-1); int z1 = min(z0+1, RESI-1);
    int bx0 = x0*R2I, bx1 = x1*R2I, by0 = y0*RESI, by1 = y1*RESI;
    float wx0 = 1.f-frx, wy0 = 1.f-fry, wz0 = 1.f-frz;
    float4 LA = make_float4(0.f,0.f,0.f,0.f);
    float4 LB = make_float4(0.f,0.f,0.f,0.f);
    float4 LC = make_float4(0.f,0.f,0.f,0.f);
#define CORNER(OFF, W_) { const unsigned short* vp = P.tgrid + (OFF)*16; \
    uint4 a_ = *(const uint4*)vp; uint2 b_ = *(const uint2*)(vp + 8); const float w = (W_); \
    LA.x = fmaf(w, blo(a_.x), LA.x); LA.y = fmaf(w, bhi(a_.x), LA.y); \
    LA.z = fmaf(w, blo(a_.y), LA.z); LA.w = fmaf(w, bhi(a_.y), LA.w); \
    LB.x = fmaf(w, blo(a_.z), LB.x); LB.y = fmaf(w, bhi(a_.z), LB.y); \
    LB.z = fmaf(w, blo(a_.w), LB.z); LB.w = fmaf(w, bhi(a_.w), LB.w); \
    LC.x = fmaf(w, blo(b_.x), LC.x); LC.y = fmaf(w, bhi(b_.x), LC.y); \
    LC.z = fmaf(w, blo(b_.y), LC.z); LC.w = fmaf(w, bhi(b_.y), LC.w); }
    CORNER(bx0+by0+z0, wx0*wy0*wz0)
    CORNER(bx0+by0+z1, wx0*wy0*frz)
    CORNER(bx0+by1+z0, wx0*fry*wz0)
    CORNER(bx0+by1+z1, wx0*fry*frz)
    CORNER(bx1+by0+z0, frx*wy0*wz0)
    CORNER(bx1+by0+z1, frx*wy0*frz)
    CORNER(bx1+by1+z0, frx*fry*wz0)
    CORNER(bx1+by1+z1, frx*fry*frz)
#undef CORNER
    P.lat[idx]          = LA;
    P.lat[NTOT + idx]   = LB;
    P.lat[2*NTOT + idx] = LC;
}

// =============== MLP kernel, LDS weights (control / fallback) ===============
// covers rays [rayBase, rayBase+1024)
template <typename T>
__global__ __launch_bounds__(BLK, 3)
void mlp_lds_k(KParams<T> P) {
    if (*P.flag != P.want) return;
    __shared__ float sw[SW2_FLOATS];
    const int tid = threadIdx.x;
    stage_all(sw, P, tid);
    __syncthreads();

    const int idx = P.rayBase * NSAMP + blockIdx.x * BLK + tid;
    const int ray = idx / NSAMP;
    const int s   = idx - ray * NSAMP;
    const float* rd = P.rayData + ray * RAYSTRIDE;
    const float tmin = rd[6], inv_nd = rd[7];
    const float it = fmaf(STEP_F * (float)s, inv_nd, tmin);
    const float px = fmaf(rd[3], it, rd[0]);
    const float py = fmaf(rd[4], it, rd[1]);
    const float pz = fmaf(rd[5], it, rd[2]);
    bool inb = (px >= -1.f) & (px <= 1.f) & (py >= -1.f) & (py <= 1.f)
             & (pz >= -1.f) & (pz <= 1.f);
    float4 res = make_float4(0.f, 0.f, 0.f, 0.f);
    if (inb) {
        float4 A = P.lat[idx];
        float4 B = P.lat[NTOT + idx];
        float4 C = P.lat[2*NTOT + idx];
        res = mlp_macro1(sw, rd, A, B, C, px, py, pz);
    }
    P.samp[idx] = res;
}

// =============== MLP kernel, SCALAR weights (weights via uniform global -> s_load) =======
// No LDS, no barrier. covers rays [rayBase, rayBase+1024)
template <typename T>
__global__ __launch_bounds__(BLK, 4)
void mlp_sm_k(KParams<T> P) {
    if (*P.flag != P.want) return;
    const float* __restrict__ sw = P.wsW;   // wave-uniform base, constant indices -> scalar loads
    const int tid = threadIdx.x;
    const int idx = P.rayBase * NSAMP + blockIdx.x * BLK + tid;
    const int ray = idx / NSAMP;
    const int s   = idx - ray * NSAMP;
    const float* rd = P.rayData + ray * RAYSTRIDE;
    const float tmin = rd[6], inv_nd = rd[7];
    const float it = fmaf(STEP_F * (float)s, inv_nd, tmin);
    const float px = fmaf(rd[3], it, rd[0]);
    const float py = fmaf(rd[4], it, rd[1]);
    const float pz = fmaf(rd[5], it, rd[2]);
    bool inb = (px >= -1.f) & (px <= 1.f) & (py >= -1.f) & (py <= 1.f)
             & (pz >= -1.f) & (pz <= 1.f);
    float4 res = make_float4(0.f, 0.f, 0.f, 0.f);
    if (inb) {
        float4 A = P.lat[idx];
        float4 B = P.lat[NTOT + idx];
        float4 C = P.lat[2*NTOT + idx];
        res = mlp_macro1(sw, rd, A, B, C, px, py, pz);
    }
    P.samp[idx] = res;
}

// =============== Kernel 2 (big path): fused gather + MLP, AoS transposed grid ===============
template <typename T>
__global__ __launch_bounds__(BLK, 3)
void sample_tg_k(KParams<T> P) {
    if (*P.flag != P.want) return;
    __shared__ float sw[SW2_FLOATS];
    const int tid = threadIdx.x;
    stage_all(sw, P, tid);
    __syncthreads();

    const int idx = blockIdx.x * BLK + tid;
    const int ray = idx / NSAMP;
    const int s   = idx - ray * NSAMP;
    const float* rd = P.rayData + ray * RAYSTRIDE;
    const float tmin = rd[6], inv_nd = rd[7];
    const float it = fmaf(STEP_F * (float)s, inv_nd, tmin);
    const float px = fmaf(rd[3], it, rd[0]);
    const float py = fmaf(rd[4], it, rd[1]);
    const float pz = fmaf(rd[5], it, rd[2]);
    bool inb = (px >= -1.f) & (px <= 1.f) & (py >= -1.f) & (py <= 1.f)
             & (pz >= -1.f) & (pz <= 1.f);
    float4 res = make_float4(0.f, 0.f, 0.f, 0.f);
    if (inb) {
        float gx = (px + 1.f) * 79.5f;
        float gy = (py + 1.f) * 79.5f;
        float gz = (pz + 1.f) * 79.5f;
        float fx0 = floorf(gx), fy0 = floorf(gy), fz0 = floorf(gz);
        float frx = gx - fx0, fry = gy - fy0, frz = gz - fz0;
        int x0 = min(max((int)fx0, 0), RESI-1); int x1 = min(x0+1, RESI-1);
        int y0 = min(max((int)fy0, 0), RESI-1); int y1 = min(y0+1, RESI-1);
        int z0 = min(max((int)fz0, 0), RESI-1); int z1 = min(z0+1, RESI-1);
        int bx0 = x0*R2I, bx1 = x1*R2I, by0 = y0*RESI, by1 = y1*RESI;
        float wx0 = 1.f-frx, wy0 = 1.f-fry, wz0 = 1.f-frz;
        float4 LA = make_float4(0.f,0.f,0.f,0.f);
        float4 LB = make_float4(0.f,0.f,0.f,0.f);
        float4 LC = make_float4(0.f,0.f,0.f,0.f);
#define CORNER(OFF, W_) { const unsigned short* vp = P.tgrid + (OFF)*16; \
        uint4 a_ = *(const uint4*)vp; uint2 b_ = *(const uint2*)(vp + 8); const float w = (W_); \
        LA.x = fmaf(w, blo(a_.x), LA.x); LA.y = fmaf(w, bhi(a_.x), LA.y); \
        LA.z = fmaf(w, blo(a_.y), LA.z); LA.w = fmaf(w, bhi(a_.y), LA.w); \
        LB.x = fmaf(w, blo(a_.z), LB.x); LB.y = fmaf(w, bhi(a_.z), LB.y); \
        LB.z = fmaf(w, blo(a_.w), LB.z); LB.w = fmaf(w, bhi(a_.w), LB.w); \
        LC.x = fmaf(w, blo(b_.x), LC.x); LC.y = fmaf(w, bhi(b_.x), LC.y); \
        LC.z = fmaf(w, blo(b_.y), LC.z); LC.w = fmaf(w, bhi(b_.y), LC.w); }
        CORNER(bx0+by0+z0, wx0*wy0*wz0)
        CORNER(bx0+by0+z1, wx0*wy0*frz)
        CORNER(bx0+by1+z0, wx0*fry*wz0)
        CORNER(bx0+by1+z1, wx0*fry*frz)
        CORNER(bx1+by0+z0, frx*wy0*wz0)
        CORNER(bx1+by0+z1, frx*wy0*frz)
        CORNER(bx1+by1+z0, frx*fry*wz0)
        CORNER(bx1+by1+z1, frx*fry*frz)
#undef CORNER
        res = mlp_macro1(sw, rd, LA, LB, LC, px, py, pz);
    }
    P.samp[idx] = res;
}

// =============== Kernel 2 (mid fallback): scattered gather from original grid ===============
template <typename T>
__global__ __launch_bounds__(BLK, 3)
void sample_k(KParams<T> P) {
    if (*P.flag != P.want) return;
    __shared__ float sw[SW2_FLOATS];
    const int tid = threadIdx.x;
    stage_all(sw, P, tid);
    __syncthreads();

    const int idx = blockIdx.x * BLK + tid;
    const int ray = idx / NSAMP;
    const int s   = idx - ray * NSAMP;
    const float* rd = P.rayData + ray * RAYSTRIDE;
    const float tmin = rd[6], inv_nd = rd[7];
    const float it = fmaf(STEP_F * (float)s, inv_nd, tmin);
    const float px = fmaf(rd[3], it, rd[0]);
    const float py = fmaf(rd[4], it, rd[1]);
    const float pz = fmaf(rd[5], it, rd[2]);
    bool inb = (px >= -1.f) & (px <= 1.f) & (py >= -1.f) & (py <= 1.f)
             & (pz >= -1.f) & (pz <= 1.f);
    float4 res = make_float4(0.f, 0.f, 0.f, 0.f);
    if (inb) {
        float gx = (px + 1.f) * 79.5f;
        float gy = (py + 1.f) * 79.5f;
        float gz = (pz + 1.f) * 79.5f;
        float fx0 = floorf(gx), fy0 = floorf(gy), fz0 = floorf(gz);
        float frx = gx - fx0, fry = gy - fy0, frz = gz - fz0;
        int x0 = min(max((int)fx0, 0), RESI-1); int x1 = min(x0+1, RESI-1);
        int y0 = min(max((int)fy0, 0), RESI-1); int y1 = min(y0+1, RESI-1);
        int z0 = min(max((int)fz0, 0), RESI-1); int z1 = min(z0+1, RESI-1);
        int bx0 = x0*R2I, bx1 = x1*R2I, by0 = y0*RESI, by1 = y1*RESI;
        int o000 = bx0+by0+z0, o001 = bx0+by0+z1, o010 = bx0+by1+z0, o011 = bx0+by1+z1;
        int o100 = bx1+by0+z0, o101 = bx1+by0+z1, o110 = bx1+by1+z0, o111 = bx1+by1+z1;
        float wx0 = 1.f-frx, wy0 = 1.f-fry, wz0 = 1.f-frz;
        float w000 = wx0*wy0*wz0, w001 = wx0*wy0*frz, w010 = wx0*fry*wz0, w011 = wx0*fry*frz;
        float w100 = frx*wy0*wz0, w101 = frx*wy0*frz, w110 = frx*fry*wz0, w111 = frx*fry*frz;
        float lat[12];
        #pragma unroll
        for (int c = 0; c < 12; ++c) {
            const T* g = P.grid + c*R3I;
            lat[c] = w000*ldv<T>(g,o000) + w001*ldv<T>(g,o001)
                   + w010*ldv<T>(g,o010) + w011*ldv<T>(g,o011)
                   + w100*ldv<T>(g,o100) + w101*ldv<T>(g,o101)
                   + w110*ldv<T>(g,o110) + w111*ldv<T>(g,o111);
        }
        float4 LA = make_float4(lat[0], lat[1], lat[2],  lat[3]);
        float4 LB = make_float4(lat[4], lat[5], lat[6],  lat[7]);
        float4 LC = make_float4(lat[8], lat[9], lat[10], lat[11]);
        res = mlp_macro1(sw, rd, LA, LB, LC, px, py, pz);
    }
    P.samp[idx] = res;
}

// =============== Kernel 3: per-ray composite (one wave per ray) ===============
template <typename T>
__global__ __launch_bounds__(64)
void composite_k(KParams<T> P) {
    if (*P.flag != P.want) return;
    const int ray = blockIdx.x;
    const int lane = threadIdx.x;
    const float base_depth = P.rayData[ray * RAYSTRIDE + 24];
    const float4* sp = P.samp + ray * NSAMP;
    float lp = 1.f, cr = 0.f, cg = 0.f, cb = 0.f, cd = 0.f, ca = 0.f;
    #pragma unroll
    for (int k = 0; k < 9; ++k) {
        int s = lane * 9 + k;
        if (s < NSAMP) {
            float4 sm = sp[s];
            float w = sm.x * lp;
            cr += w * sm.y;
            cg += w * sm.z;
            cb += w * sm.w;
            cd += w * (base_depth + STEP_F * (float)s);
            ca += w;
            lp *= fmaxf(1.f - sm.x, 1e-10f);
        }
    }
    float pincl = lp;
    #pragma unroll
    for (int off = 1; off < 64; off <<= 1) {
        float v = __shfl_up(pincl, off, 64);
        if (lane >= off) pincl *= v;
    }
    float Tf = __shfl(pincl, 63, 64);
    float excl = __shfl_up(pincl, 1, 64);
    if (lane == 0) excl = 1.f;
    cr *= excl; cg *= excl; cb *= excl; cd *= excl; ca *= excl;
    #pragma unroll
    for (int off = 32; off > 0; off >>= 1) {
        cr += __shfl_down(cr, off, 64);
        cg += __shfl_down(cg, off, 64);
        cb += __shfl_down(cb, off, 64);
        cd += __shfl_down(cd, off, 64);
        ca += __shfl_down(ca, off, 64);
    }
    if (lane == 0) {
        float depth_m = cd + Tf * 3.5f;
        T* o = P.out + ray*6;
        o[0] = cvt_out<T>(cr + Tf);
        o[1] = cvt_out<T>(cg + Tf);
        o[2] = cvt_out<T>(cb + Tf);
        o[3] = cvt_out<T>(depth_m);
        o[4] = cvt_out<T>(1.f / depth_m);
        o[5] = cvt_out<T>(ca);
    }
}

template <typename T>
static void fill_params(KParams<T>& P, void* const* d_in, void* d_out, void* d_ws, int want) {
    P.rays_o   = (const T*)d_in[0];
    P.rays_d   = (const T*)d_in[1];
    P.viewdirs = (const T*)d_in[2];
    P.grid     = (const T*)d_in[3];
    P.aw1 = (const T*)d_in[4];  P.ab1 = (const T*)d_in[5];
    P.aw2 = (const T*)d_in[6];  P.ab2 = (const T*)d_in[7];
    P.aw3 = (const T*)d_in[8];  P.ab3 = (const T*)d_in[9];
    P.pw1 = (const T*)d_in[10]; P.pb1 = (const T*)d_in[11];
    P.pw2 = (const T*)d_in[12]; P.pb2 = (const T*)d_in[13];
    P.pw3 = (const T*)d_in[14]; P.pb3 = (const T*)d_in[15];
    P.dw1 = (const T*)d_in[16]; P.db1 = (const T*)d_in[17];
    P.dw2 = (const T*)d_in[18]; P.db2 = (const T*)d_in[19];
    P.dw3 = (const T*)d_in[20]; P.db3 = (const T*)d_in[21];
    P.dw4 = (const T*)d_in[22]; P.db4 = (const T*)d_in[23];
    P.out = (T*)d_out;
    P.flag = (const int*)d_ws;
    P.rayData = (float*)((char*)d_ws + RAYDATA_OFF);
    P.samp = (float4*)((char*)d_ws + SAMP_OFF);
    P.tgrid = (unsigned short*)((char*)d_ws + TG_OFF);
    P.lat = (float4*)((char*)d_ws + LAT_OFF);
    P.wsW = (float*)((char*)d_ws + WSW_OFF);
    P.want = want;
    P.rayBase = 0;
}

extern "C" void kernel_launch(void* const* d_in, const int* in_sizes, int n_in,
                              void* d_out, int out_size, void* d_ws, size_t ws_size,
                              hipStream_t stream) {
    int* flag = (int*)d_ws;
    hipLaunchKernelGGL(detect_dtype, dim3(1), dim3(64), 0, stream, d_in[2], flag);

    KParams<float> Pf;
    fill_params<float>(Pf, d_in, d_out, d_ws, 0);
    KParams<__hip_bfloat16> Pb;
    fill_params<__hip_bfloat16>(Pb, d_in, d_out, d_ws, 1);

    hipLaunchKernelGGL(prep_k<float>, dim3((NRAYS + BLK - 1)/BLK), dim3(BLK), 0, stream, Pf);
    hipLaunchKernelGGL(prep_k<__hip_bfloat16>, dim3((NRAYS + BLK - 1)/BLK), dim3(BLK), 0, stream, Pb);

    if (ws_size >= WS_SPLIT) {
        hipLaunchKernelGGL(transpose_k<float>, dim3(TG_BLOCKS), dim3(BLK), 0, stream, Pf);
        hipLaunchKernelGGL(transpose_k<__hip_bfloat16>, dim3(TG_BLOCKS), dim3(BLK), 0, stream, Pb);
        hipLaunchKernelGGL(gather_tg_k<float>, dim3(SAMP_BLOCKS), dim3(BLK), 0, stream, Pf);
        hipLaunchKernelGGL(gather_tg_k<__hip_bfloat16>, dim3(SAMP_BLOCKS), dim3(BLK), 0, stream, Pb);
        if (ws_size >= WS_SPLIT2) {
            // stage f32 weights once, then A/B: rays [0,1024) LDS control, [1024,2048) scalar-weight
            hipLaunchKernelGGL(stagew_k<float>, dim3(1), dim3(BLK), 0, stream, Pf);
            hipLaunchKernelGGL(stagew_k<__hip_bfloat16>, dim3(1), dim3(BLK), 0, stream, Pb);
            hipLaunchKernelGGL(mlp_lds_k<float>, dim3(MLPH_BLOCKS), dim3(BLK), 0, stream, Pf);
            hipLaunchKernelGGL(mlp_lds_k<__hip_bfloat16>, dim3(MLPH_BLOCKS), dim3(BLK), 0, stream, Pb);
            KParams<float> Pf2 = Pf; Pf2.rayBase = HALF_RAYS;
            KParams<__hip_bfloat16> Pb2 = Pb; Pb2.rayBase = HALF_RAYS;
            hipLaunchKernelGGL(mlp_sm_k<float>, dim3(MLPH_BLOCKS), dim3(BLK), 0, stream, Pf2);
            hipLaunchKernelGGL(mlp_sm_k<__hip_bfloat16>, dim3(MLPH_BLOCKS), dim3(BLK), 0, stream, Pb2);
        } else {
            hipLaunchKernelGGL(mlp_lds_k<float>, dim3(MLPH_BLOCKS), dim3(BLK), 0, stream, Pf);
            hipLaunchKernelGGL(mlp_lds_k<__hip_bfloat16>, dim3(MLPH_BLOCKS), dim3(BLK), 0, stream, Pb);
            KParams<float> Pf2 = Pf; Pf2.rayBase = HALF_RAYS;
            KParams<__hip_bfloat16> Pb2 = Pb; Pb2.rayBase = HALF_RAYS;
            hipLaunchKernelGGL(mlp_lds_k<float>, dim3(MLPH_BLOCKS), dim3(BLK), 0, stream, Pf2);
            hipLaunchKernelGGL(mlp_lds_k<__hip_bfloat16>, dim3(MLPH_BLOCKS), dim3(BLK), 0, stream, Pb2);
        }
    } else if (ws_size >= WS_BIG) {
        hipLaunchKernelGGL(transpose_k<float>, dim3(TG_BLOCKS), dim3(BLK), 0, stream, Pf);
        hipLaunchKernelGGL(transpose_k<__hip_bfloat16>, dim3(TG_BLOCKS), dim3(BLK), 0, stream, Pb);
        hipLaunchKernelGGL(sample_tg_k<float>, dim3(SAMP_BLOCKS), dim3(BLK), 0, stream, Pf);
        hipLaunchKernelGGL(sample_tg_k<__hip_bfloat16>, dim3(SAMP_BLOCKS), dim3(BLK), 0, stream, Pb);
    } else {
        hipLaunchKernelGGL(sample_k<float>, dim3(SAMP_BLOCKS), dim3(BLK), 0, stream, Pf);
        hipLaunchKernelGGL(sample_k<__hip_bfloat16>, dim3(SAMP_BLOCKS), dim3(BLK), 0, stream, Pb);
    }
    hipLaunchKernelGGL(composite_k<float>, dim3(NRAYS), dim3(64), 0, stream, Pf);
    hipLaunchKernelGGL(composite_k<__hip_bfloat16>, dim3(NRAYS), dim3(64), 0, stream, Pb);
}

// Round 6
// 844.833 us; speedup vs baseline: 3.0922x; 1.2771x over previous
//
#include <hip/hip_runtime.h>
#include <hip/hip_bf16.h>

#define BLK   256
#define NSAMP 558
#define NRAYS 2048
#define RESI  160
#define R2I   25600
#define R3I   4096000
#define NTOT  (NRAYS * NSAMP)          // 1,142,784
#define SAMP_BLOCKS (NTOT / BLK)       // 4464 exact
#define RAYSTRIDE 32
#define NVOX  4096000                  // 160^3
#define TG_BLOCKS (NVOX / BLK)         // 16000 exact
#define HALF_RAYS 1024
#define MLPH_BLOCKS (HALF_RAYS * NSAMP / BLK)    // 2232 exact

#define ACT_SHIFT_F (-4.5951198501345896f)
#define STEP_F 0.00625f   // STEPSIZE * VOXEL

// ---------------- ws layout ----------------
#define RAYDATA_OFF 256
#define SAMP_OFF    (RAYDATA_OFF + NRAYS * RAYSTRIDE * 4)
#define TG_OFF      (SAMP_OFF + (size_t)NTOT * 16)
#define WS_BIG      (TG_OFF + (size_t)NVOX * 32)
#define LAT_OFF     WS_BIG
#define WS_SPLIT    (LAT_OFF + (size_t)NTOT * 48)
#define WSW_OFF     WS_SPLIT                       // f32 weight buffer (13.3 KB)
#define WS_SPLIT2   (WSW_OFF + 16384)

template <typename T> __device__ __forceinline__ float ldv(const T* p, int i);
template <> __device__ __forceinline__ float ldv<float>(const float* p, int i) { return p[i]; }
template <> __device__ __forceinline__ float ldv<__hip_bfloat16>(const __hip_bfloat16* p, int i) {
    return __bfloat162float(p[i]);
}
template <typename T> __device__ __forceinline__ T cvt_out(float v);
template <> __device__ __forceinline__ float cvt_out<float>(float v) { return v; }
template <> __device__ __forceinline__ __hip_bfloat16 cvt_out<__hip_bfloat16>(float v) {
    return __float2bfloat16(v);
}
__device__ __forceinline__ float b2f(unsigned short u) {
    union { float f; unsigned int i; } c; c.i = ((unsigned int)u) << 16; return c.f;
}
__device__ __forceinline__ float blo(unsigned int u) {
    union { float f; unsigned int i; } c; c.i = u << 16; return c.f;
}
__device__ __forceinline__ float bhi(unsigned int u) {
    union { float f; unsigned int i; } c; c.i = u & 0xffff0000u; return c.f;
}
__device__ __forceinline__ unsigned short f2b(float v) {
    __hip_bfloat16 h = __float2bfloat16(v);
    unsigned short u;
    __builtin_memcpy(&u, &h, sizeof(u));
    return u;
}

template <typename T>
struct KParams {
    const T *rays_o, *rays_d, *viewdirs, *grid;
    const T *aw1,*ab1,*aw2,*ab2,*aw3,*ab3;
    const T *pw1,*pb1,*pw2,*pb2,*pw3,*pb3;
    const T *dw1,*db1,*dw2,*db2,*dw3,*db3,*dw4,*db4;
    T *out;
    const int* flag;
    float* rayData;
    float4* samp;
    unsigned short* tgrid;
    float4* lat;     // [3*NTOT]
    float* wsW;      // staged f32 weights (global, wave-uniform reads -> s_load)
    int want;
    int rayBase;     // first ray handled by this launch
};

// ---- dtype detector ----
__global__ void detect_dtype(const void* vd, int* flag) {
    if (threadIdx.x == 0 && blockIdx.x == 0) {
        const float* f = (const float*)vd;
        const __hip_bfloat16* h = (const __hip_bfloat16*)vd;
        float sf = 0.f, sb = 0.f;
        for (int r = 0; r < 8; ++r) {
            float a = f[r*3], b = f[r*3+1], c = f[r*3+2];
            float d = (a*a + b*b + c*c) - 1.f;
            sf += d*d;
            float a2 = __bfloat162float(h[r*3]);
            float b2 = __bfloat162float(h[r*3+1]);
            float c2 = __bfloat162float(h[r*3+2]);
            float d2 = (a2*a2 + b2*b2 + c2*c2) - 1.f;
            sb += d2*d2;
        }
        bool sf_ok = (sf == sf) && (sf < 1e30f);
        bool sb_ok = (sb == sb) && (sb < 1e30f);
        int fl = 0;
        if (sb_ok && (!sf_ok || sb < sf)) fl = 1;
        *flag = fl;
    }
}

// =============== Transpose: (12, X, Y, Z) -> voxel-major [X][Y][Z][16ch] bf16 ===============
template <typename T>
__global__ __launch_bounds__(BLK)
void transpose_k(KParams<T> P) {
    if (*P.flag != P.want) return;
    const int i = blockIdx.x * BLK + threadIdx.x;
    unsigned short r[16];
    #pragma unroll
    for (int c = 0; c < 12; ++c) r[c] = f2b(ldv<T>(P.grid, c * R3I + i));
    #pragma unroll
    for (int c = 12; c < 16; ++c) r[c] = 0;
    uint4* dst = (uint4*)(P.tgrid + (size_t)i * 16);
    uint4 w0, w1;
    w0.x = (unsigned int)r[0] | ((unsigned int)r[1] << 16);
    w0.y = (unsigned int)r[2] | ((unsigned int)r[3] << 16);
    w0.z = (unsigned int)r[4] | ((unsigned int)r[5] << 16);
    w0.w = (unsigned int)r[6] | ((unsigned int)r[7] << 16);
    w1.x = (unsigned int)r[8] | ((unsigned int)r[9] << 16);
    w1.y = (unsigned int)r[10] | ((unsigned int)r[11] << 16);
    w1.z = 0; w1.w = 0;
    dst[0] = w0; dst[1] = w1;
}

// =============== Kernel 1: per-ray prep ===============
template <typename T>
__global__ __launch_bounds__(BLK)
void prep_k(KParams<T> P) {
    if (*P.flag != P.want) return;
    __shared__ float semb[BLK * 39];
    const int tid = threadIdx.x;
    const int ray = blockIdx.x * BLK + tid;
    if (ray >= NRAYS) return;
    const float ox = ldv<T>(P.rays_o, ray*3+0);
    const float oy = ldv<T>(P.rays_o, ray*3+1);
    const float oz = ldv<T>(P.rays_o, ray*3+2);
    const float dx = ldv<T>(P.rays_d, ray*3+0);
    const float dy = ldv<T>(P.rays_d, ray*3+1);
    const float dz = ldv<T>(P.rays_d, ray*3+2);
    const float vx = (dx == 0.f) ? 1e-6f : dx;
    const float vy = (dy == 0.f) ? 1e-6f : dy;
    const float vz = (dz == 0.f) ? 1e-6f : dz;
    const float rax = (1.f - ox) / vx, rbx = (-1.f - ox) / vx;
    const float ray_ = (1.f - oy) / vy, rby = (-1.f - oy) / vy;
    const float raz = (1.f - oz) / vz, rbz = (-1.f - oz) / vz;
    float tmin = fmaxf(fmaxf(fminf(rax, rbx), fminf(ray_, rby)), fminf(raz, rbz));
    float tmax = fminf(fminf(fmaxf(rax, rbx), fmaxf(ray_, rby)), fmaxf(raz, rbz));
    tmin = fminf(fmaxf(tmin, 0.05f), 3.5f);
    tmax = fminf(fmaxf(tmax, 0.05f), 3.5f);
    const bool mask_ray = (tmax <= tmin);
    const float norm_d = sqrtf(dx*dx + dy*dy + dz*dz);
    const float inv_nd = 1.f / norm_d;
    {
        float v0 = ldv<T>(P.viewdirs, ray*3+0);
        float v1 = ldv<T>(P.viewdirs, ray*3+1);
        float v2 = ldv<T>(P.viewdirs, ray*3+2);
        float* e = semb + tid*39;
        e[0] = v0; e[1] = v1; e[2] = v2;
        #pragma unroll
        for (int l = 0; l < 6; ++l) {
            float f = (float)(1 << l);
            e[3 + l*6 + 0] = __sinf(v0*f);
            e[3 + l*6 + 1] = __sinf(v1*f);
            e[3 + l*6 + 2] = __sinf(v2*f);
            e[3 + l*6 + 3] = __cosf(v0*f);
            e[3 + l*6 + 4] = __cosf(v1*f);
            e[3 + l*6 + 5] = __cosf(v2*f);
        }
    }
    float acc[16];
    #pragma unroll
    for (int j = 0; j < 16; ++j) acc[j] = ldv<T>(P.db1, j);
    const float* e = semb + tid*39;
    for (int i = 0; i < 39; ++i) {
        float xi = e[i];
        #pragma unroll
        for (int j = 0; j < 16; ++j) acc[j] = fmaf(xi, ldv<T>(P.dw1, (15+i)*16 + j), acc[j]);
    }
    float* rd = P.rayData + ray * RAYSTRIDE;
    rd[0] = ox; rd[1] = oy; rd[2] = oz;
    rd[3] = dx; rd[4] = dy; rd[5] = dz;
    rd[6] = mask_ray ? __int_as_float(0x7fc00000) : tmin;
    rd[7] = inv_nd;
    #pragma unroll
    for (int j = 0; j < 16; ++j) rd[8 + j] = acc[j];
    rd[24] = tmin * norm_d;
}

// =============== shared weight layout (LDS or staged-global, same offsets) ===============
#define AW1_O 0
#define AB1_O 480
#define AW2_O 512
#define AB2_O 1536
#define AW3_O 1568
#define AB3_O 1696
#define PW1_O 1700
#define PB1_O 1892
#define PW2_O 1908
#define PB2_O 2164
#define PW3_O 2180
#define PB3_O 2436
#define DW1_O 2452   /* rows 0..14 only: 240 */
#define DW2_O 2692
#define DB2_O 2948
#define DW3_O 2964
#define DB3_O 3220
#define DW4_O 3236   /* PADDED: 16 rows x 4 floats (col 3 = 0) */
#define DB4_O 3300   /* PADDED: 4 floats (last = 0) */
#define SW2_FLOATS 3304

template <typename T>
__device__ __forceinline__ void stage_w(float* dst, const T* src, int n, int tid) {
    for (int i = tid; i < n; i += BLK) dst[i] = ldv<T>(src, i);
}

template <typename T>
__device__ __forceinline__ void stage_all(float* sw, const KParams<T>& P, int tid) {
    stage_w(sw + AW1_O, P.aw1, 480, tid);
    stage_w(sw + AB1_O, P.ab1, 32, tid);
    stage_w(sw + AW2_O, P.aw2, 1024, tid);
    stage_w(sw + AB2_O, P.ab2, 32, tid);
    stage_w(sw + AW3_O, P.aw3, 128, tid);
    stage_w(sw + AB3_O, P.ab3, 4, tid);
    stage_w(sw + PW1_O, P.pw1, 192, tid);
    stage_w(sw + PB1_O, P.pb1, 16, tid);
    stage_w(sw + PW2_O, P.pw2, 256, tid);
    stage_w(sw + PB2_O, P.pb2, 16, tid);
    stage_w(sw + PW3_O, P.pw3, 256, tid);
    stage_w(sw + PB3_O, P.pb3, 16, tid);
    stage_w(sw + DW1_O, P.dw1, 240, tid);
    stage_w(sw + DW2_O, P.dw2, 256, tid);
    stage_w(sw + DB2_O, P.db2, 16, tid);
    stage_w(sw + DW3_O, P.dw3, 256, tid);
    stage_w(sw + DB3_O, P.db3, 16, tid);
    for (int i = tid; i < 64; i += BLK) {
        int r = i >> 2, c = i & 3;
        sw[DW4_O + i] = (c < 3) ? ldv<T>(P.dw4, r*3 + c) : 0.f;
    }
    if (tid < 4) sw[DB4_O + tid] = (tid < 3) ? ldv<T>(P.db4, tid) : 0.f;
}

// one-block kernel: stage converted f32 weights into global wsW
template <typename T>
__global__ __launch_bounds__(BLK)
void stagew_k(KParams<T> P) {
    if (*P.flag != P.want) return;
    stage_all(P.wsW, P, threadIdx.x);
}

// ---- register-resident float4 helpers ----
__device__ __forceinline__ float4 lds4(const float* p) { return *(const float4*)p; }
__device__ __forceinline__ void fma4(float4& a, float s, float4 w) {
    a.x = fmaf(s, w.x, a.x); a.y = fmaf(s, w.y, a.y);
    a.z = fmaf(s, w.z, a.z); a.w = fmaf(s, w.w, a.w);
}
__device__ __forceinline__ void relu4(float4& a) {
    a.x = fmaxf(a.x, 0.f); a.y = fmaxf(a.y, 0.f);
    a.z = fmaxf(a.z, 0.f); a.w = fmaxf(a.w, 0.f);
}

// ================= SINGLE-SAMPLE MLP (transport-agnostic: sw may be LDS or global) ======
__device__ __forceinline__ float4 mlp_macro1(const float* __restrict__ sw, const float* rd,
                                             float4 A, float4 B, float4 C,
                                             float px, float py, float pz) {
    float4 q0 = lds4(sw+AB1_O+0),  q1 = lds4(sw+AB1_O+4),
           q2 = lds4(sw+AB1_O+8),  q3 = lds4(sw+AB1_O+12),
           q4 = lds4(sw+AB1_O+16), q5 = lds4(sw+AB1_O+20),
           q6 = lds4(sw+AB1_O+24), q7 = lds4(sw+AB1_O+28);
#define L1ROW(i, s_) { const float* W_ = sw + AW1_O + (i)*32; const float s = (s_); \
    fma4(q0,s,lds4(W_+0));  fma4(q1,s,lds4(W_+4));  fma4(q2,s,lds4(W_+8));  fma4(q3,s,lds4(W_+12)); \
    fma4(q4,s,lds4(W_+16)); fma4(q5,s,lds4(W_+20)); fma4(q6,s,lds4(W_+24)); fma4(q7,s,lds4(W_+28)); }
    L1ROW(0,pz) L1ROW(1,py) L1ROW(2,px)
    L1ROW(3,A.x) L1ROW(4,A.y) L1ROW(5,A.z) L1ROW(6,A.w)
    L1ROW(7,B.x) L1ROW(8,B.y) L1ROW(9,B.z) L1ROW(10,B.w)
    L1ROW(11,C.x) L1ROW(12,C.y) L1ROW(13,C.z) L1ROW(14,C.w)
#undef L1ROW
    relu4(q0); relu4(q1); relu4(q2); relu4(q3);
    relu4(q4); relu4(q5); relu4(q6); relu4(q7);
    float4 lg = lds4(sw+AB3_O);
#define A2ROW(c,i,s_) { const float* W_ = sw + AW2_O + (i)*32 + (c)*8; const float s = (s_); \
    fma4(t0,s,lds4(W_)); fma4(t1,s,lds4(W_+4)); }
#define A2Q(c,i0,qv) A2ROW(c,(i0)+0,qv.x) A2ROW(c,(i0)+1,qv.y) A2ROW(c,(i0)+2,qv.z) A2ROW(c,(i0)+3,qv.w)
#define A3F(c,j,t_) { const float s = fmaxf((t_),0.f); fma4(lg,s,lds4(sw + AW3_O + ((c)*8+(j))*4)); }
#define ABLK(c) { float4 t0 = lds4(sw+AB2_O+(c)*8); float4 t1 = lds4(sw+AB2_O+(c)*8+4); \
    A2Q(c,0,q0) A2Q(c,4,q1) A2Q(c,8,q2) A2Q(c,12,q3) \
    A2Q(c,16,q4) A2Q(c,20,q5) A2Q(c,24,q6) A2Q(c,28,q7) \
    A3F(c,0,t0.x) A3F(c,1,t0.y) A3F(c,2,t0.z) A3F(c,3,t0.w) \
    A3F(c,4,t1.x) A3F(c,5,t1.y) A3F(c,6,t1.z) A3F(c,7,t1.w) }
    ABLK(0) ABLK(1) ABLK(2) ABLK(3)
#undef ABLK
#undef A3F
#undef A2Q
#undef A2ROW
    float m = fmaxf(fmaxf(lg.x,lg.y), fmaxf(lg.z,lg.w));
    float e0 = __expf(lg.x-m), e1 = __expf(lg.y-m), e2 = __expf(lg.z-m), e3 = __expf(lg.w-m);
    float att1 = e1 / (e0+e1+e2+e3);
#define R16(i, s_, BASE, r0,r1,r2,r3) { const float* W_ = sw + (BASE) + (i)*16; const float s = (s_); \
    fma4(r0,s,lds4(W_)); fma4(r1,s,lds4(W_+4)); fma4(r2,s,lds4(W_+8)); fma4(r3,s,lds4(W_+12)); }
#define R16Q(i0, qv, BASE, r0,r1,r2,r3) \
    R16((i0)+0,qv.x,BASE,r0,r1,r2,r3) R16((i0)+1,qv.y,BASE,r0,r1,r2,r3) \
    R16((i0)+2,qv.z,BASE,r0,r1,r2,r3) R16((i0)+3,qv.w,BASE,r0,r1,r2,r3)
    float4 u0 = lds4(sw+PB1_O), u1 = lds4(sw+PB1_O+4), u2 = lds4(sw+PB1_O+8), u3 = lds4(sw+PB1_O+12);
    R16Q(0,A,PW1_O,u0,u1,u2,u3) R16Q(4,B,PW1_O,u0,u1,u2,u3) R16Q(8,C,PW1_O,u0,u1,u2,u3)
    relu4(u0); relu4(u1); relu4(u2); relu4(u3);
    float4 v0 = lds4(sw+PB2_O), v1 = lds4(sw+PB2_O+4), v2 = lds4(sw+PB2_O+8), v3 = lds4(sw+PB2_O+12);
    R16Q(0,u0,PW2_O,v0,v1,v2,v3) R16Q(4,u1,PW2_O,v0,v1,v2,v3)
    R16Q(8,u2,PW2_O,v0,v1,v2,v3) R16Q(12,u3,PW2_O,v0,v1,v2,v3)
    relu4(v0); relu4(v1); relu4(v2); relu4(v3);
    float4 o0 = lds4(sw+PB3_O), o1 = lds4(sw+PB3_O+4), o2 = lds4(sw+PB3_O+8), o3 = lds4(sw+PB3_O+12);
    R16Q(0,v0,PW3_O,o0,o1,o2,o3) R16Q(4,v1,PW3_O,o0,o1,o2,o3)
    R16Q(8,v2,PW3_O,o0,o1,o2,o3) R16Q(12,v3,PW3_O,o0,o1,o2,o3)
    const float4* rdv = (const float4*)(rd + 8);
    float4 d0 = rdv[0], d1 = rdv[1], d2 = rdv[2], d3 = rdv[3];
    R16(0,o0.y,DW1_O,d0,d1,d2,d3) R16(1,o0.z,DW1_O,d0,d1,d2,d3) R16(2,o0.w,DW1_O,d0,d1,d2,d3)
    R16Q(3,o1,DW1_O,d0,d1,d2,d3) R16Q(7,o2,DW1_O,d0,d1,d2,d3) R16Q(11,o3,DW1_O,d0,d1,d2,d3)
    relu4(d0); relu4(d1); relu4(d2); relu4(d3);
    float4 g0 = lds4(sw+DB2_O), g1 = lds4(sw+DB2_O+4), g2 = lds4(sw+DB2_O+8), g3 = lds4(sw+DB2_O+12);
    R16Q(0,d0,DW2_O,g0,g1,g2,g3) R16Q(4,d1,DW2_O,g0,g1,g2,g3)
    R16Q(8,d2,DW2_O,g0,g1,g2,g3) R16Q(12,d3,DW2_O,g0,g1,g2,g3)
    relu4(g0); relu4(g1); relu4(g2); relu4(g3);
    float4 h0 = lds4(sw+DB3_O), h1 = lds4(sw+DB3_O+4), h2 = lds4(sw+DB3_O+8), h3 = lds4(sw+DB3_O+12);
    R16Q(0,g0,DW3_O,h0,h1,h2,h3) R16Q(4,g1,DW3_O,h0,h1,h2,h3)
    R16Q(8,g2,DW3_O,h0,h1,h2,h3) R16Q(12,g3,DW3_O,h0,h1,h2,h3)
    relu4(h0); relu4(h1); relu4(h2); relu4(h3);
    float4 rr = lds4(sw+DB4_O);
#define R4(i, s_) { fma4(rr,(s_),lds4(sw + DW4_O + (i)*4)); }
    R4(0,h0.x) R4(1,h0.y) R4(2,h0.z) R4(3,h0.w)
    R4(4,h1.x) R4(5,h1.y) R4(6,h1.z) R4(7,h1.w)
    R4(8,h2.x) R4(9,h2.y) R4(10,h2.z) R4(11,h2.w)
    R4(12,h3.x) R4(13,h3.y) R4(14,h3.z) R4(15,h3.w)
#undef R4
#undef R16Q
#undef R16
    float dens = att1 * o0.x;
    float xsh = dens + ACT_SHIFT_F;
    float sp = (xsh > 0.f) ? xsh + log1pf(__expf(-xsh)) : log1pf(__expf(xsh));
    float4 res;
    res.x = 1.f - __expf(-sp * 0.5f);
    res.y = 1.f / (1.f + __expf(-att1 * rr.x));
    res.z = 1.f / (1.f + __expf(-att1 * rr.y));
    res.w = 1.f / (1.f + __expf(-att1 * rr.z));
    return res;
}

// =============== SPLIT PATH kernel A: pure trilinear gather -> lat buffer ===============
// covers rays [rayBase, rayBase + grid*BLK/NSAMP)
template <typename T>
__global__ __launch_bounds__(BLK, 4)
void gather_tg_k(KParams<T> P) {
    if (*P.flag != P.want) return;
    const int idx = P.rayBase * NSAMP + blockIdx.x * BLK + threadIdx.x;
    const int ray = idx / NSAMP;
    const int s   = idx - ray * NSAMP;
    const float* rd = P.rayData + ray * RAYSTRIDE;
    const float tmin = rd[6], inv_nd = rd[7];
    const float it = fmaf(STEP_F * (float)s, inv_nd, tmin);
    const float px = fmaf(rd[3], it, rd[0]);
    const float py = fmaf(rd[4], it, rd[1]);
    const float pz = fmaf(rd[5], it, rd[2]);
    bool inb = (px >= -1.f) & (px <= 1.f) & (py >= -1.f) & (py <= 1.f)
             & (pz >= -1.f) & (pz <= 1.f);
    if (!inb) return;
    float gx = (px + 1.f) * 79.5f;
    float gy = (py + 1.f) * 79.5f;
    float gz = (pz + 1.f) * 79.5f;
    float fx0 = floorf(gx), fy0 = floorf(gy), fz0 = floorf(gz);
    float frx = gx - fx0, fry = gy - fy0, frz = gz - fz0;
    int x0 = min(max((int)fx0, 0), RESI-1); int x1 = min(x0+1, RESI-1);
    int y0 = min(max((int)fy0, 0), RESI-1); int y1 = min(y0+1, RESI-1);
    int z0 = min(max((int)fz0, 0), RESI-1); int z1 = min(z0+1, RESI-1);
    int bx0 = x0*R2I, bx1 = x1*R2I, by0 = y0*RESI, by1 = y1*RESI;
    float wx0 = 1.f-frx, wy0 = 1.f-fry, wz0 = 1.f-frz;
    float4 LA = make_float4(0.f,0.f,0.f,0.f);
    float4 LB = make_float4(0.f,0.f,0.f,0.f);
    float4 LC = make_float4(0.f,0.f,0.f,0.f);
#define CORNER(OFF, W_) { const unsigned short* vp = P.tgrid + (OFF)*16; \
    uint4 a_ = *(const uint4*)vp; uint2 b_ = *(const uint2*)(vp + 8); const float w = (W_); \
    LA.x = fmaf(w, blo(a_.x), LA.x); LA.y = fmaf(w, bhi(a_.x), LA.y); \
    LA.z = fmaf(w, blo(a_.y), LA.z); LA.w = fmaf(w, bhi(a_.y), LA.w); \
    LB.x = fmaf(w, blo(a_.z), LB.x); LB.y = fmaf(w, bhi(a_.z), LB.y); \
    LB.z = fmaf(w, blo(a_.w), LB.z); LB.w = fmaf(w, bhi(a_.w), LB.w); \
    LC.x = fmaf(w, blo(b_.x), LC.x); LC.y = fmaf(w, bhi(b_.x), LC.y); \
    LC.z = fmaf(w, blo(b_.y), LC.z); LC.w = fmaf(w, bhi(b_.y), LC.w); }
    CORNER(bx0+by0+z0, wx0*wy0*wz0)
    CORNER(bx0+by0+z1, wx0*wy0*frz)
    CORNER(bx0+by1+z0, wx0*fry*wz0)
    CORNER(bx0+by1+z1, wx0*fry*frz)
    CORNER(bx1+by0+z0, frx*wy0*wz0)
    CORNER(bx1+by0+z1, frx*wy0*frz)
    CORNER(bx1+by1+z0, frx*fry*wz0)
    CORNER(bx1+by1+z1, frx*fry*frz)
#undef CORNER
    P.lat[idx]          = LA;
    P.lat[NTOT + idx]   = LB;
    P.lat[2*NTOT + idx] = LC;
}

// =============== FUSED kernel: tgrid gather + MLP, scalar weights, no LDS ===============
// covers rays [rayBase, rayBase+1024)
template <typename T>
__global__ __launch_bounds__(BLK, 2)
void fused_sm_k(KParams<T> P) {
    if (*P.flag != P.want) return;
    const float* __restrict__ sw = P.wsW;
    const int idx = P.rayBase * NSAMP + blockIdx.x * BLK + threadIdx.x;
    const int ray = idx / NSAMP;
    const int s   = idx - ray * NSAMP;
    const float* rd = P.rayData + ray * RAYSTRIDE;
    const float tmin = rd[6], inv_nd = rd[7];
    const float it = fmaf(STEP_F * (float)s, inv_nd, tmin);
    const float px = fmaf(rd[3], it, rd[0]);
    const float py = fmaf(rd[4], it, rd[1]);
    const float pz = fmaf(rd[5], it, rd[2]);
    bool inb = (px >= -1.f) & (px <= 1.f) & (py >= -1.f) & (py <= 1.f)
             & (pz >= -1.f) & (pz <= 1.f);
    float4 res = make_float4(0.f, 0.f, 0.f, 0.f);
    if (inb) {
        float gx = (px + 1.f) * 79.5f;
        float gy = (py + 1.f) * 79.5f;
        float gz = (pz + 1.f) * 79.5f;
        float fx0 = floorf(gx), fy0 = floorf(gy), fz0 = floorf(gz);
        float frx = gx - fx0, fry = gy - fy0, frz = gz - fz0;
        int x0 = min(max((int)fx0, 0), RESI-1); int x1 = min(x0+1, RESI-1);
        int y0 = min(max((int)fy0, 0), RESI-1); int y1 = min(y0+1, RESI-1);
        int z0 = min(max((int)fz0, 0), RESI-1); int z1 = min(z0+1, RESI-1);
        int bx0 = x0*R2I, bx1 = x1*R2I, by0 = y0*RESI, by1 = y1*RESI;
        float wx0 = 1.f-frx, wy0 = 1.f-fry, wz0 = 1.f-frz;
        float4 LA = make_float4(0.f,0.f,0.f,0.f);
        float4 LB = make_float4(0.f,0.f,0.f,0.f);
        float4 LC = make_float4(0.f,0.f,0.f,0.f);
#define CORNER(OFF, W_) { const unsigned short* vp = P.tgrid + (OFF)*16; \
        uint4 a_ = *(const uint4*)vp; uint2 b_ = *(const uint2*)(vp + 8); const float w = (W_); \
        LA.x = fmaf(w, blo(a_.x), LA.x); LA.y = fmaf(w, bhi(a_.x), LA.y); \
        LA.z = fmaf(w, blo(a_.y), LA.z); LA.w = fmaf(w, bhi(a_.y), LA.w); \
        LB.x = fmaf(w, blo(a_.z), LB.x); LB.y = fmaf(w, bhi(a_.z), LB.y); \
        LB.z = fmaf(w, blo(a_.w), LB.z); LB.w = fmaf(w, bhi(a_.w), LB.w); \
        LC.x = fmaf(w, blo(b_.x), LC.x); LC.y = fmaf(w, bhi(b_.x), LC.y); \
        LC.z = fmaf(w, blo(b_.y), LC.z); LC.w = fmaf(w, bhi(b_.y), LC.w); }
        CORNER(bx0+by0+z0, wx0*wy0*wz0)
        CORNER(bx0+by0+z1, wx0*wy0*frz)
        CORNER(bx0+by1+z0, wx0*fry*wz0)
        CORNER(bx0+by1+z1, wx0*fry*frz)
        CORNER(bx1+by0+z0, frx*wy0*wz0)
        CORNER(bx1+by0+z1, frx*wy0*frz)
        CORNER(bx1+by1+z0, frx*fry*wz0)
        CORNER(bx1+by1+z1, frx*fry*frz)
#undef CORNER
        res = mlp_macro1(sw, rd, LA, LB, LC, px, py, pz);
    }
    P.samp[idx] = res;
}

// =============== MLP kernel, LDS weights (fallback when no WSW space) ===============
template <typename T>
__global__ __launch_bounds__(BLK, 3)
void mlp_lds_k(KParams<T> P) {
    if (*P.flag != P.want) return;
    __shared__ float sw[SW2_FLOATS];
    const int tid = threadIdx.x;
    stage_all(sw, P, tid);
    __syncthreads();

    const int idx = P.rayBase * NSAMP + blockIdx.x * BLK + tid;
    const int ray = idx / NSAMP;
    const int s   = idx - ray * NSAMP;
    const float* rd = P.rayData + ray * RAYSTRIDE;
    const float tmin = rd[6], inv_nd = rd[7];
    const float it = fmaf(STEP_F * (float)s, inv_nd, tmin);
    const float px = fmaf(rd[3], it, rd[0]);
    const float py = fmaf(rd[4], it, rd[1]);
    const float pz = fmaf(rd[5], it, rd[2]);
    bool inb = (px >= -1.f) & (px <= 1.f) & (py >= -1.f) & (py <= 1.f)
             & (pz >= -1.f) & (pz <= 1.f);
    float4 res = make_float4(0.f, 0.f, 0.f, 0.f);
    if (inb) {
        float4 A = P.lat[idx];
        float4 B = P.lat[NTOT + idx];
        float4 C = P.lat[2*NTOT + idx];
        res = mlp_macro1(sw, rd, A, B, C, px, py, pz);
    }
    P.samp[idx] = res;
}

// =============== MLP kernel, SCALAR weights (split path) ===============
template <typename T>
__global__ __launch_bounds__(BLK, 4)
void mlp_sm_k(KParams<T> P) {
    if (*P.flag != P.want) return;
    const float* __restrict__ sw = P.wsW;
    const int tid = threadIdx.x;
    const int idx = P.rayBase * NSAMP + blockIdx.x * BLK + tid;
    const int ray = idx / NSAMP;
    const int s   = idx - ray * NSAMP;
    const float* rd = P.rayData + ray * RAYSTRIDE;
    const float tmin = rd[6], inv_nd = rd[7];
    const float it = fmaf(STEP_F * (float)s, inv_nd, tmin);
    const float px = fmaf(rd[3], it, rd[0]);
    const float py = fmaf(rd[4], it, rd[1]);
    const float pz = fmaf(rd[5], it, rd[2]);
    bool inb = (px >= -1.f) & (px <= 1.f) & (py >= -1.f) & (py <= 1.f)
             & (pz >= -1.f) & (pz <= 1.f);
    float4 res = make_float4(0.f, 0.f, 0.f, 0.f);
    if (inb) {
        float4 A = P.lat[idx];
        float4 B = P.lat[NTOT + idx];
        float4 C = P.lat[2*NTOT + idx];
        res = mlp_macro1(sw, rd, A, B, C, px, py, pz);
    }
    P.samp[idx] = res;
}

// =============== Kernel 2 (big path): fused gather + MLP, LDS weights ===============
template <typename T>
__global__ __launch_bounds__(BLK, 3)
void sample_tg_k(KParams<T> P) {
    if (*P.flag != P.want) return;
    __shared__ float sw[SW2_FLOATS];
    const int tid = threadIdx.x;
    stage_all(sw, P, tid);
    __syncthreads();

    const int idx = blockIdx.x * BLK + tid;
    const int ray = idx / NSAMP;
    const int s   = idx - ray * NSAMP;
    const float* rd = P.rayData + ray * RAYSTRIDE;
    const float tmin = rd[6], inv_nd = rd[7];
    const float it = fmaf(STEP_F * (float)s, inv_nd, tmin);
    const float px = fmaf(rd[3], it, rd[0]);
    const float py = fmaf(rd[4], it, rd[1]);
    const float pz = fmaf(rd[5], it, rd[2]);
    bool inb = (px >= -1.f) & (px <= 1.f) & (py >= -1.f) & (py <= 1.f)
             & (pz >= -1.f) & (pz <= 1.f);
    float4 res = make_float4(0.f, 0.f, 0.f, 0.f);
    if (inb) {
        float gx = (px + 1.f) * 79.5f;
        float gy = (py + 1.f) * 79.5f;
        float gz = (pz + 1.f) * 79.5f;
        float fx0 = floorf(gx), fy0 = floorf(gy), fz0 = floorf(gz);
        float frx = gx - fx0, fry = gy - fy0, frz = gz - fz0;
        int x0 = min(max((int)fx0, 0), RESI-1); int x1 = min(x0+1, RESI-1);
        int y0 = min(max((int)fy0, 0), RESI-1); int y1 = min(y0+1, RESI-1);
        int z0 = min(max((int)fz0, 0), RESI-1); int z1 = min(z0+1, RESI-1);
        int bx0 = x0*R2I, bx1 = x1*R2I, by0 = y0*RESI, by1 = y1*RESI;
        float wx0 = 1.f-frx, wy0 = 1.f-fry, wz0 = 1.f-frz;
        float4 LA = make_float4(0.f,0.f,0.f,0.f);
        float4 LB = make_float4(0.f,0.f,0.f,0.f);
        float4 LC = make_float4(0.f,0.f,0.f,0.f);
#define CORNER(OFF, W_) { const unsigned short* vp = P.tgrid + (OFF)*16; \
        uint4 a_ = *(const uint4*)vp; uint2 b_ = *(const uint2*)(vp + 8); const float w = (W_); \
        LA.x = fmaf(w, blo(a_.x), LA.x); LA.y = fmaf(w, bhi(a_.x), LA.y); \
        LA.z = fmaf(w, blo(a_.y), LA.z); LA.w = fmaf(w, bhi(a_.y), LA.w); \
        LB.x = fmaf(w, blo(a_.z), LB.x); LB.y = fmaf(w, bhi(a_.z), LB.y); \
        LB.z = fmaf(w, blo(a_.w), LB.z); LB.w = fmaf(w, bhi(a_.w), LB.w); \
        LC.x = fmaf(w, blo(b_.x), LC.x); LC.y = fmaf(w, bhi(b_.x), LC.y); \
        LC.z = fmaf(w, blo(b_.y), LC.z); LC.w = fmaf(w, bhi(b_.y), LC.w); }
        CORNER(bx0+by0+z0, wx0*wy0*wz0)
        CORNER(bx0+by0+z1, wx0*wy0*frz)
        CORNER(bx0+by1+z0, wx0*fry*wz0)
        CORNER(bx0+by1+z1, wx0*fry*frz)
        CORNER(bx1+by0+z0, frx*wy0*wz0)
        CORNER(bx1+by0+z1, frx*wy0*frz)
        CORNER(bx1+by1+z0, frx*fry*wz0)
        CORNER(bx1+by1+z1, frx*fry*frz)
#undef CORNER
        res = mlp_macro1(sw, rd, LA, LB, LC, px, py, pz);
    }
    P.samp[idx] = res;
}

// =============== Kernel 2 (mid fallback): scattered gather from original grid ===============
template <typename T>
__global__ __launch_bounds__(BLK, 3)
void sample_k(KParams<T> P) {
    if (*P.flag != P.want) return;
    __shared__ float sw[SW2_FLOATS];
    const int tid = threadIdx.x;
    stage_all(sw, P, tid);
    __syncthreads();

    const int idx = blockIdx.x * BLK + tid;
    const int ray = idx / NSAMP;
    const int s   = idx - ray * NSAMP;
    const float* rd = P.rayData + ray * RAYSTRIDE;
    const float tmin = rd[6], inv_nd = rd[7];
    const float it = fmaf(STEP_F * (float)s, inv_nd, tmin);
    const float px = fmaf(rd[3], it, rd[0]);
    const float py = fmaf(rd[4], it, rd[1]);
    const float pz = fmaf(rd[5], it, rd[2]);
    bool inb = (px >= -1.f) & (px <= 1.f) & (py >= -1.f) & (py <= 1.f)
             & (pz >= -1.f) & (pz <= 1.f);
    float4 res = make_float4(0.f, 0.f, 0.f, 0.f);
    if (inb) {
        float gx = (px + 1.f) * 79.5f;
        float gy = (py + 1.f) * 79.5f;
        float gz = (pz + 1.f) * 79.5f;
        float fx0 = floorf(gx), fy0 = floorf(gy), fz0 = floorf(gz);
        float frx = gx - fx0, fry = gy - fy0, frz = gz - fz0;
        int x0 = min(max((int)fx0, 0), RESI-1); int x1 = min(x0+1, RESI-1);
        int y0 = min(max((int)fy0, 0), RESI-1); int y1 = min(y0+1, RESI-1);
        int z0 = min(max((int)fz0, 0), RESI-1); int z1 = min(z0+1, RESI-1);
        int bx0 = x0*R2I, bx1 = x1*R2I, by0 = y0*RESI, by1 = y1*RESI;
        int o000 = bx0+by0+z0, o001 = bx0+by0+z1, o010 = bx0+by1+z0, o011 = bx0+by1+z1;
        int o100 = bx1+by0+z0, o101 = bx1+by0+z1, o110 = bx1+by1+z0, o111 = bx1+by1+z1;
        float wx0 = 1.f-frx, wy0 = 1.f-fry, wz0 = 1.f-frz;
        float w000 = wx0*wy0*wz0, w001 = wx0*wy0*frz, w010 = wx0*fry*wz0, w011 = wx0*fry*frz;
        float w100 = frx*wy0*wz0, w101 = frx*wy0*frz, w110 = frx*fry*wz0, w111 = frx*fry*frz;
        float lat[12];
        #pragma unroll
        for (int c = 0; c < 12; ++c) {
            const T* g = P.grid + c*R3I;
            lat[c] = w000*ldv<T>(g,o000) + w001*ldv<T>(g,o001)
                   + w010*ldv<T>(g,o010) + w011*ldv<T>(g,o011)
                   + w100*ldv<T>(g,o100) + w101*ldv<T>(g,o101)
                   + w110*ldv<T>(g,o110) + w111*ldv<T>(g,o111);
        }
        float4 LA = make_float4(lat[0], lat[1], lat[2],  lat[3]);
        float4 LB = make_float4(lat[4], lat[5], lat[6],  lat[7]);
        float4 LC = make_float4(lat[8], lat[9], lat[10], lat[11]);
        res = mlp_macro1(sw, rd, LA, LB, LC, px, py, pz);
    }
    P.samp[idx] = res;
}

// =============== Kernel 3: per-ray composite (one wave per ray) ===============
template <typename T>
__global__ __launch_bounds__(64)
void composite_k(KParams<T> P) {
    if (*P.flag != P.want) return;
    const int ray = blockIdx.x;
    const int lane = threadIdx.x;
    const float base_depth = P.rayData[ray * RAYSTRIDE + 24];
    const float4* sp = P.samp + ray * NSAMP;
    float lp = 1.f, cr = 0.f, cg = 0.f, cb = 0.f, cd = 0.f, ca = 0.f;
    #pragma unroll
    for (int k = 0; k < 9; ++k) {
        int s = lane * 9 + k;
        if (s < NSAMP) {
            float4 sm = sp[s];
            float w = sm.x * lp;
            cr += w * sm.y;
            cg += w * sm.z;
            cb += w * sm.w;
            cd += w * (base_depth + STEP_F * (float)s);
            ca += w;
            lp *= fmaxf(1.f - sm.x, 1e-10f);
        }
    }
    float pincl = lp;
    #pragma unroll
    for (int off = 1; off < 64; off <<= 1) {
        float v = __shfl_up(pincl, off, 64);
        if (lane >= off) pincl *= v;
    }
    float Tf = __shfl(pincl, 63, 64);
    float excl = __shfl_up(pincl, 1, 64);
    if (lane == 0) excl = 1.f;
    cr *= excl; cg *= excl; cb *= excl; cd *= excl; ca *= excl;
    #pragma unroll
    for (int off = 32; off > 0; off >>= 1) {
        cr += __shfl_down(cr, off, 64);
        cg += __shfl_down(cg, off, 64);
        cb += __shfl_down(cb, off, 64);
        cd += __shfl_down(cd, off, 64);
        ca += __shfl_down(ca, off, 64);
    }
    if (lane == 0) {
        float depth_m = cd + Tf * 3.5f;
        T* o = P.out + ray*6;
        o[0] = cvt_out<T>(cr + Tf);
        o[1] = cvt_out<T>(cg + Tf);
        o[2] = cvt_out<T>(cb + Tf);
        o[3] = cvt_out<T>(depth_m);
        o[4] = cvt_out<T>(1.f / depth_m);
        o[5] = cvt_out<T>(ca);
    }
}

template <typename T>
static void fill_params(KParams<T>& P, void* const* d_in, void* d_out, void* d_ws, int want) {
    P.rays_o   = (const T*)d_in[0];
    P.rays_d   = (const T*)d_in[1];
    P.viewdirs = (const T*)d_in[2];
    P.grid     = (const T*)d_in[3];
    P.aw1 = (const T*)d_in[4];  P.ab1 = (const T*)d_in[5];
    P.aw2 = (const T*)d_in[6];  P.ab2 = (const T*)d_in[7];
    P.aw3 = (const T*)d_in[8];  P.ab3 = (const T*)d_in[9];
    P.pw1 = (const T*)d_in[10]; P.pb1 = (const T*)d_in[11];
    P.pw2 = (const T*)d_in[12]; P.pb2 = (const T*)d_in[13];
    P.pw3 = (const T*)d_in[14]; P.pb3 = (const T*)d_in[15];
    P.dw1 = (const T*)d_in[16]; P.db1 = (const T*)d_in[17];
    P.dw2 = (const T*)d_in[18]; P.db2 = (const T*)d_in[19];
    P.dw3 = (const T*)d_in[20]; P.db3 = (const T*)d_in[21];
    P.dw4 = (const T*)d_in[22]; P.db4 = (const T*)d_in[23];
    P.out = (T*)d_out;
    P.flag = (const int*)d_ws;
    P.rayData = (float*)((char*)d_ws + RAYDATA_OFF);
    P.samp = (float4*)((char*)d_ws + SAMP_OFF);
    P.tgrid = (unsigned short*)((char*)d_ws + TG_OFF);
    P.lat = (float4*)((char*)d_ws + LAT_OFF);
    P.wsW = (float*)((char*)d_ws + WSW_OFF);
    P.want = want;
    P.rayBase = 0;
}

extern "C" void kernel_launch(void* const* d_in, const int* in_sizes, int n_in,
                              void* d_out, int out_size, void* d_ws, size_t ws_size,
                              hipStream_t stream) {
    int* flag = (int*)d_ws;
    hipLaunchKernelGGL(detect_dtype, dim3(1), dim3(64), 0, stream, d_in[2], flag);

    KParams<float> Pf;
    fill_params<float>(Pf, d_in, d_out, d_ws, 0);
    KParams<__hip_bfloat16> Pb;
    fill_params<__hip_bfloat16>(Pb, d_in, d_out, d_ws, 1);

    hipLaunchKernelGGL(prep_k<float>, dim3((NRAYS + BLK - 1)/BLK), dim3(BLK), 0, stream, Pf);
    hipLaunchKernelGGL(prep_k<__hip_bfloat16>, dim3((NRAYS + BLK - 1)/BLK), dim3(BLK), 0, stream, Pb);

    if (ws_size >= WS_SPLIT2) {
        // Scalar-weight path + fused-vs-split A/B:
        //   rays [0,1024):    fused_sm_k  (gather+MLP in one kernel)
        //   rays [1024,2048): gather_tg_k + mlp_sm_k (proven split pipeline)
        hipLaunchKernelGGL(transpose_k<float>, dim3(TG_BLOCKS), dim3(BLK), 0, stream, Pf);
        hipLaunchKernelGGL(transpose_k<__hip_bfloat16>, dim3(TG_BLOCKS), dim3(BLK), 0, stream, Pb);
        hipLaunchKernelGGL(stagew_k<float>, dim3(1), dim3(BLK), 0, stream, Pf);
        hipLaunchKernelGGL(stagew_k<__hip_bfloat16>, dim3(1), dim3(BLK), 0, stream, Pb);

        hipLaunchKernelGGL(fused_sm_k<float>, dim3(MLPH_BLOCKS), dim3(BLK), 0, stream, Pf);
        hipLaunchKernelGGL(fused_sm_k<__hip_bfloat16>, dim3(MLPH_BLOCKS), dim3(BLK), 0, stream, Pb);

        KParams<float> Pf2 = Pf; Pf2.rayBase = HALF_RAYS;
        KParams<__hip_bfloat16> Pb2 = Pb; Pb2.rayBase = HALF_RAYS;
        hipLaunchKernelGGL(gather_tg_k<float>, dim3(MLPH_BLOCKS), dim3(BLK), 0, stream, Pf2);
        hipLaunchKernelGGL(gather_tg_k<__hip_bfloat16>, dim3(MLPH_BLOCKS), dim3(BLK), 0, stream, Pb2);
        hipLaunchKernelGGL(mlp_sm_k<float>, dim3(MLPH_BLOCKS), dim3(BLK), 0, stream, Pf2);
        hipLaunchKernelGGL(mlp_sm_k<__hip_bfloat16>, dim3(MLPH_BLOCKS), dim3(BLK), 0, stream, Pb2);
    } else if (ws_size >= WS_SPLIT) {
        hipLaunchKernelGGL(transpose_k<float>, dim3(TG_BLOCKS), dim3(BLK), 0, stream, Pf);
        hipLaunchKernelGGL(transpose_k<__hip_bfloat16>, dim3(TG_BLOCKS), dim3(BLK), 0, stream, Pb);
        hipLaunchKernelGGL(gather_tg_k<float>, dim3(SAMP_BLOCKS), dim3(BLK), 0, stream, Pf);
        hipLaunchKernelGGL(gather_tg_k<__hip_bfloat16>, dim3(SAMP_BLOCKS), dim3(BLK), 0, stream, Pb);
        hipLaunchKernelGGL(mlp_lds_k<float>, dim3(MLPH_BLOCKS), dim3(BLK), 0, stream, Pf);
        hipLaunchKernelGGL(mlp_lds_k<__hip_bfloat16>, dim3(MLPH_BLOCKS), dim3(BLK), 0, stream, Pb);
        KParams<float> Pf2 = Pf; Pf2.rayBase = HALF_RAYS;
        KParams<__hip_bfloat16> Pb2 = Pb; Pb2.rayBase = HALF_RAYS;
        hipLaunchKernelGGL(mlp_lds_k<float>, dim3(MLPH_BLOCKS), dim3(BLK), 0, stream, Pf2);
        hipLaunchKernelGGL(mlp_lds_k<__hip_bfloat16>, dim3(MLPH_BLOCKS), dim3(BLK), 0, stream, Pb2);
    } else if (ws_size >= WS_BIG) {
        hipLaunchKernelGGL(transpose_k<float>, dim3(TG_BLOCKS), dim3(BLK), 0, stream, Pf);
        hipLaunchKernelGGL(transpose_k<__hip_bfloat16>, dim3(TG_BLOCKS), dim3(BLK), 0, stream, Pb);
        hipLaunchKernelGGL(sample_tg_k<float>, dim3(SAMP_BLOCKS), dim3(BLK), 0, stream, Pf);
        hipLaunchKernelGGL(sample_tg_k<__hip_bfloat16>, dim3(SAMP_BLOCKS), dim3(BLK), 0, stream, Pb);
    } else {
        hipLaunchKernelGGL(sample_k<float>, dim3(SAMP_BLOCKS), dim3(BLK), 0, stream, Pf);
        hipLaunchKernelGGL(sample_k<__hip_bfloat16>, dim3(SAMP_BLOCKS), dim3(BLK), 0, stream, Pb);
    }
    hipLaunchKernelGGL(composite_k<float>, dim3(NRAYS), dim3(64), 0, stream, Pf);
    hipLaunchKernelGGL(composite_k<__hip_bfloat16>, dim3(NRAYS), dim3(64), 0, stream, Pb);
}

// Round 7
// 760.692 us; speedup vs baseline: 3.4342x; 1.1106x over previous
//
#include <hip/hip_runtime.h>
#include <hip/hip_bf16.h>

#define BLK   256
#define NSAMP 558
#define NRAYS 2048
#define RESI  160
#define R2I   25600
#define R3I   4096000
#define NTOT  (NRAYS * NSAMP)          // 1,142,784
#define SAMP_BLOCKS (NTOT / BLK)       // 4464 exact
#define RAYSTRIDE 32
#define NVOX  4096000                  // 160^3
#define TG_BLOCKS (NVOX / BLK)         // 16000 exact
#define HALF_RAYS 1024
#define MLPH_BLOCKS (HALF_RAYS * NSAMP / BLK)    // 2232 exact
#define TPR2  279                                 // samples-pairs per ray (558/2)
#define FUSED2_BLOCKS (HALF_RAYS * TPR2 / BLK)   // 1116 exact

#define ACT_SHIFT_F (-4.5951198501345896f)
#define STEP_F 0.00625f   // STEPSIZE * VOXEL

// ---------------- ws layout ----------------
#define RAYDATA_OFF 256
#define SAMP_OFF    (RAYDATA_OFF + NRAYS * RAYSTRIDE * 4)
#define TG_OFF      (SAMP_OFF + (size_t)NTOT * 16)
#define WS_BIG      (TG_OFF + (size_t)NVOX * 32)
#define LAT_OFF     WS_BIG
#define WS_SPLIT    (LAT_OFF + (size_t)NTOT * 48)
#define WSW_OFF     WS_SPLIT                       // f32 weight buffer (13.3 KB)
#define WS_SPLIT2   (WSW_OFF + 16384)

template <typename T> __device__ __forceinline__ float ldv(const T* p, int i);
template <> __device__ __forceinline__ float ldv<float>(const float* p, int i) { return p[i]; }
template <> __device__ __forceinline__ float ldv<__hip_bfloat16>(const __hip_bfloat16* p, int i) {
    return __bfloat162float(p[i]);
}
template <typename T> __device__ __forceinline__ T cvt_out(float v);
template <> __device__ __forceinline__ float cvt_out<float>(float v) { return v; }
template <> __device__ __forceinline__ __hip_bfloat16 cvt_out<__hip_bfloat16>(float v) {
    return __float2bfloat16(v);
}
__device__ __forceinline__ float b2f(unsigned short u) {
    union { float f; unsigned int i; } c; c.i = ((unsigned int)u) << 16; return c.f;
}
__device__ __forceinline__ float blo(unsigned int u) {
    union { float f; unsigned int i; } c; c.i = u << 16; return c.f;
}
__device__ __forceinline__ float bhi(unsigned int u) {
    union { float f; unsigned int i; } c; c.i = u & 0xffff0000u; return c.f;
}
__device__ __forceinline__ unsigned short f2b(float v) {
    __hip_bfloat16 h = __float2bfloat16(v);
    unsigned short u;
    __builtin_memcpy(&u, &h, sizeof(u));
    return u;
}

template <typename T>
struct KParams {
    const T *rays_o, *rays_d, *viewdirs, *grid;
    const T *aw1,*ab1,*aw2,*ab2,*aw3,*ab3;
    const T *pw1,*pb1,*pw2,*pb2,*pw3,*pb3;
    const T *dw1,*db1,*dw2,*db2,*dw3,*db3,*dw4,*db4;
    T *out;
    const int* flag;
    float* rayData;
    float4* samp;
    unsigned short* tgrid;
    float4* lat;     // [3*NTOT]  (legacy split path only)
    float* wsW;      // staged f32 weights (global, wave-uniform reads -> s_load)
    int want;
    int rayBase;     // first ray handled by this launch
};

// ---- dtype detector ----
__global__ void detect_dtype(const void* vd, int* flag) {
    if (threadIdx.x == 0 && blockIdx.x == 0) {
        const float* f = (const float*)vd;
        const __hip_bfloat16* h = (const __hip_bfloat16*)vd;
        float sf = 0.f, sb = 0.f;
        for (int r = 0; r < 8; ++r) {
            float a = f[r*3], b = f[r*3+1], c = f[r*3+2];
            float d = (a*a + b*b + c*c) - 1.f;
            sf += d*d;
            float a2 = __bfloat162float(h[r*3]);
            float b2 = __bfloat162float(h[r*3+1]);
            float c2 = __bfloat162float(h[r*3+2]);
            float d2 = (a2*a2 + b2*b2 + c2*c2) - 1.f;
            sb += d2*d2;
        }
        bool sf_ok = (sf == sf) && (sf < 1e30f);
        bool sb_ok = (sb == sb) && (sb < 1e30f);
        int fl = 0;
        if (sb_ok && (!sf_ok || sb < sf)) fl = 1;
        *flag = fl;
    }
}

// =============== Transpose: (12, X, Y, Z) -> voxel-major [X][Y][Z][16ch] bf16 ===============
template <typename T>
__global__ __launch_bounds__(BLK)
void transpose_k(KParams<T> P) {
    if (*P.flag != P.want) return;
    const int i = blockIdx.x * BLK + threadIdx.x;
    unsigned short r[16];
    #pragma unroll
    for (int c = 0; c < 12; ++c) r[c] = f2b(ldv<T>(P.grid, c * R3I + i));
    #pragma unroll
    for (int c = 12; c < 16; ++c) r[c] = 0;
    uint4* dst = (uint4*)(P.tgrid + (size_t)i * 16);
    uint4 w0, w1;
    w0.x = (unsigned int)r[0] | ((unsigned int)r[1] << 16);
    w0.y = (unsigned int)r[2] | ((unsigned int)r[3] << 16);
    w0.z = (unsigned int)r[4] | ((unsigned int)r[5] << 16);
    w0.w = (unsigned int)r[6] | ((unsigned int)r[7] << 16);
    w1.x = (unsigned int)r[8] | ((unsigned int)r[9] << 16);
    w1.y = (unsigned int)r[10] | ((unsigned int)r[11] << 16);
    w1.z = 0; w1.w = 0;
    dst[0] = w0; dst[1] = w1;
}

// =============== Kernel 1: per-ray prep ===============
template <typename T>
__global__ __launch_bounds__(BLK)
void prep_k(KParams<T> P) {
    if (*P.flag != P.want) return;
    __shared__ float semb[BLK * 39];
    const int tid = threadIdx.x;
    const int ray = blockIdx.x * BLK + tid;
    if (ray >= NRAYS) return;
    const float ox = ldv<T>(P.rays_o, ray*3+0);
    const float oy = ldv<T>(P.rays_o, ray*3+1);
    const float oz = ldv<T>(P.rays_o, ray*3+2);
    const float dx = ldv<T>(P.rays_d, ray*3+0);
    const float dy = ldv<T>(P.rays_d, ray*3+1);
    const float dz = ldv<T>(P.rays_d, ray*3+2);
    const float vx = (dx == 0.f) ? 1e-6f : dx;
    const float vy = (dy == 0.f) ? 1e-6f : dy;
    const float vz = (dz == 0.f) ? 1e-6f : dz;
    const float rax = (1.f - ox) / vx, rbx = (-1.f - ox) / vx;
    const float ray_ = (1.f - oy) / vy, rby = (-1.f - oy) / vy;
    const float raz = (1.f - oz) / vz, rbz = (-1.f - oz) / vz;
    float tmin = fmaxf(fmaxf(fminf(rax, rbx), fminf(ray_, rby)), fminf(raz, rbz));
    float tmax = fminf(fminf(fmaxf(rax, rbx), fmaxf(ray_, rby)), fmaxf(raz, rbz));
    tmin = fminf(fmaxf(tmin, 0.05f), 3.5f);
    tmax = fminf(fmaxf(tmax, 0.05f), 3.5f);
    const bool mask_ray = (tmax <= tmin);
    const float norm_d = sqrtf(dx*dx + dy*dy + dz*dz);
    const float inv_nd = 1.f / norm_d;
    {
        float v0 = ldv<T>(P.viewdirs, ray*3+0);
        float v1 = ldv<T>(P.viewdirs, ray*3+1);
        float v2 = ldv<T>(P.viewdirs, ray*3+2);
        float* e = semb + tid*39;
        e[0] = v0; e[1] = v1; e[2] = v2;
        #pragma unroll
        for (int l = 0; l < 6; ++l) {
            float f = (float)(1 << l);
            e[3 + l*6 + 0] = __sinf(v0*f);
            e[3 + l*6 + 1] = __sinf(v1*f);
            e[3 + l*6 + 2] = __sinf(v2*f);
            e[3 + l*6 + 3] = __cosf(v0*f);
            e[3 + l*6 + 4] = __cosf(v1*f);
            e[3 + l*6 + 5] = __cosf(v2*f);
        }
    }
    float acc[16];
    #pragma unroll
    for (int j = 0; j < 16; ++j) acc[j] = ldv<T>(P.db1, j);
    const float* e = semb + tid*39;
    for (int i = 0; i < 39; ++i) {
        float xi = e[i];
        #pragma unroll
        for (int j = 0; j < 16; ++j) acc[j] = fmaf(xi, ldv<T>(P.dw1, (15+i)*16 + j), acc[j]);
    }
    float* rd = P.rayData + ray * RAYSTRIDE;
    rd[0] = ox; rd[1] = oy; rd[2] = oz;
    rd[3] = dx; rd[4] = dy; rd[5] = dz;
    rd[6] = mask_ray ? __int_as_float(0x7fc00000) : tmin;
    rd[7] = inv_nd;
    #pragma unroll
    for (int j = 0; j < 16; ++j) rd[8 + j] = acc[j];
    rd[24] = tmin * norm_d;
}

// =============== shared weight layout (LDS or staged-global, same offsets) ===============
#define AW1_O 0
#define AB1_O 480
#define AW2_O 512
#define AB2_O 1536
#define AW3_O 1568
#define AB3_O 1696
#define PW1_O 1700
#define PB1_O 1892
#define PW2_O 1908
#define PB2_O 2164
#define PW3_O 2180
#define PB3_O 2436
#define DW1_O 2452   /* rows 0..14 only: 240 */
#define DW2_O 2692
#define DB2_O 2948
#define DW3_O 2964
#define DB3_O 3220
#define DW4_O 3236   /* PADDED: 16 rows x 4 floats (col 3 = 0) */
#define DB4_O 3300   /* PADDED: 4 floats (last = 0) */
#define SW2_FLOATS 3304

template <typename T>
__device__ __forceinline__ void stage_w(float* dst, const T* src, int n, int tid) {
    for (int i = tid; i < n; i += BLK) dst[i] = ldv<T>(src, i);
}

template <typename T>
__device__ __forceinline__ void stage_all(float* sw, const KParams<T>& P, int tid) {
    stage_w(sw + AW1_O, P.aw1, 480, tid);
    stage_w(sw + AB1_O, P.ab1, 32, tid);
    stage_w(sw + AW2_O, P.aw2, 1024, tid);
    stage_w(sw + AB2_O, P.ab2, 32, tid);
    stage_w(sw + AW3_O, P.aw3, 128, tid);
    stage_w(sw + AB3_O, P.ab3, 4, tid);
    stage_w(sw + PW1_O, P.pw1, 192, tid);
    stage_w(sw + PB1_O, P.pb1, 16, tid);
    stage_w(sw + PW2_O, P.pw2, 256, tid);
    stage_w(sw + PB2_O, P.pb2, 16, tid);
    stage_w(sw + PW3_O, P.pw3, 256, tid);
    stage_w(sw + PB3_O, P.pb3, 16, tid);
    stage_w(sw + DW1_O, P.dw1, 240, tid);
    stage_w(sw + DW2_O, P.dw2, 256, tid);
    stage_w(sw + DB2_O, P.db2, 16, tid);
    stage_w(sw + DW3_O, P.dw3, 256, tid);
    stage_w(sw + DB3_O, P.db3, 16, tid);
    for (int i = tid; i < 64; i += BLK) {
        int r = i >> 2, c = i & 3;
        sw[DW4_O + i] = (c < 3) ? ldv<T>(P.dw4, r*3 + c) : 0.f;
    }
    if (tid < 4) sw[DB4_O + tid] = (tid < 3) ? ldv<T>(P.db4, tid) : 0.f;
}

// one-block kernel: stage converted f32 weights into global wsW
template <typename T>
__global__ __launch_bounds__(BLK)
void stagew_k(KParams<T> P) {
    if (*P.flag != P.want) return;
    stage_all(P.wsW, P, threadIdx.x);
}

// ---- register-resident float4 helpers ----
__device__ __forceinline__ float4 lds4(const float* p) { return *(const float4*)p; }
__device__ __forceinline__ void fma4(float4& a, float s, float4 w) {
    a.x = fmaf(s, w.x, a.x); a.y = fmaf(s, w.y, a.y);
    a.z = fmaf(s, w.z, a.z); a.w = fmaf(s, w.w, a.w);
}
__device__ __forceinline__ void relu4(float4& a) {
    a.x = fmaxf(a.x, 0.f); a.y = fmaxf(a.y, 0.f);
    a.z = fmaxf(a.z, 0.f); a.w = fmaxf(a.w, 0.f);
}

// ---- shared trilinear gather from voxel-major tgrid ----
__device__ __forceinline__ void tri_gather(const unsigned short* __restrict__ tg,
                                           float px, float py, float pz,
                                           float4& LA, float4& LB, float4& LC) {
    float gx = (px + 1.f) * 79.5f;
    float gy = (py + 1.f) * 79.5f;
    float gz = (pz + 1.f) * 79.5f;
    float fx0 = floorf(gx), fy0 = floorf(gy), fz0 = floorf(gz);
    float frx = gx - fx0, fry = gy - fy0, frz = gz - fz0;
    int x0 = min(max((int)fx0, 0), RESI-1); int x1 = min(x0+1, RESI-1);
    int y0 = min(max((int)fy0, 0), RESI-1); int y1 = min(y0+1, RESI-1);
    int z0 = min(max((int)fz0, 0), RESI-1); int z1 = min(z0+1, RESI-1);
    int bx0 = x0*R2I, bx1 = x1*R2I, by0 = y0*RESI, by1 = y1*RESI;
    float wx0 = 1.f-frx, wy0 = 1.f-fry, wz0 = 1.f-frz;
    LA = make_float4(0.f,0.f,0.f,0.f);
    LB = make_float4(0.f,0.f,0.f,0.f);
    LC = make_float4(0.f,0.f,0.f,0.f);
#define CORNER(OFF, W_) { const unsigned short* vp = tg + (size_t)(OFF)*16; \
    uint4 a_ = *(const uint4*)vp; uint2 b_ = *(const uint2*)(vp + 8); const float w = (W_); \
    LA.x = fmaf(w, blo(a_.x), LA.x); LA.y = fmaf(w, bhi(a_.x), LA.y); \
    LA.z = fmaf(w, blo(a_.y), LA.z); LA.w = fmaf(w, bhi(a_.y), LA.w); \
    LB.x = fmaf(w, blo(a_.z), LB.x); LB.y = fmaf(w, bhi(a_.z), LB.y); \
    LB.z = fmaf(w, blo(a_.w), LB.z); LB.w = fmaf(w, bhi(a_.w), LB.w); \
    LC.x = fmaf(w, blo(b_.x), LC.x); LC.y = fmaf(w, bhi(b_.x), LC.y); \
    LC.z = fmaf(w, blo(b_.y), LC.z); LC.w = fmaf(w, bhi(b_.y), LC.w); }
    CORNER(bx0+by0+z0, wx0*wy0*wz0)
    CORNER(bx0+by0+z1, wx0*wy0*frz)
    CORNER(bx0+by1+z0, wx0*fry*wz0)
    CORNER(bx0+by1+z1, wx0*fry*frz)
    CORNER(bx1+by0+z0, frx*wy0*wz0)
    CORNER(bx1+by0+z1, frx*wy0*frz)
    CORNER(bx1+by1+z0, frx*fry*wz0)
    CORNER(bx1+by1+z1, frx*fry*frz)
#undef CORNER
}

// ================= SINGLE-SAMPLE MLP (transport-agnostic: sw may be LDS or global) ======
__device__ __forceinline__ float4 mlp_macro1(const float* __restrict__ sw, const float* rd,
                                             float4 A, float4 B, float4 C,
                                             float px, float py, float pz) {
    float4 q0 = lds4(sw+AB1_O+0),  q1 = lds4(sw+AB1_O+4),
           q2 = lds4(sw+AB1_O+8),  q3 = lds4(sw+AB1_O+12),
           q4 = lds4(sw+AB1_O+16), q5 = lds4(sw+AB1_O+20),
           q6 = lds4(sw+AB1_O+24), q7 = lds4(sw+AB1_O+28);
#define L1ROW(i, s_) { const float* W_ = sw + AW1_O + (i)*32; const float s = (s_); \
    fma4(q0,s,lds4(W_+0));  fma4(q1,s,lds4(W_+4));  fma4(q2,s,lds4(W_+8));  fma4(q3,s,lds4(W_+12)); \
    fma4(q4,s,lds4(W_+16)); fma4(q5,s,lds4(W_+20)); fma4(q6,s,lds4(W_+24)); fma4(q7,s,lds4(W_+28)); }
    L1ROW(0,pz) L1ROW(1,py) L1ROW(2,px)
    L1ROW(3,A.x) L1ROW(4,A.y) L1ROW(5,A.z) L1ROW(6,A.w)
    L1ROW(7,B.x) L1ROW(8,B.y) L1ROW(9,B.z) L1ROW(10,B.w)
    L1ROW(11,C.x) L1ROW(12,C.y) L1ROW(13,C.z) L1ROW(14,C.w)
#undef L1ROW
    relu4(q0); relu4(q1); relu4(q2); relu4(q3);
    relu4(q4); relu4(q5); relu4(q6); relu4(q7);
    float4 lg = lds4(sw+AB3_O);
#define A2ROW(c,i,s_) { const float* W_ = sw + AW2_O + (i)*32 + (c)*8; const float s = (s_); \
    fma4(t0,s,lds4(W_)); fma4(t1,s,lds4(W_+4)); }
#define A2Q(c,i0,qv) A2ROW(c,(i0)+0,qv.x) A2ROW(c,(i0)+1,qv.y) A2ROW(c,(i0)+2,qv.z) A2ROW(c,(i0)+3,qv.w)
#define A3F(c,j,t_) { const float s = fmaxf((t_),0.f); fma4(lg,s,lds4(sw + AW3_O + ((c)*8+(j))*4)); }
#define ABLK(c) { float4 t0 = lds4(sw+AB2_O+(c)*8); float4 t1 = lds4(sw+AB2_O+(c)*8+4); \
    A2Q(c,0,q0) A2Q(c,4,q1) A2Q(c,8,q2) A2Q(c,12,q3) \
    A2Q(c,16,q4) A2Q(c,20,q5) A2Q(c,24,q6) A2Q(c,28,q7) \
    A3F(c,0,t0.x) A3F(c,1,t0.y) A3F(c,2,t0.z) A3F(c,3,t0.w) \
    A3F(c,4,t1.x) A3F(c,5,t1.y) A3F(c,6,t1.z) A3F(c,7,t1.w) }
    ABLK(0) ABLK(1) ABLK(2) ABLK(3)
#undef ABLK
#undef A3F
#undef A2Q
#undef A2ROW
    float m = fmaxf(fmaxf(lg.x,lg.y), fmaxf(lg.z,lg.w));
    float e0 = __expf(lg.x-m), e1 = __expf(lg.y-m), e2 = __expf(lg.z-m), e3 = __expf(lg.w-m);
    float att1 = e1 / (e0+e1+e2+e3);
#define R16(i, s_, BASE, r0,r1,r2,r3) { const float* W_ = sw + (BASE) + (i)*16; const float s = (s_); \
    fma4(r0,s,lds4(W_)); fma4(r1,s,lds4(W_+4)); fma4(r2,s,lds4(W_+8)); fma4(r3,s,lds4(W_+12)); }
#define R16Q(i0, qv, BASE, r0,r1,r2,r3) \
    R16((i0)+0,qv.x,BASE,r0,r1,r2,r3) R16((i0)+1,qv.y,BASE,r0,r1,r2,r3) \
    R16((i0)+2,qv.z,BASE,r0,r1,r2,r3) R16((i0)+3,qv.w,BASE,r0,r1,r2,r3)
    float4 u0 = lds4(sw+PB1_O), u1 = lds4(sw+PB1_O+4), u2 = lds4(sw+PB1_O+8), u3 = lds4(sw+PB1_O+12);
    R16Q(0,A,PW1_O,u0,u1,u2,u3) R16Q(4,B,PW1_O,u0,u1,u2,u3) R16Q(8,C,PW1_O,u0,u1,u2,u3)
    relu4(u0); relu4(u1); relu4(u2); relu4(u3);
    float4 v0 = lds4(sw+PB2_O), v1 = lds4(sw+PB2_O+4), v2 = lds4(sw+PB2_O+8), v3 = lds4(sw+PB2_O+12);
    R16Q(0,u0,PW2_O,v0,v1,v2,v3) R16Q(4,u1,PW2_O,v0,v1,v2,v3)
    R16Q(8,u2,PW2_O,v0,v1,v2,v3) R16Q(12,u3,PW2_O,v0,v1,v2,v3)
    relu4(v0); relu4(v1); relu4(v2); relu4(v3);
    float4 o0 = lds4(sw+PB3_O), o1 = lds4(sw+PB3_O+4), o2 = lds4(sw+PB3_O+8), o3 = lds4(sw+PB3_O+12);
    R16Q(0,v0,PW3_O,o0,o1,o2,o3) R16Q(4,v1,PW3_O,o0,o1,o2,o3)
    R16Q(8,v2,PW3_O,o0,o1,o2,o3) R16Q(12,v3,PW3_O,o0,o1,o2,o3)
    const float4* rdv = (const float4*)(rd + 8);
    float4 d0 = rdv[0], d1 = rdv[1], d2 = rdv[2], d3 = rdv[3];
    R16(0,o0.y,DW1_O,d0,d1,d2,d3) R16(1,o0.z,DW1_O,d0,d1,d2,d3) R16(2,o0.w,DW1_O,d0,d1,d2,d3)
    R16Q(3,o1,DW1_O,d0,d1,d2,d3) R16Q(7,o2,DW1_O,d0,d1,d2,d3) R16Q(11,o3,DW1_O,d0,d1,d2,d3)
    relu4(d0); relu4(d1); relu4(d2); relu4(d3);
    float4 g0 = lds4(sw+DB2_O), g1 = lds4(sw+DB2_O+4), g2 = lds4(sw+DB2_O+8), g3 = lds4(sw+DB2_O+12);
    R16Q(0,d0,DW2_O,g0,g1,g2,g3) R16Q(4,d1,DW2_O,g0,g1,g2,g3)
    R16Q(8,d2,DW2_O,g0,g1,g2,g3) R16Q(12,d3,DW2_O,g0,g1,g2,g3)
    relu4(g0); relu4(g1); relu4(g2); relu4(g3);
    float4 h0 = lds4(sw+DB3_O), h1 = lds4(sw+DB3_O+4), h2 = lds4(sw+DB3_O+8), h3 = lds4(sw+DB3_O+12);
    R16Q(0,g0,DW3_O,h0,h1,h2,h3) R16Q(4,g1,DW3_O,h0,h1,h2,h3)
    R16Q(8,g2,DW3_O,h0,h1,h2,h3) R16Q(12,g3,DW3_O,h0,h1,h2,h3)
    relu4(h0); relu4(h1); relu4(h2); relu4(h3);
    float4 rr = lds4(sw+DB4_O);
#define R4(i, s_) { fma4(rr,(s_),lds4(sw + DW4_O + (i)*4)); }
    R4(0,h0.x) R4(1,h0.y) R4(2,h0.z) R4(3,h0.w)
    R4(4,h1.x) R4(5,h1.y) R4(6,h1.z) R4(7,h1.w)
    R4(8,h2.x) R4(9,h2.y) R4(10,h2.z) R4(11,h2.w)
    R4(12,h3.x) R4(13,h3.y) R4(14,h3.z) R4(15,h3.w)
#undef R4
#undef R16Q
#undef R16
    float dens = att1 * o0.x;
    float xsh = dens + ACT_SHIFT_F;
    float sp = (xsh > 0.f) ? xsh + log1pf(__expf(-xsh)) : log1pf(__expf(xsh));
    float4 res;
    res.x = 1.f - __expf(-sp * 0.5f);
    res.y = 1.f / (1.f + __expf(-att1 * rr.x));
    res.z = 1.f / (1.f + __expf(-att1 * rr.y));
    res.w = 1.f / (1.f + __expf(-att1 * rr.z));
    return res;
}

// ================= PAIRED MLP (K=2; scalar weights feed BOTH independent chains) =========
__device__ __forceinline__ void mlp_macro2(const float* __restrict__ sw, const float* rd,
        float4 A0, float4 B0, float4 C0, float4 A1, float4 B1, float4 C1,
        float px0, float py0, float pz0, float px1, float py1, float pz1,
        float4& res0, float4& res1) {
    float4 qa0 = lds4(sw+AB1_O+0),  qa1 = lds4(sw+AB1_O+4),
           qa2 = lds4(sw+AB1_O+8),  qa3 = lds4(sw+AB1_O+12),
           qa4 = lds4(sw+AB1_O+16), qa5 = lds4(sw+AB1_O+20),
           qa6 = lds4(sw+AB1_O+24), qa7 = lds4(sw+AB1_O+28);
    float4 qb0 = qa0, qb1 = qa1, qb2 = qa2, qb3 = qa3,
           qb4 = qa4, qb5 = qa5, qb6 = qa6, qb7 = qa7;
#define PL1ROW(i, sa_, sb_) { const float* W_ = sw + AW1_O + (i)*32; const float sa=(sa_), sb=(sb_); \
    { const float4 w_=lds4(W_+0);  fma4(qa0,sa,w_); fma4(qb0,sb,w_); } \
    { const float4 w_=lds4(W_+4);  fma4(qa1,sa,w_); fma4(qb1,sb,w_); } \
    { const float4 w_=lds4(W_+8);  fma4(qa2,sa,w_); fma4(qb2,sb,w_); } \
    { const float4 w_=lds4(W_+12); fma4(qa3,sa,w_); fma4(qb3,sb,w_); } \
    { const float4 w_=lds4(W_+16); fma4(qa4,sa,w_); fma4(qb4,sb,w_); } \
    { const float4 w_=lds4(W_+20); fma4(qa5,sa,w_); fma4(qb5,sb,w_); } \
    { const float4 w_=lds4(W_+24); fma4(qa6,sa,w_); fma4(qb6,sb,w_); } \
    { const float4 w_=lds4(W_+28); fma4(qa7,sa,w_); fma4(qb7,sb,w_); } }
    PL1ROW(0,pz0,pz1) PL1ROW(1,py0,py1) PL1ROW(2,px0,px1)
    PL1ROW(3,A0.x,A1.x) PL1ROW(4,A0.y,A1.y) PL1ROW(5,A0.z,A1.z) PL1ROW(6,A0.w,A1.w)
    PL1ROW(7,B0.x,B1.x) PL1ROW(8,B0.y,B1.y) PL1ROW(9,B0.z,B1.z) PL1ROW(10,B0.w,B1.w)
    PL1ROW(11,C0.x,C1.x) PL1ROW(12,C0.y,C1.y) PL1ROW(13,C0.z,C1.z) PL1ROW(14,C0.w,C1.w)
#undef PL1ROW
    relu4(qa0); relu4(qa1); relu4(qa2); relu4(qa3);
    relu4(qa4); relu4(qa5); relu4(qa6); relu4(qa7);
    relu4(qb0); relu4(qb1); relu4(qb2); relu4(qb3);
    relu4(qb4); relu4(qb5); relu4(qb6); relu4(qb7);
    float4 lga = lds4(sw+AB3_O);
    float4 lgb = lga;
#define PA2ROW(c,i,sa_,sb_) { const float* W_ = sw + AW2_O + (i)*32 + (c)*8; \
    const float4 w0_=lds4(W_), w1_=lds4(W_+4); const float sa=(sa_), sb=(sb_); \
    fma4(ta0,sa,w0_); fma4(ta1,sa,w1_); fma4(tb0,sb,w0_); fma4(tb1,sb,w1_); }
#define PA2Q(c,i0,qva,qvb) PA2ROW(c,(i0)+0,qva.x,qvb.x) PA2ROW(c,(i0)+1,qva.y,qvb.y) \
                           PA2ROW(c,(i0)+2,qva.z,qvb.z) PA2ROW(c,(i0)+3,qva.w,qvb.w)
#define PA3F(c,j,ta_,tb_) { const float4 w_=lds4(sw + AW3_O + ((c)*8+(j))*4); \
    fma4(lga, fmaxf((ta_),0.f), w_); fma4(lgb, fmaxf((tb_),0.f), w_); }
#define PABLK(c) { float4 ta0 = lds4(sw+AB2_O+(c)*8); float4 ta1 = lds4(sw+AB2_O+(c)*8+4); \
    float4 tb0 = ta0, tb1 = ta1; \
    PA2Q(c,0,qa0,qb0) PA2Q(c,4,qa1,qb1) PA2Q(c,8,qa2,qb2) PA2Q(c,12,qa3,qb3) \
    PA2Q(c,16,qa4,qb4) PA2Q(c,20,qa5,qb5) PA2Q(c,24,qa6,qb6) PA2Q(c,28,qa7,qb7) \
    PA3F(c,0,ta0.x,tb0.x) PA3F(c,1,ta0.y,tb0.y) PA3F(c,2,ta0.z,tb0.z) PA3F(c,3,ta0.w,tb0.w) \
    PA3F(c,4,ta1.x,tb1.x) PA3F(c,5,ta1.y,tb1.y) PA3F(c,6,ta1.z,tb1.z) PA3F(c,7,ta1.w,tb1.w) }
    PABLK(0) PABLK(1) PABLK(2) PABLK(3)
#undef PABLK
#undef PA3F
#undef PA2Q
#undef PA2ROW
    float ma = fmaxf(fmaxf(lga.x,lga.y), fmaxf(lga.z,lga.w));
    float ea0 = __expf(lga.x-ma), ea1 = __expf(lga.y-ma), ea2 = __expf(lga.z-ma), ea3 = __expf(lga.w-ma);
    float att1a = ea1 / (ea0+ea1+ea2+ea3);
    float mb = fmaxf(fmaxf(lgb.x,lgb.y), fmaxf(lgb.z,lgb.w));
    float eb0 = __expf(lgb.x-mb), eb1 = __expf(lgb.y-mb), eb2 = __expf(lgb.z-mb), eb3 = __expf(lgb.w-mb);
    float att1b = eb1 / (eb0+eb1+eb2+eb3);
#define PR16(pre,i,sa_,sb_,BASE) { const float* W_ = sw + (BASE) + (i)*16; \
    const float4 w0_=lds4(W_), w1_=lds4(W_+4), w2_=lds4(W_+8), w3_=lds4(W_+12); \
    const float sa=(sa_), sb=(sb_); \
    fma4(pre##a0,sa,w0_); fma4(pre##a1,sa,w1_); fma4(pre##a2,sa,w2_); fma4(pre##a3,sa,w3_); \
    fma4(pre##b0,sb,w0_); fma4(pre##b1,sb,w1_); fma4(pre##b2,sb,w2_); fma4(pre##b3,sb,w3_); }
#define PR16Q(pre,i0,qva,qvb,BASE) PR16(pre,(i0)+0,qva.x,qvb.x,BASE) PR16(pre,(i0)+1,qva.y,qvb.y,BASE) \
                                   PR16(pre,(i0)+2,qva.z,qvb.z,BASE) PR16(pre,(i0)+3,qva.w,qvb.w,BASE)
    float4 ua0 = lds4(sw+PB1_O), ua1 = lds4(sw+PB1_O+4), ua2 = lds4(sw+PB1_O+8), ua3 = lds4(sw+PB1_O+12);
    float4 ub0 = ua0, ub1 = ua1, ub2 = ua2, ub3 = ua3;
    PR16Q(u,0,A0,A1,PW1_O) PR16Q(u,4,B0,B1,PW1_O) PR16Q(u,8,C0,C1,PW1_O)
    relu4(ua0); relu4(ua1); relu4(ua2); relu4(ua3);
    relu4(ub0); relu4(ub1); relu4(ub2); relu4(ub3);
    float4 va0 = lds4(sw+PB2_O), va1 = lds4(sw+PB2_O+4), va2 = lds4(sw+PB2_O+8), va3 = lds4(sw+PB2_O+12);
    float4 vb0 = va0, vb1 = va1, vb2 = va2, vb3 = va3;
    PR16Q(v,0,ua0,ub0,PW2_O) PR16Q(v,4,ua1,ub1,PW2_O)
    PR16Q(v,8,ua2,ub2,PW2_O) PR16Q(v,12,ua3,ub3,PW2_O)
    relu4(va0); relu4(va1); relu4(va2); relu4(va3);
    relu4(vb0); relu4(vb1); relu4(vb2); relu4(vb3);
    float4 oa0 = lds4(sw+PB3_O), oa1 = lds4(sw+PB3_O+4), oa2 = lds4(sw+PB3_O+8), oa3 = lds4(sw+PB3_O+12);
    float4 ob0 = oa0, ob1 = oa1, ob2 = oa2, ob3 = oa3;
    PR16Q(o,0,va0,vb0,PW3_O) PR16Q(o,4,va1,vb1,PW3_O)
    PR16Q(o,8,va2,vb2,PW3_O) PR16Q(o,12,va3,vb3,PW3_O)
    const float4* rdv = (const float4*)(rd + 8);
    float4 da0 = rdv[0], da1 = rdv[1], da2 = rdv[2], da3 = rdv[3];
    float4 db0 = da0, db1 = da1, db2 = da2, db3 = da3;
    PR16(d,0,oa0.y,ob0.y,DW1_O) PR16(d,1,oa0.z,ob0.z,DW1_O) PR16(d,2,oa0.w,ob0.w,DW1_O)
    PR16Q(d,3,oa1,ob1,DW1_O) PR16Q(d,7,oa2,ob2,DW1_O) PR16Q(d,11,oa3,ob3,DW1_O)
    relu4(da0); relu4(da1); relu4(da2); relu4(da3);
    relu4(db0); relu4(db1); relu4(db2); relu4(db3);
    float4 ga0 = lds4(sw+DB2_O), ga1 = lds4(sw+DB2_O+4), ga2 = lds4(sw+DB2_O+8), ga3 = lds4(sw+DB2_O+12);
    float4 gb0 = ga0, gb1 = ga1, gb2 = ga2, gb3 = ga3;
    PR16Q(g,0,da0,db0,DW2_O) PR16Q(g,4,da1,db1,DW2_O)
    PR16Q(g,8,da2,db2,DW2_O) PR16Q(g,12,da3,db3,DW2_O)
    relu4(ga0); relu4(ga1); relu4(ga2); relu4(ga3);
    relu4(gb0); relu4(gb1); relu4(gb2); relu4(gb3);
    float4 ha0 = lds4(sw+DB3_O), ha1 = lds4(sw+DB3_O+4), ha2 = lds4(sw+DB3_O+8), ha3 = lds4(sw+DB3_O+12);
    float4 hb0 = ha0, hb1 = ha1, hb2 = ha2, hb3 = ha3;
    PR16Q(h,0,ga0,gb0,DW3_O) PR16Q(h,4,ga1,gb1,DW3_O)
    PR16Q(h,8,ga2,gb2,DW3_O) PR16Q(h,12,ga3,gb3,DW3_O)
    relu4(ha0); relu4(ha1); relu4(ha2); relu4(ha3);
    relu4(hb0); relu4(hb1); relu4(hb2); relu4(hb3);
    float4 rra = lds4(sw+DB4_O);
    float4 rrb = rra;
#define PR4(i, sa_, sb_) { const float4 w_=lds4(sw + DW4_O + (i)*4); fma4(rra,(sa_),w_); fma4(rrb,(sb_),w_); }
    PR4(0,ha0.x,hb0.x) PR4(1,ha0.y,hb0.y) PR4(2,ha0.z,hb0.z) PR4(3,ha0.w,hb0.w)
    PR4(4,ha1.x,hb1.x) PR4(5,ha1.y,hb1.y) PR4(6,ha1.z,hb1.z) PR4(7,ha1.w,hb1.w)
    PR4(8,ha2.x,hb2.x) PR4(9,ha2.y,hb2.y) PR4(10,ha2.z,hb2.z) PR4(11,ha2.w,hb2.w)
    PR4(12,ha3.x,hb3.x) PR4(13,ha3.y,hb3.y) PR4(14,ha3.z,hb3.z) PR4(15,ha3.w,hb3.w)
#undef PR4
#undef PR16Q
#undef PR16
    {
        float dens = att1a * oa0.x;
        float xsh = dens + ACT_SHIFT_F;
        float sp = (xsh > 0.f) ? xsh + log1pf(__expf(-xsh)) : log1pf(__expf(xsh));
        res0.x = 1.f - __expf(-sp * 0.5f);
        res0.y = 1.f / (1.f + __expf(-att1a * rra.x));
        res0.z = 1.f / (1.f + __expf(-att1a * rra.y));
        res0.w = 1.f / (1.f + __expf(-att1a * rra.z));
    }
    {
        float dens = att1b * ob0.x;
        float xsh = dens + ACT_SHIFT_F;
        float sp = (xsh > 0.f) ? xsh + log1pf(__expf(-xsh)) : log1pf(__expf(xsh));
        res1.x = 1.f - __expf(-sp * 0.5f);
        res1.y = 1.f / (1.f + __expf(-att1b * rrb.x));
        res1.z = 1.f / (1.f + __expf(-att1b * rrb.y));
        res1.w = 1.f / (1.f + __expf(-att1b * rrb.z));
    }
}

// =============== FUSED kernel K=1: tgrid gather + MLP, scalar weights, no LDS ===============
template <typename T>
__global__ __launch_bounds__(BLK, 2)
void fused_sm_k(KParams<T> P) {
    if (*P.flag != P.want) return;
    const float* __restrict__ sw = P.wsW;
    const int idx = P.rayBase * NSAMP + blockIdx.x * BLK + threadIdx.x;
    const int ray = idx / NSAMP;
    const int s   = idx - ray * NSAMP;
    const float* rd = P.rayData + ray * RAYSTRIDE;
    const float tmin = rd[6], inv_nd = rd[7];
    const float it = fmaf(STEP_F * (float)s, inv_nd, tmin);
    const float px = fmaf(rd[3], it, rd[0]);
    const float py = fmaf(rd[4], it, rd[1]);
    const float pz = fmaf(rd[5], it, rd[2]);
    bool inb = (px >= -1.f) & (px <= 1.f) & (py >= -1.f) & (py <= 1.f)
             & (pz >= -1.f) & (pz <= 1.f);
    float4 res = make_float4(0.f, 0.f, 0.f, 0.f);
    if (inb) {
        float4 LA, LB, LC;
        tri_gather(P.tgrid, px, py, pz, LA, LB, LC);
        res = mlp_macro1(sw, rd, LA, LB, LC, px, py, pz);
    }
    P.samp[idx] = res;
}

// =============== FUSED kernel K=2: two samples/thread, scalar weights, no LDS ===============
template <typename T>
__global__ __launch_bounds__(BLK, 2)
void fused2_sm_k(KParams<T> P) {
    if (*P.flag != P.want) return;
    const float* __restrict__ sw = P.wsW;
    const int gid = blockIdx.x * BLK + threadIdx.x;     // 0 .. HALF_RAYS*TPR2-1
    const int rl  = gid / TPR2;
    const int ray = P.rayBase + rl;
    const int s0  = 2 * (gid - rl * TPR2);
    const int idx0 = ray * NSAMP + s0;
    const float* rd = P.rayData + ray * RAYSTRIDE;
    const float tmin = rd[6], inv_nd = rd[7];
    const float it0 = fmaf(STEP_F * (float)s0, inv_nd, tmin);
    const float it1 = fmaf(STEP_F * (float)(s0+1), inv_nd, tmin);
    const float px0 = fmaf(rd[3], it0, rd[0]);
    const float py0 = fmaf(rd[4], it0, rd[1]);
    const float pz0 = fmaf(rd[5], it0, rd[2]);
    const float px1 = fmaf(rd[3], it1, rd[0]);
    const float py1 = fmaf(rd[4], it1, rd[1]);
    const float pz1 = fmaf(rd[5], it1, rd[2]);
    const bool inb0 = (px0 >= -1.f) & (px0 <= 1.f) & (py0 >= -1.f) & (py0 <= 1.f)
                    & (pz0 >= -1.f) & (pz0 <= 1.f);
    const bool inb1 = (px1 >= -1.f) & (px1 <= 1.f) & (py1 >= -1.f) & (py1 <= 1.f)
                    & (pz1 >= -1.f) & (pz1 <= 1.f);
    const float4 z = make_float4(0.f, 0.f, 0.f, 0.f);
    float4 r0 = z, r1 = z;
    if (inb0 | inb1) {
        float4 A0 = z, B0 = z, C0 = z, A1 = z, B1 = z, C1 = z;
        if (inb0) tri_gather(P.tgrid, px0, py0, pz0, A0, B0, C0);
        if (inb1) tri_gather(P.tgrid, px1, py1, pz1, A1, B1, C1);
        mlp_macro2(sw, rd, A0, B0, C0, A1, B1, C1,
                   px0, py0, pz0, px1, py1, pz1, r0, r1);
        if (!inb0) r0 = z;
        if (!inb1) r1 = z;
    }
    P.samp[idx0]   = r0;
    P.samp[idx0+1] = r1;
}

// =============== legacy split-path kernels (fallbacks for smaller ws) ===============
template <typename T>
__global__ __launch_bounds__(BLK, 4)
void gather_tg_k(KParams<T> P) {
    if (*P.flag != P.want) return;
    const int idx = P.rayBase * NSAMP + blockIdx.x * BLK + threadIdx.x;
    const int ray = idx / NSAMP;
    const int s   = idx - ray * NSAMP;
    const float* rd = P.rayData + ray * RAYSTRIDE;
    const float tmin = rd[6], inv_nd = rd[7];
    const float it = fmaf(STEP_F * (float)s, inv_nd, tmin);
    const float px = fmaf(rd[3], it, rd[0]);
    const float py = fmaf(rd[4], it, rd[1]);
    const float pz = fmaf(rd[5], it, rd[2]);
    bool inb = (px >= -1.f) & (px <= 1.f) & (py >= -1.f) & (py <= 1.f)
             & (pz >= -1.f) & (pz <= 1.f);
    if (!inb) return;
    float4 LA, LB, LC;
    tri_gather(P.tgrid, px, py, pz, LA, LB, LC);
    P.lat[idx]          = LA;
    P.lat[NTOT + idx]   = LB;
    P.lat[2*NTOT + idx] = LC;
}

template <typename T>
__global__ __launch_bounds__(BLK, 3)
void mlp_lds_k(KParams<T> P) {
    if (*P.flag != P.want) return;
    __shared__ float sw[SW2_FLOATS];
    const int tid = threadIdx.x;
    stage_all(sw, P, tid);
    __syncthreads();

    const int idx = P.rayBase * NSAMP + blockIdx.x * BLK + tid;
    const int ray = idx / NSAMP;
    const int s   = idx - ray * NSAMP;
    const float* rd = P.rayData + ray * RAYSTRIDE;
    const float tmin = rd[6], inv_nd = rd[7];
    const float it = fmaf(STEP_F * (float)s, inv_nd, tmin);
    const float px = fmaf(rd[3], it, rd[0]);
    const float py = fmaf(rd[4], it, rd[1]);
    const float pz = fmaf(rd[5], it, rd[2]);
    bool inb = (px >= -1.f) & (px <= 1.f) & (py >= -1.f) & (py <= 1.f)
             & (pz >= -1.f) & (pz <= 1.f);
    float4 res = make_float4(0.f, 0.f, 0.f, 0.f);
    if (inb) {
        float4 A = P.lat[idx];
        float4 B = P.lat[NTOT + idx];
        float4 C = P.lat[2*NTOT + idx];
        res = mlp_macro1(sw, rd, A, B, C, px, py, pz);
    }
    P.samp[idx] = res;
}

// =============== Kernel 2 (big path): fused gather + MLP, LDS weights ===============
template <typename T>
__global__ __launch_bounds__(BLK, 3)
void sample_tg_k(KParams<T> P) {
    if (*P.flag != P.want) return;
    __shared__ float sw[SW2_FLOATS];
    const int tid = threadIdx.x;
    stage_all(sw, P, tid);
    __syncthreads();

    const int idx = blockIdx.x * BLK + tid;
    const int ray = idx / NSAMP;
    const int s   = idx - ray * NSAMP;
    const float* rd = P.rayData + ray * RAYSTRIDE;
    const float tmin = rd[6], inv_nd = rd[7];
    const float it = fmaf(STEP_F * (float)s, inv_nd, tmin);
    const float px = fmaf(rd[3], it, rd[0]);
    const float py = fmaf(rd[4], it, rd[1]);
    const float pz = fmaf(rd[5], it, rd[2]);
    bool inb = (px >= -1.f) & (px <= 1.f) & (py >= -1.f) & (py <= 1.f)
             & (pz >= -1.f) & (pz <= 1.f);
    float4 res = make_float4(0.f, 0.f, 0.f, 0.f);
    if (inb) {
        float4 LA, LB, LC;
        tri_gather(P.tgrid, px, py, pz, LA, LB, LC);
        res = mlp_macro1(sw, rd, LA, LB, LC, px, py, pz);
    }
    P.samp[idx] = res;
}

// =============== Kernel 2 (mid fallback): scattered gather from original grid ===============
template <typename T>
__global__ __launch_bounds__(BLK, 3)
void sample_k(KParams<T> P) {
    if (*P.flag != P.want) return;
    __shared__ float sw[SW2_FLOATS];
    const int tid = threadIdx.x;
    stage_all(sw, P, tid);
    __syncthreads();

    const int idx = blockIdx.x * BLK + tid;
    const int ray = idx / NSAMP;
    const int s   = idx - ray * NSAMP;
    const float* rd = P.rayData + ray * RAYSTRIDE;
    const float tmin = rd[6], inv_nd = rd[7];
    const float it = fmaf(STEP_F * (float)s, inv_nd, tmin);
    const float px = fmaf(rd[3], it, rd[0]);
    const float py = fmaf(rd[4], it, rd[1]);
    const float pz = fmaf(rd[5], it, rd[2]);
    bool inb = (px >= -1.f) & (px <= 1.f) & (py >= -1.f) & (py <= 1.f)
             & (pz >= -1.f) & (pz <= 1.f);
    float4 res = make_float4(0.f, 0.f, 0.f, 0.f);
    if (inb) {
        float gx = (px + 1.f) * 79.5f;
        float gy = (py + 1.f) * 79.5f;
        float gz = (pz + 1.f) * 79.5f;
        float fx0 = floorf(gx), fy0 = floorf(gy), fz0 = floorf(gz);
        float frx = gx - fx0, fry = gy - fy0, frz = gz - fz0;
        int x0 = min(max((int)fx0, 0), RESI-1); int x1 = min(x0+1, RESI-1);
        int y0 = min(max((int)fy0, 0), RESI-1); int y1 = min(y0+1, RESI-1);
        int z0 = min(max((int)fz0, 0), RESI-1); int z1 = min(z0+1, RESI-1);
        int bx0 = x0*R2I, bx1 = x1*R2I, by0 = y0*RESI, by1 = y1*RESI;
        int o000 = bx0+by0+z0, o001 = bx0+by0+z1, o010 = bx0+by1+z0, o011 = bx0+by1+z1;
        int o100 = bx1+by0+z0, o101 = bx1+by0+z1, o110 = bx1+by1+z0, o111 = bx1+by1+z1;
        float wx0 = 1.f-frx, wy0 = 1.f-fry, wz0 = 1.f-frz;
        float w000 = wx0*wy0*wz0, w001 = wx0*wy0*frz, w010 = wx0*fry*wz0, w011 = wx0*fry*frz;
        float w100 = frx*wy0*wz0, w101 = frx*wy0*frz, w110 = frx*fry*wz0, w111 = frx*fry*frz;
        float lat[12];
        #pragma unroll
        for (int c = 0; c < 12; ++c) {
            const T* g = P.grid + c*R3I;
            lat[c] = w000*ldv<T>(g,o000) + w001*ldv<T>(g,o001)
                   + w010*ldv<T>(g,o010) + w011*ldv<T>(g,o011)
                   + w100*ldv<T>(g,o100) + w101*ldv<T>(g,o101)
                   + w110*ldv<T>(g,o110) + w111*ldv<T>(g,o111);
        }
        float4 LA = make_float4(lat[0], lat[1], lat[2],  lat[3]);
        float4 LB = make_float4(lat[4], lat[5], lat[6],  lat[7]);
        float4 LC = make_float4(lat[8], lat[9], lat[10], lat[11]);
        res = mlp_macro1(sw, rd, LA, LB, LC, px, py, pz);
    }
    P.samp[idx] = res;
}

// =============== Kernel 3: per-ray composite (one wave per ray) ===============
template <typename T>
__global__ __launch_bounds__(64)
void composite_k(KParams<T> P) {
    if (*P.flag != P.want) return;
    const int ray = blockIdx.x;
    const int lane = threadIdx.x;
    const float base_depth = P.rayData[ray * RAYSTRIDE + 24];
    const float4* sp = P.samp + ray * NSAMP;
    float lp = 1.f, cr = 0.f, cg = 0.f, cb = 0.f, cd = 0.f, ca = 0.f;
    #pragma unroll
    for (int k = 0; k < 9; ++k) {
        int s = lane * 9 + k;
        if (s < NSAMP) {
            float4 sm = sp[s];
            float w = sm.x * lp;
            cr += w * sm.y;
            cg += w * sm.z;
            cb += w * sm.w;
            cd += w * (base_depth + STEP_F * (float)s);
            ca += w;
            lp *= fmaxf(1.f - sm.x, 1e-10f);
        }
    }
    float pincl = lp;
    #pragma unroll
    for (int off = 1; off < 64; off <<= 1) {
        float v = __shfl_up(pincl, off, 64);
        if (lane >= off) pincl *= v;
    }
    float Tf = __shfl(pincl, 63, 64);
    float excl = __shfl_up(pincl, 1, 64);
    if (lane == 0) excl = 1.f;
    cr *= excl; cg *= excl; cb *= excl; cd *= excl; ca *= excl;
    #pragma unroll
    for (int off = 32; off > 0; off >>= 1) {
        cr += __shfl_down(cr, off, 64);
        cg += __shfl_down(cg, off, 64);
        cb += __shfl_down(cb, off, 64);
        cd += __shfl_down(cd, off, 64);
        ca += __shfl_down(ca, off, 64);
    }
    if (lane == 0) {
        float depth_m = cd + Tf * 3.5f;
        T* o = P.out + ray*6;
        o[0] = cvt_out<T>(cr + Tf);
        o[1] = cvt_out<T>(cg + Tf);
        o[2] = cvt_out<T>(cb + Tf);
        o[3] = cvt_out<T>(depth_m);
        o[4] = cvt_out<T>(1.f / depth_m);
        o[5] = cvt_out<T>(ca);
    }
}

template <typename T>
static void fill_params(KParams<T>& P, void* const* d_in, void* d_out, void* d_ws, int want) {
    P.rays_o   = (const T*)d_in[0];
    P.rays_d   = (const T*)d_in[1];
    P.viewdirs = (const T*)d_in[2];
    P.grid     = (const T*)d_in[3];
    P.aw1 = (const T*)d_in[4];  P.ab1 = (const T*)d_in[5];
    P.aw2 = (const T*)d_in[6];  P.ab2 = (const T*)d_in[7];
    P.aw3 = (const T*)d_in[8];  P.ab3 = (const T*)d_in[9];
    P.pw1 = (const T*)d_in[10]; P.pb1 = (const T*)d_in[11];
    P.pw2 = (const T*)d_in[12]; P.pb2 = (const T*)d_in[13];
    P.pw3 = (const T*)d_in[14]; P.pb3 = (const T*)d_in[15];
    P.dw1 = (const T*)d_in[16]; P.db1 = (const T*)d_in[17];
    P.dw2 = (const T*)d_in[18]; P.db2 = (const T*)d_in[19];
    P.dw3 = (const T*)d_in[20]; P.db3 = (const T*)d_in[21];
    P.dw4 = (const T*)d_in[22]; P.db4 = (const T*)d_in[23];
    P.out = (T*)d_out;
    P.flag = (const int*)d_ws;
    P.rayData = (float*)((char*)d_ws + RAYDATA_OFF);
    P.samp = (float4*)((char*)d_ws + SAMP_OFF);
    P.tgrid = (unsigned short*)((char*)d_ws + TG_OFF);
    P.lat = (float4*)((char*)d_ws + LAT_OFF);
    P.wsW = (float*)((char*)d_ws + WSW_OFF);
    P.want = want;
    P.rayBase = 0;
}

extern "C" void kernel_launch(void* const* d_in, const int* in_sizes, int n_in,
                              void* d_out, int out_size, void* d_ws, size_t ws_size,
                              hipStream_t stream) {
    int* flag = (int*)d_ws;
    hipLaunchKernelGGL(detect_dtype, dim3(1), dim3(64), 0, stream, d_in[2], flag);

    KParams<float> Pf;
    fill_params<float>(Pf, d_in, d_out, d_ws, 0);
    KParams<__hip_bfloat16> Pb;
    fill_params<__hip_bfloat16>(Pb, d_in, d_out, d_ws, 1);

    hipLaunchKernelGGL(prep_k<float>, dim3((NRAYS + BLK - 1)/BLK), dim3(BLK), 0, stream, Pf);
    hipLaunchKernelGGL(prep_k<__hip_bfloat16>, dim3((NRAYS + BLK - 1)/BLK), dim3(BLK), 0, stream, Pb);

    if (ws_size >= WS_SPLIT2) {
        // All-fused scalar-weight path + K1-vs-K2 A/B:
        //   rays [0,1024):    fused_sm_k  (1 sample/thread)  -- control
        //   rays [1024,2048): fused2_sm_k (2 samples/thread, shared scalar weights)
        hipLaunchKernelGGL(transpose_k<float>, dim3(TG_BLOCKS), dim3(BLK), 0, stream, Pf);
        hipLaunchKernelGGL(transpose_k<__hip_bfloat16>, dim3(TG_BLOCKS), dim3(BLK), 0, stream, Pb);
        hipLaunchKernelGGL(stagew_k<float>, dim3(1), dim3(BLK), 0, stream, Pf);
        hipLaunchKernelGGL(stagew_k<__hip_bfloat16>, dim3(1), dim3(BLK), 0, stream, Pb);

        hipLaunchKernelGGL(fused_sm_k<float>, dim3(MLPH_BLOCKS), dim3(BLK), 0, stream, Pf);
        hipLaunchKernelGGL(fused_sm_k<__hip_bfloat16>, dim3(MLPH_BLOCKS), dim3(BLK), 0, stream, Pb);

        KParams<float> Pf2 = Pf; Pf2.rayBase = HALF_RAYS;
        KParams<__hip_bfloat16> Pb2 = Pb; Pb2.rayBase = HALF_RAYS;
        hipLaunchKernelGGL(fused2_sm_k<float>, dim3(FUSED2_BLOCKS), dim3(BLK), 0, stream, Pf2);
        hipLaunchKernelGGL(fused2_sm_k<__hip_bfloat16>, dim3(FUSED2_BLOCKS), dim3(BLK), 0, stream, Pb2);
    } else if (ws_size >= WS_SPLIT) {
        hipLaunchKernelGGL(transpose_k<float>, dim3(TG_BLOCKS), dim3(BLK), 0, stream, Pf);
        hipLaunchKernelGGL(transpose_k<__hip_bfloat16>, dim3(TG_BLOCKS), dim3(BLK), 0, stream, Pb);
        hipLaunchKernelGGL(gather_tg_k<float>, dim3(SAMP_BLOCKS), dim3(BLK), 0, stream, Pf);
        hipLaunchKernelGGL(gather_tg_k<__hip_bfloat16>, dim3(SAMP_BLOCKS), dim3(BLK), 0, stream, Pb);
        hipLaunchKernelGGL(mlp_lds_k<float>, dim3(MLPH_BLOCKS), dim3(BLK), 0, stream, Pf);
        hipLaunchKernelGGL(mlp_lds_k<__hip_bfloat16>, dim3(MLPH_BLOCKS), dim3(BLK), 0, stream, Pb);
        KParams<float> Pf2 = Pf; Pf2.rayBase = HALF_RAYS;
        KParams<__hip_bfloat16> Pb2 = Pb; Pb2.rayBase = HALF_RAYS;
        hipLaunchKernelGGL(mlp_lds_k<float>, dim3(MLPH_BLOCKS), dim3(BLK), 0, stream, Pf2);
        hipLaunchKernelGGL(mlp_lds_k<__hip_bfloat16>, dim3(MLPH_BLOCKS), dim3(BLK), 0, stream, Pb2);
    } else if (ws_size >= WS_BIG) {
        hipLaunchKernelGGL(transpose_k<float>, dim3(TG_BLOCKS), dim3(BLK), 0, stream, Pf);
        hipLaunchKernelGGL(transpose_k<__hip_bfloat16>, dim3(TG_BLOCKS), dim3(BLK), 0, stream, Pb);
        hipLaunchKernelGGL(sample_tg_k<float>, dim3(SAMP_BLOCKS), dim3(BLK), 0, stream, Pf);
        hipLaunchKernelGGL(sample_tg_k<__hip_bfloat16>, dim3(SAMP_BLOCKS), dim3(BLK), 0, stream, Pb);
    } else {
        hipLaunchKernelGGL(sample_k<float>, dim3(SAMP_BLOCKS), dim3(BLK), 0, stream, Pf);
        hipLaunchKernelGGL(sample_k<__hip_bfloat16>, dim3(SAMP_BLOCKS), dim3(BLK), 0, stream, Pb);
    }
    hipLaunchKernelGGL(composite_k<float>, dim3(NRAYS), dim3(64), 0, stream, Pf);
    hipLaunchKernelGGL(composite_k<__hip_bfloat16>, dim3(NRAYS), dim3(64), 0, stream, Pb);
}